// Round 1
// baseline (5859.468 us; speedup 1.0000x reference)
//
#include <hip/hip_runtime.h>
#include <math.h>

#define DEVI static __device__ __forceinline__

namespace {
constexpr int Bc   = 2;
constexpr int Nc   = 1024;
constexpr int Dc   = 256;
constexpr int Hc   = 4;
constexpr int NP1c = 1025;
constexpr float LN_EPS = 1e-6f;
constexpr float NORMV  = -7.6246189861593985f; // -log(2048)
constexpr float LOGNV  =  6.9314718055994531f; // log(1024)
}

// ---------------- helpers ----------------
DEVI float block_sum_256(float v, float* scratch) {
    int t = threadIdx.x;
    scratch[t] = v;
    __syncthreads();
    for (int s = 128; s > 0; s >>= 1) {
        if (t < s) scratch[t] += scratch[t + s];
        __syncthreads();
    }
    float r = scratch[0];
    __syncthreads();
    return r;
}

DEVI void ln_relu_inplace(float* x, const float* g, const float* be, int C, float* scratch) {
    int t = threadIdx.x;
    float v = (t < C) ? x[t] : 0.f;
    float mean = block_sum_256(v, scratch) / (float)C;
    float dv = (t < C) ? (x[t] - mean) : 0.f;
    float var = block_sum_256(dv * dv, scratch) / (float)(C - 1);
    float rstd = 1.f / (sqrtf(var) + LN_EPS);
    if (t < C) x[t] = fmaxf(g[t] * dv * rstd + be[t], 0.f);
    __syncthreads();
}

// ---------------- keypoint encoder: one block per (n,b) position ----------------
__global__ __launch_bounds__(256) void kenc_kernel(
    const float* __restrict__ kpts, const float* __restrict__ scr,
    const float* __restrict__ desc_in, float* __restrict__ desc_out,
    const float* __restrict__ w0, const float* __restrict__ b0,
    const float* __restrict__ g0, const float* __restrict__ be0,
    const float* __restrict__ w1, const float* __restrict__ b1,
    const float* __restrict__ g1, const float* __restrict__ be1,
    const float* __restrict__ w2, const float* __restrict__ b2,
    const float* __restrict__ g2, const float* __restrict__ be2,
    const float* __restrict__ w3, const float* __restrict__ b3)
{
    __shared__ float xa[256], xb[256], scratch[256];
    const int n = blockIdx.x, b = blockIdx.y, t = threadIdx.x;
    if (t == 0) {
        float kx = kpts[((long)b * Nc + n) * 2 + 0];
        float ky = kpts[((long)b * Nc + n) * 2 + 1];
        xa[0] = (kx - 320.f) * (1.f / 448.f);
        xa[1] = (ky - 240.f) * (1.f / 448.f);
        xa[2] = scr[b * Nc + n];
    }
    __syncthreads();
    if (t < 32) { float a = b0[t]; for (int c = 0; c < 3;   ++c) a += w0[t*3   + c] * xa[c]; xb[t] = a; }
    __syncthreads();
    ln_relu_inplace(xb, g0, be0, 32, scratch);
    if (t < 64) { float a = b1[t]; for (int c = 0; c < 32;  ++c) a += w1[t*32  + c] * xb[c]; xa[t] = a; }
    __syncthreads();
    ln_relu_inplace(xa, g1, be1, 64, scratch);
    if (t < 128){ float a = b2[t]; for (int c = 0; c < 64;  ++c) a += w2[t*64  + c] * xa[c]; xb[t] = a; }
    __syncthreads();
    ln_relu_inplace(xb, g2, be2, 128, scratch);
    {   float a = b3[t]; for (int c = 0; c < 128; ++c) a += w3[t*128 + c] * xb[c];
        long idx = ((long)b * Dc + t) * Nc + n;
        desc_out[idx] = desc_in[idx] + a; }
}

// ---------------- conv1 (1x1 conv == W[O,C] @ in[B,C,N] + bias) tiled GEMM ----------------
// grid: (Nc/BN, O/BM, B). Optional concat second input (channels CA..CA+CB-1).
template<int BM, int BN, int TM, int TN>
__global__ __launch_bounds__(256) void conv1_gemm(
    const float* __restrict__ W, const float* __restrict__ bias,
    const float* __restrict__ inA, int CA,
    const float* __restrict__ inB, int CB,
    float* __restrict__ out, int O)
{
    constexpr int KC = 16;
    const int C = CA + CB;
    __shared__ float Wt[KC][BM + 4];
    __shared__ float It[KC][BN + 4];
    const int b = blockIdx.z;
    const int o0 = blockIdx.y * BM, n0 = blockIdx.x * BN;
    const int t = threadIdx.x;
    const int tx = t % (BN / TN), ty = t / (BN / TN);
    float acc[TM][TN];
    for (int i = 0; i < TM; ++i) for (int j = 0; j < TN; ++j) acc[i][j] = 0.f;

    for (int c0 = 0; c0 < C; c0 += KC) {
        __syncthreads();
        for (int e = t; e < BM * KC; e += 256) {
            int m = e >> 4, k = e & 15;
            Wt[k][m] = W[(long)(o0 + m) * C + (c0 + k)];
        }
        for (int e = t; e < KC * BN; e += 256) {
            int k = e / BN, n = e % BN;
            int c = c0 + k;
            float vv;
            if (c < CA) vv = inA[((long)b * CA + c) * Nc + n0 + n];
            else        vv = inB[((long)b * CB + (c - CA)) * Nc + n0 + n];
            It[k][n] = vv;
        }
        __syncthreads();
        #pragma unroll
        for (int k = 0; k < KC; ++k) {
            float av[TM], bv[TN];
            #pragma unroll
            for (int i = 0; i < TM; ++i) av[i] = Wt[k][ty * TM + i];
            #pragma unroll
            for (int j = 0; j < TN; ++j) bv[j] = It[k][tx * TN + j];
            #pragma unroll
            for (int i = 0; i < TM; ++i)
                #pragma unroll
                for (int j = 0; j < TN; ++j) acc[i][j] += av[i] * bv[j];
        }
    }
    for (int i = 0; i < TM; ++i) {
        int o = o0 + ty * TM + i;
        float bs = bias[o];
        for (int j = 0; j < TN; ++j)
            out[((long)b * O + o) * Nc + n0 + tx * TN + j] = acc[i][j] + bs;
    }
}

// ---------------- NT GEMM: out[i,j] = scale * sum_k A[k*aRow+i] * B[k*bRow+j] ----------------
// grid: (cols/64, rows/64, B*Hcnt)
__global__ __launch_bounds__(256) void gemm_nt(
    const float* __restrict__ A, const float* __restrict__ Bm,
    float* __restrict__ outp, int K, int aRow, int bRow, int Hcnt,
    long aOffB, long aOffH, long bOffB, long bOffH,
    long oOffB, long oOffH, int ldo, float scale)
{
    __shared__ float At[16][68], Bt[16][68];
    const int z = blockIdx.z, b = z / Hcnt, h = z % Hcnt;
    const float* Ab = A + (long)b * aOffB + (long)h * aOffH;
    const float* Bb = Bm + (long)b * bOffB + (long)h * bOffH;
    float* Ob = outp + (long)b * oOffB + (long)h * oOffH;
    const int i0 = blockIdx.y * 64, j0 = blockIdx.x * 64;
    const int t = threadIdx.x, tx = t & 15, ty = t >> 4;
    float acc[4][4] = {};
    for (int k0 = 0; k0 < K; k0 += 16) {
        __syncthreads();
        for (int e = t; e < 1024; e += 256) {
            int k = e >> 6, x = e & 63;
            At[k][x] = Ab[(long)(k0 + k) * aRow + i0 + x];
        }
        for (int e = t; e < 1024; e += 256) {
            int k = e >> 6, x = e & 63;
            Bt[k][x] = Bb[(long)(k0 + k) * bRow + j0 + x];
        }
        __syncthreads();
        #pragma unroll
        for (int k = 0; k < 16; ++k) {
            float av[4], bv[4];
            #pragma unroll
            for (int i = 0; i < 4; ++i) av[i] = At[k][ty * 4 + i];
            #pragma unroll
            for (int j = 0; j < 4; ++j) bv[j] = Bt[k][tx * 4 + j];
            #pragma unroll
            for (int i = 0; i < 4; ++i)
                #pragma unroll
                for (int j = 0; j < 4; ++j) acc[i][j] += av[i] * bv[j];
        }
    }
    for (int i = 0; i < 4; ++i)
        for (int j = 0; j < 4; ++j)
            Ob[(long)(i0 + ty * 4 + i) * ldo + j0 + tx * 4 + j] = acc[i][j] * scale;
}

// ---------------- row softmax over prob [B*H*N rows][N] ----------------
__global__ __launch_bounds__(256) void softmax_rows(float* __restrict__ P)
{
    __shared__ float scratch[256];
    long row = (long)blockIdx.y * gridDim.x + blockIdx.x;
    float* p = P + row * Nc;
    int t = threadIdx.x;
    float4 x = ((const float4*)p)[t];
    float m = fmaxf(fmaxf(x.x, x.y), fmaxf(x.z, x.w));
    scratch[t] = m; __syncthreads();
    for (int s = 128; s > 0; s >>= 1) {
        if (t < s) scratch[t] = fmaxf(scratch[t], scratch[t + s]);
        __syncthreads();
    }
    float M = scratch[0]; __syncthreads();
    float e0 = __expf(x.x - M), e1 = __expf(x.y - M), e2 = __expf(x.z - M), e3 = __expf(x.w - M);
    float S = block_sum_256(e0 + e1 + e2 + e3, scratch);
    float inv = 1.f / S;
    float4 o; o.x = e0 * inv; o.y = e1 * inv; o.z = e2 * inv; o.w = e3 * inv;
    ((float4*)p)[t] = o;
}

// ---------------- PV: msg partial over m-chunk; part[kc][b][d][n] ----------------
// grid: (Nc/64, 4, B*H)
__global__ __launch_bounds__(256) void msg_kernel(
    const float* __restrict__ qkvSrc, const float* __restrict__ P,
    float* __restrict__ part)
{
    __shared__ float Vt[16][68], Pt[16][68];
    const int z = blockIdx.z, b = z / Hc, h = z % Hc;
    const int kc = blockIdx.y;
    const int n0 = blockIdx.x * 64;
    const int m_base = kc * 256;
    const float* vb = qkvSrc + ((long)b * 768 + 512 + h) * Nc;
    const float* pb = P + ((long)(b * Hc + h) * Nc) * Nc;
    const int t = threadIdx.x, tx = t & 15, ty = t >> 4;
    float acc[4][4] = {};
    for (int ch = 0; ch < 256; ch += 16) {
        int m0 = m_base + ch;
        __syncthreads();
        for (int e = t; e < 1024; e += 256) {
            int hd = e >> 4, k = e & 15;
            Vt[k][hd] = vb[(long)hd * 4 * Nc + m0 + k];
        }
        for (int e = t; e < 1024; e += 256) {
            int n = e >> 4, k = e & 15;
            Pt[k][n] = pb[(long)(n0 + n) * Nc + m0 + k];
        }
        __syncthreads();
        #pragma unroll
        for (int k = 0; k < 16; ++k) {
            float av[4], bv[4];
            #pragma unroll
            for (int i = 0; i < 4; ++i) av[i] = Vt[k][ty * 4 + i];
            #pragma unroll
            for (int j = 0; j < 4; ++j) bv[j] = Pt[k][tx * 4 + j];
            #pragma unroll
            for (int i = 0; i < 4; ++i)
                #pragma unroll
                for (int j = 0; j < 4; ++j) acc[i][j] += av[i] * bv[j];
        }
    }
    const long BDN = (long)Bc * Dc * Nc;
    for (int i = 0; i < 4; ++i) {
        int hd = ty * 4 + i, d = hd * 4 + h;
        for (int j = 0; j < 4; ++j)
            part[(long)kc * BDN + ((long)b * Dc + d) * Nc + n0 + tx * 4 + j] = acc[i][j];
    }
}

__global__ __launch_bounds__(256) void reduce4_kernel(
    const float* __restrict__ part, float* __restrict__ outp)
{
    const long BDN = (long)Bc * Dc * Nc;
    long i = ((long)blockIdx.x * 256 + threadIdx.x) * 4;
    float4 a = *(const float4*)(part + i);
    float4 b = *(const float4*)(part + BDN + i);
    float4 c = *(const float4*)(part + 2 * BDN + i);
    float4 d = *(const float4*)(part + 3 * BDN + i);
    float4 o;
    o.x = a.x + b.x + c.x + d.x; o.y = a.y + b.y + c.y + d.y;
    o.z = a.z + b.z + c.z + d.z; o.w = a.w + b.w + c.w + d.w;
    *(float4*)(outp + i) = o;
}

// ---------------- LayerNorm(channel dim, ddof=1, eps on std) + ReLU, C=512 ----------------
// grid: (Nc/16, B), block 256 = 16 nn x 16 cg
__global__ __launch_bounds__(256) void ln_relu_512(
    float* __restrict__ x, const float* __restrict__ g, const float* __restrict__ be)
{
    __shared__ float ps[16][17], pq[16][17];
    __shared__ float smean[16], srcp[16];
    const int b = blockIdx.y, n0 = blockIdx.x * 16;
    const int t = threadIdx.x, nn = t & 15, cg = t >> 4;
    float* xb = x + (long)b * 512 * Nc;
    float s = 0.f, q = 0.f;
    for (int c = cg; c < 512; c += 16) {
        float v = xb[(long)c * Nc + n0 + nn];
        s += v; q += v * v;
    }
    ps[cg][nn] = s; pq[cg][nn] = q;
    __syncthreads();
    for (int st = 8; st > 0; st >>= 1) {
        if (cg < st) { ps[cg][nn] += ps[cg + st][nn]; pq[cg][nn] += pq[cg + st][nn]; }
        __syncthreads();
    }
    if (cg == 0) {
        float S = ps[0][nn], Q = pq[0][nn];
        float mean = S / 512.f;
        float var = fmaxf((Q - 512.f * mean * mean) / 511.f, 0.f);
        smean[nn] = mean;
        srcp[nn] = 1.f / (sqrtf(var) + LN_EPS);
    }
    __syncthreads();
    float mean = smean[nn], rcp = srcp[nn];
    for (int c = cg; c < 512; c += 16) {
        long idx = (long)c * Nc + n0 + nn;
        float v = xb[idx];
        xb[idx] = fmaxf(g[c] * (v - mean) * rcp + be[c], 0.f);
    }
}

// ---------------- residual adds (two pairs) ----------------
__global__ __launch_bounds__(256) void add_pair(
    float* __restrict__ d0, const float* __restrict__ s0,
    float* __restrict__ d1, const float* __restrict__ s1)
{
    long i = ((long)blockIdx.x * 256 + threadIdx.x) * 4;
    float* d = blockIdx.y ? d1 : d0;
    const float* s = blockIdx.y ? s1 : s0;
    float4 a = *(const float4*)(d + i);
    float4 bv = *(const float4*)(s + i);
    a.x += bv.x; a.y += bv.y; a.z += bv.z; a.w += bv.w;
    *(float4*)(d + i) = a;
}

// ---------------- Sinkhorn setup / iterate / finish ----------------
__global__ void bins_fill(float* __restrict__ Z, const float* __restrict__ alpha_p)
{
    float alpha = alpha_p[0];
    int idx = blockIdx.x * 256 + threadIdx.x;
    int b = blockIdx.y;
    float* Zb = Z + (long)b * NP1c * NP1c;
    if (idx < NP1c) Zb[(long)1024 * NP1c + idx] = alpha;
    else { int i = idx - NP1c; if (i < 1024) Zb[(long)i * NP1c + 1024] = alpha; }
}

__global__ void transpose_np1(const float* __restrict__ Z, float* __restrict__ ZT)
{
    __shared__ float tile[32][33];
    int b = blockIdx.z;
    int i0 = blockIdx.y * 32, j0 = blockIdx.x * 32;
    int tx = threadIdx.x, ty = threadIdx.y;
    const float* Zb = Z + (long)b * NP1c * NP1c;
    float* Tb = ZT + (long)b * NP1c * NP1c;
    for (int ii = ty; ii < 32; ii += 8) {
        int i = i0 + ii, j = j0 + tx;
        if (i < NP1c && j < NP1c) tile[ii][tx] = Zb[(long)i * NP1c + j];
    }
    __syncthreads();
    for (int jj = ty; jj < 32; jj += 8) {
        int j = j0 + jj, i = i0 + tx;
        if (j < NP1c && i < NP1c) Tb[(long)j * NP1c + i] = tile[tx][jj];
    }
}

__global__ void zero_vec(float* __restrict__ v, int n)
{
    int i = blockIdx.x * 256 + threadIdx.x;
    if (i < n) v[i] = 0.f;
}

// out[b][i] = lmu(i) - LSE_j( M[b][i][j] + addv[b][j] )   (log_mu == log_nu here)
__global__ __launch_bounds__(256) void sinkhorn_lse(
    const float* __restrict__ M, const float* __restrict__ addv, float* __restrict__ outv)
{
    __shared__ float sm[256], ss[256];
    const int i = blockIdx.x, b = blockIdx.y, t = threadIdx.x;
    const float* row = M + ((long)b * NP1c + i) * NP1c;
    const float* av = addv + b * NP1c;
    float m = -1e30f, s = 0.f;
    for (int j = t; j < NP1c; j += 256) {
        float xv = row[j] + av[j];
        if (xv > m) { s = s * __expf(m - xv) + 1.f; m = xv; }
        else s += __expf(xv - m);
    }
    sm[t] = m; ss[t] = s;
    __syncthreads();
    for (int st = 128; st > 0; st >>= 1) {
        if (t < st) {
            float m1 = sm[t], s1 = ss[t], m2 = sm[t + st], s2 = ss[t + st];
            float mm = fmaxf(m1, m2);
            sm[t] = mm;
            ss[t] = s1 * __expf(m1 - mm) + s2 * __expf(m2 - mm);
        }
        __syncthreads();
    }
    if (t == 0) {
        float lse = sm[0] + __logf(ss[0]);
        float lmu = (i < 1024) ? NORMV : (LOGNV + NORMV);
        outv[b * NP1c + i] = lmu - lse;
    }
}

__global__ __launch_bounds__(256) void final_out_k(
    const float* __restrict__ Z, const float* __restrict__ u,
    const float* __restrict__ v, float* __restrict__ outp)
{
    const int i = blockIdx.x, b = blockIdx.y, t = threadIdx.x;
    const float* row = Z + ((long)b * NP1c + i) * NP1c;
    float* orow = outp + ((long)b * NP1c + i) * NP1c;
    float ui = u[b * NP1c + i];
    for (int j = t; j < NP1c; j += 256)
        orow[j] = row[j] + ui + v[b * NP1c + j] - NORMV;
}

// =======================================================================
extern "C" void kernel_launch(void* const* d_in, const int* in_sizes, int n_in,
                              void* d_out, int out_size, void* d_ws, size_t ws_size,
                              hipStream_t stream)
{
    (void)in_sizes; (void)n_in; (void)out_size; (void)ws_size;
    const float* kpts0   = (const float*)d_in[0];
    const float* kpts1   = (const float*)d_in[1];
    const float* scores0 = (const float*)d_in[2];
    const float* scores1 = (const float*)d_in[3];
    const float* desc0   = (const float*)d_in[4];
    const float* desc1   = (const float*)d_in[5];
    const float* kw0 = (const float*)d_in[6];  const float* kb0 = (const float*)d_in[7];
    const float* kg0 = (const float*)d_in[8];  const float* ke0 = (const float*)d_in[9];
    const float* kw1 = (const float*)d_in[10]; const float* kb1 = (const float*)d_in[11];
    const float* kg1 = (const float*)d_in[12]; const float* ke1 = (const float*)d_in[13];
    const float* kw2 = (const float*)d_in[14]; const float* kb2 = (const float*)d_in[15];
    const float* kg2 = (const float*)d_in[16]; const float* ke2 = (const float*)d_in[17];
    const float* kw3 = (const float*)d_in[18]; const float* kb3 = (const float*)d_in[19];
    const float* gnn_proj_w  = (const float*)d_in[20];
    const float* gnn_proj_b  = (const float*)d_in[21];
    const float* gnn_merge_w = (const float*)d_in[22];
    const float* gnn_merge_b = (const float*)d_in[23];
    const float* gnn_mlp1_w  = (const float*)d_in[24];
    const float* gnn_mlp1_b  = (const float*)d_in[25];
    const float* gnn_ln_g    = (const float*)d_in[26];
    const float* gnn_ln_b    = (const float*)d_in[27];
    const float* gnn_mlp2_w  = (const float*)d_in[28];
    const float* gnn_mlp2_b  = (const float*)d_in[29];
    const float* final_w     = (const float*)d_in[30];
    const float* final_b     = (const float*)d_in[31];
    const float* bin_score   = (const float*)d_in[32];

    float* ws = (float*)d_ws;
    size_t off = 0;
    auto alloc = [&](size_t n) {
        float* p = ws + off;
        off += (n + 255) & ~(size_t)255;
        return p;
    };
    const long BDN = (long)Bc * Dc * Nc;          // 524288
    float* desc0w  = alloc(BDN);
    float* desc1w  = alloc(BDN);
    float* qkvA    = alloc((long)Bc * 768 * Nc);  // also reused as mdesc0 later
    float* qkvB    = alloc((long)Bc * 768 * Nc);  // also reused as mdesc1 later
    float* prob    = alloc((long)Bc * Hc * Nc * Nc); // 32MB; reused as ZT later
    float* msgpart = alloc(4 * BDN);
    float* msgsum  = alloc(BDN);
    float* msgconv = alloc(BDN);
    float* ybuf    = alloc((long)Bc * 512 * Nc);
    float* delta0  = alloc(BDN);
    float* delta1  = alloc(BDN);
    float* Z       = alloc((long)Bc * NP1c * NP1c);
    float* u       = alloc(Bc * NP1c);
    float* v       = alloc(Bc * NP1c);

    // ---- keypoint encoder + residual into working descriptors ----
    kenc_kernel<<<dim3(Nc, Bc), 256, 0, stream>>>(kpts0, scores0, desc0, desc0w,
        kw0, kb0, kg0, ke0, kw1, kb1, kg1, ke1, kw2, kb2, kg2, ke2, kw3, kb3);
    kenc_kernel<<<dim3(Nc, Bc), 256, 0, stream>>>(kpts1, scores1, desc1, desc1w,
        kw0, kb0, kg0, ke0, kw1, kb1, kg1, ke1, kw2, kb2, kg2, ke2, kw3, kb3);

    // ---- GNN layers (all 'cross') ----
    for (int l = 0; l < 9; ++l) {
        const float* pw  = gnn_proj_w  + (long)l * 3 * Dc * Dc;
        const float* pb  = gnn_proj_b  + (long)l * 3 * Dc;
        const float* mw  = gnn_merge_w + (long)l * Dc * Dc;
        const float* mbb = gnn_merge_b + (long)l * Dc;
        const float* m1w = gnn_mlp1_w  + (long)l * 512 * 512;
        const float* m1b = gnn_mlp1_b  + (long)l * 512;
        const float* lng = gnn_ln_g    + (long)l * 512;
        const float* lnb = gnn_ln_b    + (long)l * 512;
        const float* m2w = gnn_mlp2_w  + (long)l * Dc * 512;
        const float* m2b = gnn_mlp2_b  + (long)l * Dc;

        // qkv of both descriptors (q rows 0..255, k rows 256..511, v rows 512..767)
        conv1_gemm<64,64,4,4><<<dim3(16,12,2), 256, 0, stream>>>(
            pw, pb, desc0w, 256, nullptr, 0, qkvA, 768);
        conv1_gemm<64,64,4,4><<<dim3(16,12,2), 256, 0, stream>>>(
            pw, pb, desc1w, 256, nullptr, 0, qkvB, 768);

        auto prop = [&](const float* qkvX, const float* qkvY, const float* xdesc, float* delta) {
            // scores = q(x)^T k(src) / 8 ; heads strided by 4 channels
            gemm_nt<<<dim3(16,16,8), 256, 0, stream>>>(
                qkvX, qkvY + 256 * Nc, prob, 64, 4 * Nc, 4 * Nc, Hc,
                768L * Nc, (long)Nc, 768L * Nc, (long)Nc,
                (long)Hc * Nc * Nc, (long)Nc * Nc, Nc, 0.125f);
            softmax_rows<<<dim3(Nc, Bc * Hc), 256, 0, stream>>>(prob);
            msg_kernel<<<dim3(16,4,8), 256, 0, stream>>>(qkvY, prob, msgpart);
            reduce4_kernel<<<dim3(512), 256, 0, stream>>>(msgpart, msgsum);
            conv1_gemm<32,32,2,2><<<dim3(32,8,2), 256, 0, stream>>>(
                mw, mbb, msgsum, 256, nullptr, 0, msgconv, 256);
            conv1_gemm<64,64,4,4><<<dim3(16,8,2), 256, 0, stream>>>(
                m1w, m1b, xdesc, 256, msgconv, 256, ybuf, 512);
            ln_relu_512<<<dim3(64,2), 256, 0, stream>>>(ybuf, lng, lnb);
            conv1_gemm<32,32,2,2><<<dim3(32,8,2), 256, 0, stream>>>(
                m2w, m2b, ybuf, 512, nullptr, 0, delta, 256);
        };
        prop(qkvA, qkvB, desc0w, delta0);
        prop(qkvB, qkvA, desc1w, delta1);
        add_pair<<<dim3(512,2), 256, 0, stream>>>(desc0w, delta0, desc1w, delta1);
    }

    // ---- final projection + score matrix ----
    float* mdesc0 = qkvA;
    float* mdesc1 = qkvB;
    conv1_gemm<32,32,2,2><<<dim3(32,8,2), 256, 0, stream>>>(
        final_w, final_b, desc0w, 256, nullptr, 0, mdesc0, 256);
    conv1_gemm<32,32,2,2><<<dim3(32,8,2), 256, 0, stream>>>(
        final_w, final_b, desc1w, 256, nullptr, 0, mdesc1, 256);
    gemm_nt<<<dim3(16,16,2), 256, 0, stream>>>(
        mdesc0, mdesc1, Z, 256, Nc, Nc, 1,
        (long)Dc * Nc, 0, (long)Dc * Nc, 0,
        (long)NP1c * NP1c, 0, NP1c, 1.f / 16.f);
    bins_fill<<<dim3(9,2), 256, 0, stream>>>(Z, bin_score);

    // ---- Sinkhorn (log-space), 20 iterations ----
    float* ZT = prob; // reuse 32MB buffer
    transpose_np1<<<dim3(33,33,2), dim3(32,8), 0, stream>>>(Z, ZT);
    zero_vec<<<dim3(9), 256, 0, stream>>>(v, Bc * NP1c);
    for (int it = 0; it < 20; ++it) {
        sinkhorn_lse<<<dim3(NP1c, Bc), 256, 0, stream>>>(Z,  v, u);
        sinkhorn_lse<<<dim3(NP1c, Bc), 256, 0, stream>>>(ZT, u, v);
    }
    final_out_k<<<dim3(NP1c, Bc), 256, 0, stream>>>(Z, u, v, (float*)d_out);
}

// Round 2
// 3253.853 us; speedup vs baseline: 1.8008x; 1.8008x over previous
//
#include <hip/hip_runtime.h>
#include <hip/hip_bf16.h>
#include <math.h>

#define DEVI static __device__ __forceinline__

namespace {
constexpr int Bc   = 2;
constexpr int Nc   = 1024;
constexpr int Dc   = 256;
constexpr int NP1c = 1025;
constexpr float LN_EPS = 1e-6f;
constexpr float NORMV  = -7.6246189861593985f; // -log(2048)
constexpr float LOGNV  =  6.9314718055994531f; // log(1024)
}

typedef __attribute__((ext_vector_type(8))) short bf16x8;
typedef __attribute__((ext_vector_type(4))) float f32x4;

DEVI void split2(float v, __hip_bfloat16& h, __hip_bfloat16& l) {
    h = __float2bfloat16(v);
    l = __float2bfloat16(v - __bfloat162float(h));
}

// ---------------- helpers ----------------
DEVI float block_sum_256(float v, float* scratch) {
    int t = threadIdx.x;
    scratch[t] = v;
    __syncthreads();
    for (int s = 128; s > 0; s >>= 1) {
        if (t < s) scratch[t] += scratch[t + s];
        __syncthreads();
    }
    float r = scratch[0];
    __syncthreads();
    return r;
}

DEVI void ln_relu_inplace(float* x, const float* g, const float* be, int C, float* scratch) {
    int t = threadIdx.x;
    float v = (t < C) ? x[t] : 0.f;
    float mean = block_sum_256(v, scratch) / (float)C;
    float dv = (t < C) ? (x[t] - mean) : 0.f;
    float var = block_sum_256(dv * dv, scratch) / (float)(C - 1);
    float rstd = 1.f / (sqrtf(var) + LN_EPS);
    if (t < C) x[t] = fmaxf(g[t] * dv * rstd + be[t], 0.f);
    __syncthreads();
}

// ---------------- keypoint encoder: one block per (n,b) position; n-major out ----------------
__global__ __launch_bounds__(256) void kenc_kernel(
    const float* __restrict__ kpts, const float* __restrict__ scr,
    const float* __restrict__ desc_in, float* __restrict__ desc_out,
    const float* __restrict__ w0, const float* __restrict__ b0,
    const float* __restrict__ g0, const float* __restrict__ be0,
    const float* __restrict__ w1, const float* __restrict__ b1,
    const float* __restrict__ g1, const float* __restrict__ be1,
    const float* __restrict__ w2, const float* __restrict__ b2,
    const float* __restrict__ g2, const float* __restrict__ be2,
    const float* __restrict__ w3, const float* __restrict__ b3)
{
    __shared__ float xa[256], xb[256], scratch[256];
    const int n = blockIdx.x, b = blockIdx.y, t = threadIdx.x;
    if (t == 0) {
        float kx = kpts[((long)b * Nc + n) * 2 + 0];
        float ky = kpts[((long)b * Nc + n) * 2 + 1];
        xa[0] = (kx - 320.f) * (1.f / 448.f);
        xa[1] = (ky - 240.f) * (1.f / 448.f);
        xa[2] = scr[b * Nc + n];
    }
    __syncthreads();
    if (t < 32) { float a = b0[t]; for (int c = 0; c < 3;   ++c) a += w0[t*3   + c] * xa[c]; xb[t] = a; }
    __syncthreads();
    ln_relu_inplace(xb, g0, be0, 32, scratch);
    if (t < 64) { float a = b1[t]; for (int c = 0; c < 32;  ++c) a += w1[t*32  + c] * xb[c]; xa[t] = a; }
    __syncthreads();
    ln_relu_inplace(xa, g1, be1, 64, scratch);
    if (t < 128){ float a = b2[t]; for (int c = 0; c < 64;  ++c) a += w2[t*64  + c] * xa[c]; xb[t] = a; }
    __syncthreads();
    ln_relu_inplace(xb, g2, be2, 128, scratch);
    {   float a = b3[t]; for (int c = 0; c < 128; ++c) a += w3[t*128 + c] * xb[c];
        // input desc channel-major [b][d][n]; output n-major [b][n][d]
        desc_out[((long)b * Nc + n) * Dc + t] = desc_in[((long)b * Dc + t) * Nc + n] + a; }
}

// =======================================================================
// MFMA NT GEMM, hi/lo split: out[m][n] = scale * sum_k A[m][k]*B[n][k] (+bias[n])
// A,B given as bf16 hi/lo planes, row-major [rows][ld], K contiguous.
// EPI: 0 = fp32 out, 1 = bf16 hi/lo planes out
// z decomposed: i1 = z/(nz2*nz3); i2 = (z%(nz2*nz3))/nz3; i3 = z%nz3
// =======================================================================
template<int BM, int BN, int EPI>
__global__ __launch_bounds__(256) void mfma_nt(
    const short* __restrict__ Ahi0, const short* __restrict__ Alo0, int lda,
    const short* __restrict__ Bhi0, const short* __restrict__ Blo0, int ldb,
    int K, float scale, const float* __restrict__ bias,
    float* __restrict__ outF, __hip_bfloat16* __restrict__ outHi,
    __hip_bfloat16* __restrict__ outLo, int ldo,
    int nz2, int nz3,
    long aS1, long aS2, long aS3,
    long bS1, long bS2, long bS3,
    long oS1, long oS2, long oS3)
{
    constexpr int MI = BM / 32;           // frag-tiles per wave (rows)
    constexpr int NI = BN / 32;           // frag-tiles per wave (cols)
    constexpr int instA = BM / 16, instB = BN / 16;
    constexpr int OFF_AH = 0;
    constexpr int OFF_AL = BM * 32;
    constexpr int OFF_BH = 2 * BM * 32;
    constexpr int OFF_BL = 2 * BM * 32 + BN * 32;
    __shared__ short smem[(2 * BM + 2 * BN) * 32];

    const int z = blockIdx.z;
    const int i1 = z / (nz2 * nz3);
    const int i2 = (z % (nz2 * nz3)) / nz3;
    const int i3 = z % nz3;
    const long aOff = i1 * aS1 + i2 * aS2 + i3 * aS3;
    const long bOff = i1 * bS1 + i2 * bS2 + i3 * bS3;
    const long oOff = i1 * oS1 + i2 * oS2 + i3 * oS3;
    const short* Ah = Ahi0 + aOff; const short* Al = Alo0 + aOff;
    const short* Bh = Bhi0 + bOff; const short* Bl = Blo0 + bOff;

    const int m0 = blockIdx.y * BM, n0 = blockIdx.x * BN;
    const int t = threadIdx.x, lane = t & 63, wid = t >> 6;
    const int lr = lane & 15, lg = lane >> 4;
    const int wr = wid >> 1, wc = wid & 1;

    f32x4 acc[MI][NI];
    for (int mi = 0; mi < MI; ++mi)
        for (int ni = 0; ni < NI; ++ni)
            acc[mi][ni] = f32x4{0.f, 0.f, 0.f, 0.f};

    for (int k0 = 0; k0 < K; k0 += 32) {
        // ---- stage: reg-staged global -> LDS in fragment order ----
        constexpr int total = 2 * instA + 2 * instB;
        for (int q = wid; q < total; q += 4) {
            const short* gsrc; int ldg, mi, ploff, row0;
            if (q < instA)               { gsrc = Ah; ldg = lda; mi = q;                 ploff = OFF_AH; row0 = m0; }
            else if (q < 2*instA)        { gsrc = Al; ldg = lda; mi = q - instA;         ploff = OFF_AL; row0 = m0; }
            else if (q < 2*instA+instB)  { gsrc = Bh; ldg = ldb; mi = q - 2*instA;       ploff = OFF_BH; row0 = n0; }
            else                         { gsrc = Bl; ldg = ldb; mi = q - 2*instA-instB; ploff = OFF_BL; row0 = n0; }
            const short* g = gsrc + (long)(row0 + mi * 16 + lr) * ldg + (k0 + lg * 8);
            bf16x8 v = *(const bf16x8*)g;
            *(bf16x8*)(smem + ploff + mi * 512 + lane * 8) = v;
        }
        __syncthreads();
        // ---- compute ----
        bf16x8 ah[MI], al[MI];
        #pragma unroll
        for (int mi = 0; mi < MI; ++mi) {
            ah[mi] = *(const bf16x8*)(smem + OFF_AH + ((wr * MI + mi) * 64 + lane) * 8);
            al[mi] = *(const bf16x8*)(smem + OFF_AL + ((wr * MI + mi) * 64 + lane) * 8);
        }
        #pragma unroll
        for (int ni = 0; ni < NI; ++ni) {
            bf16x8 bh = *(const bf16x8*)(smem + OFF_BH + ((wc * NI + ni) * 64 + lane) * 8);
            bf16x8 bl = *(const bf16x8*)(smem + OFF_BL + ((wc * NI + ni) * 64 + lane) * 8);
            #pragma unroll
            for (int mi = 0; mi < MI; ++mi) {
                acc[mi][ni] = __builtin_amdgcn_mfma_f32_16x16x32_bf16(ah[mi], bh, acc[mi][ni], 0, 0, 0);
                acc[mi][ni] = __builtin_amdgcn_mfma_f32_16x16x32_bf16(ah[mi], bl, acc[mi][ni], 0, 0, 0);
                acc[mi][ni] = __builtin_amdgcn_mfma_f32_16x16x32_bf16(al[mi], bh, acc[mi][ni], 0, 0, 0);
            }
        }
        __syncthreads();
    }

    // ---- epilogue ----
    for (int mi = 0; mi < MI; ++mi) {
        for (int i = 0; i < 4; ++i) {
            int row = m0 + wr * (BM / 2) + mi * 16 + lg * 4 + i;
            for (int ni = 0; ni < NI; ++ni) {
                int col = n0 + wc * (BN / 2) + ni * 16 + lr;
                float v = acc[mi][ni][i] * scale;
                if (bias) v += bias[col];
                if (EPI == 0) {
                    outF[(long)row * ldo + col + oOff] = v;
                } else {
                    __hip_bfloat16 h, l;
                    split2(v, h, l);
                    outHi[(long)row * ldo + col + oOff] = h;
                    outLo[(long)row * ldo + col + oOff] = l;
                }
            }
        }
    }
}

// ---------------- fp32 rows -> bf16 hi/lo planes (generic) ----------------
__global__ __launch_bounds__(256) void rows_to_planes(
    const float* __restrict__ src, int ldsrc, int C,
    __hip_bfloat16* __restrict__ hi, __hip_bfloat16* __restrict__ lo, int ldp, long total)
{
    long idx = (long)blockIdx.x * 256 + threadIdx.x;
    if (idx >= total) return;
    long row = idx / C; int c = (int)(idx % C);
    float v = src[row * ldsrc + c];
    __hip_bfloat16 h, l; split2(v, h, l);
    hi[row * ldp + c] = h; lo[row * ldp + c] = l;
}

// ---------------- v transpose-convert: qkvF[db][n][512+c] -> vT[db][c][n] planes ----------------
__global__ __launch_bounds__(256) void vT_convert(
    const float* __restrict__ qkvF, __hip_bfloat16* __restrict__ hi, __hip_bfloat16* __restrict__ lo)
{
    __shared__ float tile[64][65];
    const int n0 = blockIdx.x * 64, c0 = blockIdx.y * 64, db = blockIdx.z;
    const int t = threadIdx.x;
    const int tc = t & 63, tg = t >> 6;
    const float* src = qkvF + ((long)db * Nc) * 768;
    for (int r = 0; r < 16; ++r) {
        int n = n0 + tg * 16 + r;
        tile[tg * 16 + r][tc] = src[(long)n * 768 + 512 + c0 + tc];
    }
    __syncthreads();
    for (int r = 0; r < 16; ++r) {
        int cLoc = tg * 16 + r;
        float v = tile[tc][cLoc];
        __hip_bfloat16 h, l; split2(v, h, l);
        long o = ((long)db * 256 + c0 + cLoc) * Nc + n0 + tc;
        hi[o] = h; lo[o] = l;
    }
}

// ---------------- row softmax: read fp32 scores, write P hi/lo planes ----------------
__global__ __launch_bounds__(256) void softmax_planes(
    const float* __restrict__ S, __hip_bfloat16* __restrict__ hi, __hip_bfloat16* __restrict__ lo)
{
    __shared__ float scratch[256];
    long row = (long)blockIdx.y * gridDim.x + blockIdx.x;
    const float* p = S + row * Nc;
    int t = threadIdx.x;
    float4 x = ((const float4*)p)[t];
    float m = fmaxf(fmaxf(x.x, x.y), fmaxf(x.z, x.w));
    scratch[t] = m; __syncthreads();
    for (int s = 128; s > 0; s >>= 1) {
        if (t < s) scratch[t] = fmaxf(scratch[t], scratch[t + s]);
        __syncthreads();
    }
    float M = scratch[0]; __syncthreads();
    float e0 = __expf(x.x - M), e1 = __expf(x.y - M), e2 = __expf(x.z - M), e3 = __expf(x.w - M);
    float Ssum = block_sum_256(e0 + e1 + e2 + e3, scratch);
    float inv = 1.f / Ssum;
    float pv[4] = {e0 * inv, e1 * inv, e2 * inv, e3 * inv};
    long base = row * Nc + t * 4;
    for (int j = 0; j < 4; ++j) {
        __hip_bfloat16 h, l; split2(pv[j], h, l);
        hi[base + j] = h; lo[base + j] = l;
    }
}

// ---------------- PV split-K reduce -> msg planes ----------------
__global__ __launch_bounds__(256) void pv_reduce_planes(
    const float* __restrict__ part, __hip_bfloat16* __restrict__ hi, __hip_bfloat16* __restrict__ lo)
{
    const long CH = (long)Bc * Nc * Dc; // 524288
    long i = (long)blockIdx.x * 256 + threadIdx.x;
    if (i >= CH) return;
    float v = part[i] + part[CH + i] + part[2 * CH + i] + part[3 * CH + i];
    __hip_bfloat16 h, l; split2(v, h, l);
    hi[i] = h; lo[i] = l;
}

// ---------------- LN(channel,ddof=1,eps-on-std)+ReLU over rows of 512; write planes ----------------
__global__ __launch_bounds__(256) void ln_relu_planes(
    const float* __restrict__ y, const float* __restrict__ g, const float* __restrict__ be,
    __hip_bfloat16* __restrict__ hi, __hip_bfloat16* __restrict__ lo)
{
    __shared__ float s1[256], s2[256];
    const long row = blockIdx.x;
    const int t = threadIdx.x;
    const float* src = y + row * 512;
    float a = src[t], b = src[t + 256];
    s1[t] = a + b; s2[t] = a * a + b * b;
    __syncthreads();
    for (int s = 128; s > 0; s >>= 1) {
        if (t < s) { s1[t] += s1[t + s]; s2[t] += s2[t + s]; }
        __syncthreads();
    }
    float mean = s1[0] / 512.f;
    float var = fmaxf((s2[0] - 512.f * mean * mean) / 511.f, 0.f);
    float rstd = 1.f / (sqrtf(var) + LN_EPS);
    float v1 = fmaxf(g[t] * (a - mean) * rstd + be[t], 0.f);
    float v2 = fmaxf(g[t + 256] * (b - mean) * rstd + be[t + 256], 0.f);
    __hip_bfloat16 h, l;
    split2(v1, h, l); hi[row * 512 + t] = h;       lo[row * 512 + t] = l;
    split2(v2, h, l); hi[row * 512 + t + 256] = h; lo[row * 512 + t + 256] = l;
}

// ---------------- residual add + convert to catbuf planes ----------------
__global__ __launch_bounds__(256) void resid_convert(
    float* __restrict__ descF, const float* __restrict__ delta,
    __hip_bfloat16* __restrict__ hi, __hip_bfloat16* __restrict__ lo)
{
    long i = (long)blockIdx.x * 256 + threadIdx.x;
    float v = descF[i] + delta[i];
    descF[i] = v;
    long row = i >> 8; int c = (int)(i & 255);
    __hip_bfloat16 h, l; split2(v, h, l);
    hi[row * 512 + c] = h; lo[row * 512 + c] = l;
}

// ---------------- weight converts ----------------
__global__ __launch_bounds__(256) void wconv_plain(
    const float* __restrict__ w, __hip_bfloat16* __restrict__ hi, __hip_bfloat16* __restrict__ lo, long total)
{
    long i = (long)blockIdx.x * 256 + threadIdx.x;
    if (i >= total) return;
    __hip_bfloat16 h, l; split2(w[i], h, l);
    hi[i] = h; lo[i] = l;
}

// proj: row-permute o' = t*256 + h*64 + hd  <-  o = t*256 + hd*4 + h
__global__ __launch_bounds__(256) void wconv_proj(
    const float* __restrict__ w, __hip_bfloat16* __restrict__ hi, __hip_bfloat16* __restrict__ lo)
{
    long i = (long)blockIdx.x * 256 + threadIdx.x;
    if (i >= 9L * 768 * 256) return;
    long l9 = i / (768 * 256);
    int rem = (int)(i % (768 * 256));
    int op = rem / 256, c = rem % 256;
    int tq = op / 256, within = op % 256;
    int h = within / 64, hd = within % 64;
    int o = tq * 256 + hd * 4 + h;
    float v = w[(l9 * 768 + o) * 256 + c];
    __hip_bfloat16 hh, ll; split2(v, hh, ll);
    hi[i] = hh; lo[i] = ll;
}

__global__ void wconv_proj_bias(const float* __restrict__ b, float* __restrict__ bp)
{
    int i = blockIdx.x * 256 + threadIdx.x;
    if (i >= 9 * 768) return;
    int l9 = i / 768, op = i % 768;
    int tq = op / 256, within = op % 256;
    int h = within / 64, hd = within % 64;
    bp[i] = b[(l9 * 3 + tq) * 256 + hd * 4 + h];
}

// merge: col-permute c' = h*64+hd reads orig col hd*4+h
__global__ __launch_bounds__(256) void wconv_merge(
    const float* __restrict__ w, __hip_bfloat16* __restrict__ hi, __hip_bfloat16* __restrict__ lo)
{
    long i = (long)blockIdx.x * 256 + threadIdx.x;
    if (i >= 9L * 256 * 256) return;
    long l9 = i / (256 * 256);
    int rem = (int)(i % (256 * 256));
    int o = rem / 256, cp = rem % 256;
    int h = cp / 64, hd = cp % 64;
    float v = w[(l9 * 256 + o) * 256 + hd * 4 + h];
    __hip_bfloat16 hh, ll; split2(v, hh, ll);
    hi[i] = hh; lo[i] = ll;
}

// ---------------- Sinkhorn pieces (unchanged from R0, passed) ----------------
__global__ void bins_fill(float* __restrict__ Z, const float* __restrict__ alpha_p)
{
    float alpha = alpha_p[0];
    int idx = blockIdx.x * 256 + threadIdx.x;
    int b = blockIdx.y;
    float* Zb = Z + (long)b * NP1c * NP1c;
    if (idx < NP1c) Zb[(long)1024 * NP1c + idx] = alpha;
    else { int i = idx - NP1c; if (i < 1024) Zb[(long)i * NP1c + 1024] = alpha; }
}

__global__ void transpose_np1(const float* __restrict__ Z, float* __restrict__ ZT)
{
    __shared__ float tile[32][33];
    int b = blockIdx.z;
    int i0 = blockIdx.y * 32, j0 = blockIdx.x * 32;
    int tx = threadIdx.x, ty = threadIdx.y;
    const float* Zb = Z + (long)b * NP1c * NP1c;
    float* Tb = ZT + (long)b * NP1c * NP1c;
    for (int ii = ty; ii < 32; ii += 8) {
        int i = i0 + ii, j = j0 + tx;
        if (i < NP1c && j < NP1c) tile[ii][tx] = Zb[(long)i * NP1c + j];
    }
    __syncthreads();
    for (int jj = ty; jj < 32; jj += 8) {
        int j = j0 + jj, i = i0 + tx;
        if (j < NP1c && i < NP1c) Tb[(long)j * NP1c + i] = tile[tx][jj];
    }
}

__global__ void zero_vec(float* __restrict__ v, int n)
{
    int i = blockIdx.x * 256 + threadIdx.x;
    if (i < n) v[i] = 0.f;
}

__global__ __launch_bounds__(256) void sinkhorn_lse(
    const float* __restrict__ M, const float* __restrict__ addv, float* __restrict__ outv)
{
    __shared__ float sm[256], ss[256];
    const int i = blockIdx.x, b = blockIdx.y, t = threadIdx.x;
    const float* row = M + ((long)b * NP1c + i) * NP1c;
    const float* av = addv + b * NP1c;
    float m = -1e30f, s = 0.f;
    for (int j = t; j < NP1c; j += 256) {
        float xv = row[j] + av[j];
        if (xv > m) { s = s * __expf(m - xv) + 1.f; m = xv; }
        else s += __expf(xv - m);
    }
    sm[t] = m; ss[t] = s;
    __syncthreads();
    for (int st = 128; st > 0; st >>= 1) {
        if (t < st) {
            float m1 = sm[t], s1 = ss[t], m2 = sm[t + st], s2 = ss[t + st];
            float mm = fmaxf(m1, m2);
            sm[t] = mm;
            ss[t] = s1 * __expf(m1 - mm) + s2 * __expf(m2 - mm);
        }
        __syncthreads();
    }
    if (t == 0) {
        float lse = sm[0] + __logf(ss[0]);
        float lmu = (i < 1024) ? NORMV : (LOGNV + NORMV);
        outv[b * NP1c + i] = lmu - lse;
    }
}

__global__ __launch_bounds__(256) void final_out_k(
    const float* __restrict__ Z, const float* __restrict__ u,
    const float* __restrict__ v, float* __restrict__ outp)
{
    const int i = blockIdx.x, b = blockIdx.y, t = threadIdx.x;
    const float* row = Z + ((long)b * NP1c + i) * NP1c;
    float* orow = outp + ((long)b * NP1c + i) * NP1c;
    float ui = u[b * NP1c + i];
    for (int j = t; j < NP1c; j += 256)
        orow[j] = row[j] + ui + v[b * NP1c + j] - NORMV;
}

// =======================================================================
extern "C" void kernel_launch(void* const* d_in, const int* in_sizes, int n_in,
                              void* d_out, int out_size, void* d_ws, size_t ws_size,
                              hipStream_t stream)
{
    (void)in_sizes; (void)n_in; (void)out_size; (void)ws_size;
    const float* kpts0   = (const float*)d_in[0];
    const float* kpts1   = (const float*)d_in[1];
    const float* scores0 = (const float*)d_in[2];
    const float* scores1 = (const float*)d_in[3];
    const float* desc0   = (const float*)d_in[4];
    const float* desc1   = (const float*)d_in[5];
    const float* kw0 = (const float*)d_in[6];  const float* kb0 = (const float*)d_in[7];
    const float* kg0 = (const float*)d_in[8];  const float* ke0 = (const float*)d_in[9];
    const float* kw1 = (const float*)d_in[10]; const float* kb1 = (const float*)d_in[11];
    const float* kg1 = (const float*)d_in[12]; const float* ke1 = (const float*)d_in[13];
    const float* kw2 = (const float*)d_in[14]; const float* kb2 = (const float*)d_in[15];
    const float* kg2 = (const float*)d_in[16]; const float* ke2 = (const float*)d_in[17];
    const float* kw3 = (const float*)d_in[18]; const float* kb3 = (const float*)d_in[19];
    const float* gnn_proj_w  = (const float*)d_in[20];
    const float* gnn_proj_b  = (const float*)d_in[21];
    const float* gnn_merge_w = (const float*)d_in[22];
    const float* gnn_merge_b = (const float*)d_in[23];
    const float* gnn_mlp1_w  = (const float*)d_in[24];
    const float* gnn_mlp1_b  = (const float*)d_in[25];
    const float* gnn_ln_g    = (const float*)d_in[26];
    const float* gnn_ln_b    = (const float*)d_in[27];
    const float* gnn_mlp2_w  = (const float*)d_in[28];
    const float* gnn_mlp2_b  = (const float*)d_in[29];
    const float* final_w     = (const float*)d_in[30];
    const float* final_b     = (const float*)d_in[31];
    const float* bin_score   = (const float*)d_in[32];

    char* wsb = (char*)d_ws;
    size_t off = 0;
    auto alloc = [&](size_t bytes) -> void* {
        void* p = wsb + off;
        off = (off + bytes + 255) & ~(size_t)255;
        return p;
    };
    typedef __hip_bfloat16 bf;
    const long ROWS = 4L * Nc;               // (dir,b,n) rows = 4096
    // fp32 buffers
    float* descF  = (float*)alloc(ROWS * 256 * 4);            // [dir][b][n][256]
    float* deltaF = (float*)alloc(ROWS * 256 * 4);
    float* ybufF  = (float*)alloc(ROWS * 512 * 4);            // 8 MB (also holds msgpart union below? no: separate)
    float* msgpart= (float*)alloc(4L * Bc * Nc * 256 * 4);    // 8 MB [kc][b][n][256]
    float* Pf     = (float*)alloc(32L * 1024 * 1024);         // 32 MB [b][h][n][m]; union: qkvF, ZT
    float* qkvF   = Pf;                                        // [dir][b][n][768] (12 MB, dead before Pf use)
    float* Zm     = (float*)alloc((long)Bc * NP1c * NP1c * 4);
    float* uvec   = (float*)alloc(Bc * NP1c * 4);
    float* vvec   = (float*)alloc(Bc * NP1c * 4);
    float* projBp = (float*)alloc(9L * 768 * 4);
    // bf16 plane buffers
    bf* catHi = (bf*)alloc(ROWS * 512 * 2);  bf* catLo = (bf*)alloc(ROWS * 512 * 2);
    bf* qkHi  = (bf*)alloc(ROWS * 512 * 2);  bf* qkLo  = (bf*)alloc(ROWS * 512 * 2);
    bf* vTHi  = (bf*)alloc(4L * 256 * Nc * 2); bf* vTLo = (bf*)alloc(4L * 256 * Nc * 2);
    bf* PPHi  = (bf*)alloc(8L * 1024 * 1024 * 2); bf* PPLo = (bf*)alloc(8L * 1024 * 1024 * 2); // 16MB each; union ybufP
    bf* ybHi  = PPHi; bf* ybLo = PPLo;       // ybufP [dir][b][n][512] (4 MB each, reuse PP)
    bf* msgHi = (bf*)alloc(ROWS * 256 * 2);  bf* msgLo = (bf*)alloc(ROWS * 256 * 2);
    bf* mdHi  = (bf*)alloc(ROWS * 256 * 2);  bf* mdLo  = (bf*)alloc(ROWS * 256 * 2);
    // weight planes
    bf* projHi = (bf*)alloc(9L*768*256*2);   bf* projLo = (bf*)alloc(9L*768*256*2);
    bf* mrgHi  = (bf*)alloc(9L*256*256*2);   bf* mrgLo  = (bf*)alloc(9L*256*256*2);
    bf* m1Hi   = (bf*)alloc(9L*512*512*2);   bf* m1Lo   = (bf*)alloc(9L*512*512*2);
    bf* m2Hi   = (bf*)alloc(9L*256*512*2);   bf* m2Lo   = (bf*)alloc(9L*256*512*2);
    bf* finHi  = (bf*)alloc(256L*256*2);     bf* finLo  = (bf*)alloc(256L*256*2);

    // ---- weight conversion (once per call) ----
    wconv_proj<<<dim3((9*768*256+255)/256), 256, 0, stream>>>(gnn_proj_w, projHi, projLo);
    wconv_proj_bias<<<dim3(27), 256, 0, stream>>>(gnn_proj_b, projBp);
    wconv_merge<<<dim3((9*256*256+255)/256), 256, 0, stream>>>(gnn_merge_w, mrgHi, mrgLo);
    wconv_plain<<<dim3((9*512*512+255)/256), 256, 0, stream>>>(gnn_mlp1_w, m1Hi, m1Lo, 9L*512*512);
    wconv_plain<<<dim3((9*256*512+255)/256), 256, 0, stream>>>(gnn_mlp2_w, m2Hi, m2Lo, 9L*256*512);
    wconv_plain<<<dim3((256*256+255)/256), 256, 0, stream>>>(final_w, finHi, finLo, 256L*256);

    // ---- keypoint encoder -> descF (n-major), both dirs ----
    kenc_kernel<<<dim3(Nc, Bc), 256, 0, stream>>>(kpts0, scores0, desc0, descF,
        kw0, kb0, kg0, ke0, kw1, kb1, kg1, ke1, kw2, kb2, kg2, ke2, kw3, kb3);
    kenc_kernel<<<dim3(Nc, Bc), 256, 0, stream>>>(kpts1, scores1, desc1, descF + 2L*Nc*256,
        kw0, kb0, kg0, ke0, kw1, kb1, kg1, ke1, kw2, kb2, kg2, ke2, kw3, kb3);
    // descF -> catbuf planes (cols 0..255 of 512)
    rows_to_planes<<<dim3((unsigned)((ROWS*256+255)/256)), 256, 0, stream>>>(
        descF, 256, 256, catHi, catLo, 512, ROWS * 256);

    const long dirCat = 2L * Nc * 512;   // catbuf/qk dir stride (elements)
    const long bCat   = (long)Nc * 512;

    // ---- GNN layers ----
    for (int l = 0; l < 9; ++l) {
        // 1) qkv GEMM: A=catbuf(cols0..255) B=projP -> qkvF [dir][b][n][768]
        mfma_nt<128,128,0><<<dim3(6,8,4), 256, 0, stream>>>(
            (const short*)catHi, (const short*)catLo, 512,
            (const short*)(projHi + (long)l*768*256), (const short*)(projLo + (long)l*768*256), 256,
            256, 1.f, projBp + (long)l*768,
            qkvF, nullptr, nullptr, 768,
            2, 1,
            dirCat, bCat, 0,  0, 0, 0,
            2L*Nc*768, (long)Nc*768, 0);
        // 2) converts: q/k cols -> qk planes ; v cols -> vT planes
        rows_to_planes<<<dim3((unsigned)((ROWS*512+255)/256)), 256, 0, stream>>>(
            qkvF, 768, 512, qkHi, qkLo, 512, ROWS * 512);
        vT_convert<<<dim3(16,4,4), 256, 0, stream>>>(qkvF, vTHi, vTLo);

        // 3) attention per direction
        for (int d = 0; d < 2; ++d) {
            const long aQ = (long)d * dirCat;           // q planes of dir d
            const long bK = (long)(1-d) * dirCat + 256; // k planes of other dir
            // scores: z=(b,h)
            mfma_nt<128,128,0><<<dim3(8,8,8), 256, 0, stream>>>(
                (const short*)qkHi + aQ, (const short*)qkLo + aQ, 512,
                (const short*)qkHi + bK, (const short*)qkLo + bK, 512,
                64, 0.125f, nullptr,
                Pf, nullptr, nullptr, 1024,
                4, 1,
                bCat, 64, 0,  bCat, 64, 0,
                4L*1024*1024, 1024L*1024, 0);
            softmax_planes<<<dim3(Nc, 8), 256, 0, stream>>>(Pf, PPHi, PPLo);
            // PV: z=(kc,b,h), split K=1024 into 4x256; B = vT of src dir (1-d)
            const long vOff = (long)(1-d) * 2 * 256 * Nc;
            mfma_nt<128,64,0><<<dim3(1,8,32), 256, 0, stream>>>(
                (const short*)PPHi, (const short*)PPLo, 1024,
                (const short*)vTHi + vOff, (const short*)vTLo + vOff, 1024,
                256, 1.f, nullptr,
                msgpart, nullptr, nullptr, 256,
                2, 4,
                256, 4L*1024*1024, 1024L*1024,
                256, 256L*1024, 64L*1024,
                2L*1024*256, 1024L*256, 64);
            pv_reduce_planes<<<dim3((unsigned)((2L*Nc*256+255)/256)), 256, 0, stream>>>(
                msgpart, msgHi + (long)d*2*Nc*256, msgLo + (long)d*2*Nc*256);
        }

        // 4) merge GEMM -> catbuf planes cols 256..511 (both dirs, z=(dir,b))
        mfma_nt<128,128,1><<<dim3(2,8,4), 256, 0, stream>>>(
            (const short*)msgHi, (const short*)msgLo, 256,
            (const short*)(mrgHi + (long)l*256*256), (const short*)(mrgLo + (long)l*256*256), 256,
            256, 1.f, gnn_merge_b + (long)l*256,
            nullptr, catHi + 256, catLo + 256, 512,
            2, 1,
            2L*Nc*256, (long)Nc*256, 0,  0, 0, 0,
            dirCat, bCat, 0);
        // 5) mlp1 -> ybufF fp32
        mfma_nt<128,128,0><<<dim3(4,8,4), 256, 0, stream>>>(
            (const short*)catHi, (const short*)catLo, 512,
            (const short*)(m1Hi + (long)l*512*512), (const short*)(m1Lo + (long)l*512*512), 512,
            512, 1.f, gnn_mlp1_b + (long)l*512,
            ybufF, nullptr, nullptr, 512,
            2, 1,
            dirCat, bCat, 0,  0, 0, 0,
            2L*Nc*512, (long)Nc*512, 0);
        // 6) LN+ReLU -> ybuf planes
        ln_relu_planes<<<dim3((unsigned)ROWS), 256, 0, stream>>>(
            ybufF, gnn_ln_g + (long)l*512, gnn_ln_b + (long)l*512, ybHi, ybLo);
        // 7) mlp2 -> deltaF
        mfma_nt<128,128,0><<<dim3(2,8,4), 256, 0, stream>>>(
            (const short*)ybHi, (const short*)ybLo, 512,
            (const short*)(m2Hi + (long)l*256*512), (const short*)(m2Lo + (long)l*256*512), 512,
            512, 1.f, gnn_mlp2_b + (long)l*256,
            deltaF, nullptr, nullptr, 256,
            2, 1,
            2L*Nc*512, (long)Nc*512, 0,  0, 0, 0,
            2L*Nc*256, (long)Nc*256, 0);
        // 8) residual + refresh catbuf planes
        resid_convert<<<dim3((unsigned)((ROWS*256+255)/256)), 256, 0, stream>>>(
            descF, deltaF, catHi, catLo);
    }

    // ---- final projection -> mdesc planes ----
    mfma_nt<128,128,1><<<dim3(2,8,4), 256, 0, stream>>>(
        (const short*)catHi, (const short*)catLo, 512,
        (const short*)finHi, (const short*)finLo, 256,
        256, 1.f, final_b,
        nullptr, mdHi, mdLo, 256,
        2, 1,
        dirCat, bCat, 0,  0, 0, 0,
        2L*Nc*256, (long)Nc*256, 0);
    // ---- score matrix into Z (rows/cols 0..1023, ldo=1025) ----
    mfma_nt<128,128,0><<<dim3(8,8,2), 256, 0, stream>>>(
        (const short*)mdHi, (const short*)mdLo, 256,
        (const short*)mdHi + 2L*Nc*256, (const short*)mdLo + 2L*Nc*256, 256,
        256, 1.f/16.f, nullptr,
        Zm, nullptr, nullptr, NP1c,
        1, 1,
        (long)Nc*256, 0, 0,  (long)Nc*256, 0, 0,
        (long)NP1c*NP1c, 0, 0);
    bins_fill<<<dim3(9,2), 256, 0, stream>>>(Zm, bin_score);

    // ---- Sinkhorn (log-space), 20 iterations ----
    float* ZT = Pf; // reuse 32MB region (qkvF/Pf dead now)
    transpose_np1<<<dim3(33,33,2), dim3(32,8), 0, stream>>>(Zm, ZT);
    zero_vec<<<dim3(9), 256, 0, stream>>>(vvec, Bc * NP1c);
    for (int it = 0; it < 20; ++it) {
        sinkhorn_lse<<<dim3(NP1c, Bc), 256, 0, stream>>>(Zm, vvec, uvec);
        sinkhorn_lse<<<dim3(NP1c, Bc), 256, 0, stream>>>(ZT, uvec, vvec);
    }
    final_out_k<<<dim3(NP1c, Bc), 256, 0, stream>>>(Zm, uvec, vvec, (float*)d_out);
}

// Round 4
// 2534.884 us; speedup vs baseline: 2.3115x; 1.2836x over previous
//
#include <hip/hip_runtime.h>
#include <hip/hip_bf16.h>
#include <math.h>

#define DEVI static __device__ __forceinline__

namespace {
constexpr int Bc   = 2;
constexpr int Nc   = 1024;
constexpr int Dc   = 256;
constexpr int NP1c = 1025;
constexpr float LN_EPS = 1e-6f;
constexpr float NORMV  = -7.6246189861593985f; // -log(2048)
constexpr float LOGNV  =  6.9314718055994531f; // log(1024)
}

typedef __attribute__((ext_vector_type(8))) short bf16x8;
typedef __attribute__((ext_vector_type(4))) float f32x4;

DEVI void split2(float v, __hip_bfloat16& h, __hip_bfloat16& l) {
    h = __float2bfloat16(v);
    l = __float2bfloat16(v - __bfloat162float(h));
}

// async global->LDS, 16B per lane: lds dest = base + lane*16 (HW), global src per-lane
#define GLDS16(gp, lp) __builtin_amdgcn_global_load_lds( \
    (const __attribute__((address_space(1))) void*)(gp), \
    (__attribute__((address_space(3))) void*)(lp), 16, 0, 0)

// ---------------- helpers ----------------
DEVI float block_sum_256(float v, float* scratch) {
    int t = threadIdx.x;
    scratch[t] = v;
    __syncthreads();
    for (int s = 128; s > 0; s >>= 1) {
        if (t < s) scratch[t] += scratch[t + s];
        __syncthreads();
    }
    float r = scratch[0];
    __syncthreads();
    return r;
}

DEVI void ln_relu_inplace(float* x, const float* g, const float* be, int C, float* scratch) {
    int t = threadIdx.x;
    float v = (t < C) ? x[t] : 0.f;
    float mean = block_sum_256(v, scratch) / (float)C;
    float dv = (t < C) ? (x[t] - mean) : 0.f;
    float var = block_sum_256(dv * dv, scratch) / (float)(C - 1);
    float rstd = 1.f / (sqrtf(var) + LN_EPS);
    if (t < C) x[t] = fmaxf(g[t] * dv * rstd + be[t], 0.f);
    __syncthreads();
}

// ---------------- keypoint encoder: one block per (n,b) position; n-major out ----------------
__global__ __launch_bounds__(256) void kenc_kernel(
    const float* __restrict__ kpts, const float* __restrict__ scr,
    const float* __restrict__ desc_in, float* __restrict__ desc_out,
    const float* __restrict__ w0, const float* __restrict__ b0,
    const float* __restrict__ g0, const float* __restrict__ be0,
    const float* __restrict__ w1, const float* __restrict__ b1,
    const float* __restrict__ g1, const float* __restrict__ be1,
    const float* __restrict__ w2, const float* __restrict__ b2,
    const float* __restrict__ g2, const float* __restrict__ be2,
    const float* __restrict__ w3, const float* __restrict__ b3)
{
    __shared__ float xa[256], xb[256], scratch[256];
    const int n = blockIdx.x, b = blockIdx.y, t = threadIdx.x;
    if (t == 0) {
        float kx = kpts[((long)b * Nc + n) * 2 + 0];
        float ky = kpts[((long)b * Nc + n) * 2 + 1];
        xa[0] = (kx - 320.f) * (1.f / 448.f);
        xa[1] = (ky - 240.f) * (1.f / 448.f);
        xa[2] = scr[b * Nc + n];
    }
    __syncthreads();
    if (t < 32) { float a = b0[t]; for (int c = 0; c < 3;   ++c) a += w0[t*3   + c] * xa[c]; xb[t] = a; }
    __syncthreads();
    ln_relu_inplace(xb, g0, be0, 32, scratch);
    if (t < 64) { float a = b1[t]; for (int c = 0; c < 32;  ++c) a += w1[t*32  + c] * xb[c]; xa[t] = a; }
    __syncthreads();
    ln_relu_inplace(xa, g1, be1, 64, scratch);
    if (t < 128){ float a = b2[t]; for (int c = 0; c < 64;  ++c) a += w2[t*64  + c] * xa[c]; xb[t] = a; }
    __syncthreads();
    ln_relu_inplace(xb, g2, be2, 128, scratch);
    {   float a = b3[t]; for (int c = 0; c < 128; ++c) a += w3[t*128 + c] * xb[c];
        desc_out[((long)b * Nc + n) * Dc + t] = desc_in[((long)b * Dc + t) * Nc + n] + a; }
}

// =======================================================================
// MFMA NT GEMM, hi/lo split: out[m][n] = scale * sum_k A[m][k]*B[n][k] (+bias[n])
// EPI: 0 = fp32 out; 1 = bf16 hi/lo planes out; 2 = qkv special (qk planes + vT planes)
// =======================================================================
template<int BM, int BN, int EPI>
__global__ __launch_bounds__(256) void mfma_nt(
    const short* __restrict__ Ahi0, const short* __restrict__ Alo0, int lda,
    const short* __restrict__ Bhi0, const short* __restrict__ Blo0, int ldb,
    int K, float scale, const float* __restrict__ bias,
    float* __restrict__ outF, __hip_bfloat16* __restrict__ outHi,
    __hip_bfloat16* __restrict__ outLo,
    __hip_bfloat16* __restrict__ outHi2, __hip_bfloat16* __restrict__ outLo2,
    int ldo,
    int nz2, int nz3,
    long aS1, long aS2, long aS3,
    long bS1, long bS2, long bS3,
    long oS1, long oS2, long oS3)
{
    constexpr int MI = BM / 32;
    constexpr int NI = BN / 32;
    constexpr int instA = BM / 16, instB = BN / 16;
    constexpr int OFF_AH = 0;
    constexpr int OFF_AL = BM * 32;
    constexpr int OFF_BH = 2 * BM * 32;
    constexpr int OFF_BL = 2 * BM * 32 + BN * 32;
    __shared__ short smem[(2 * BM + 2 * BN) * 32];

    const int z = blockIdx.z;
    const int i1 = z / (nz2 * nz3);
    const int i2 = (z % (nz2 * nz3)) / nz3;
    const int i3 = z % nz3;
    const long aOff = i1 * aS1 + i2 * aS2 + i3 * aS3;
    const long bOff = i1 * bS1 + i2 * bS2 + i3 * bS3;
    const long oOff = i1 * oS1 + i2 * oS2 + i3 * oS3;
    const short* Ah = Ahi0 + aOff; const short* Al = Alo0 + aOff;
    const short* Bh = Bhi0 + bOff; const short* Bl = Blo0 + bOff;

    const int m0 = blockIdx.y * BM, n0 = blockIdx.x * BN;
    const int t = threadIdx.x, lane = t & 63, wid = t >> 6;
    const int lr = lane & 15, lg = lane >> 4;
    const int wr = wid >> 1, wc = wid & 1;

    f32x4 acc[MI][NI];
    for (int mi = 0; mi < MI; ++mi)
        for (int ni = 0; ni < NI; ++ni)
            acc[mi][ni] = f32x4{0.f, 0.f, 0.f, 0.f};

    for (int k0 = 0; k0 < K; k0 += 32) {
        // ---- stage: async global->LDS in fragment order ----
        constexpr int total = 2 * instA + 2 * instB;
        for (int q = wid; q < total; q += 4) {
            const short* gsrc; int ldg, mi, ploff, row0;
            if (q < instA)               { gsrc = Ah; ldg = lda; mi = q;                 ploff = OFF_AH; row0 = m0; }
            else if (q < 2*instA)        { gsrc = Al; ldg = lda; mi = q - instA;         ploff = OFF_AL; row0 = m0; }
            else if (q < 2*instA+instB)  { gsrc = Bh; ldg = ldb; mi = q - 2*instA;       ploff = OFF_BH; row0 = n0; }
            else                         { gsrc = Bl; ldg = ldb; mi = q - 2*instA-instB; ploff = OFF_BL; row0 = n0; }
            const short* g = gsrc + (long)(row0 + mi * 16 + lr) * ldg + (k0 + lg * 8);
            GLDS16(g, smem + ploff + mi * 512);
        }
        __syncthreads();
        // ---- compute ----
        bf16x8 ah[MI], al[MI];
        #pragma unroll
        for (int mi = 0; mi < MI; ++mi) {
            ah[mi] = *(const bf16x8*)(smem + OFF_AH + ((wr * MI + mi) * 64 + lane) * 8);
            al[mi] = *(const bf16x8*)(smem + OFF_AL + ((wr * MI + mi) * 64 + lane) * 8);
        }
        #pragma unroll
        for (int ni = 0; ni < NI; ++ni) {
            bf16x8 bh = *(const bf16x8*)(smem + OFF_BH + ((wc * NI + ni) * 64 + lane) * 8);
            bf16x8 bl = *(const bf16x8*)(smem + OFF_BL + ((wc * NI + ni) * 64 + lane) * 8);
            #pragma unroll
            for (int mi = 0; mi < MI; ++mi) {
                acc[mi][ni] = __builtin_amdgcn_mfma_f32_16x16x32_bf16(ah[mi], bh, acc[mi][ni], 0, 0, 0);
                acc[mi][ni] = __builtin_amdgcn_mfma_f32_16x16x32_bf16(ah[mi], bl, acc[mi][ni], 0, 0, 0);
                acc[mi][ni] = __builtin_amdgcn_mfma_f32_16x16x32_bf16(al[mi], bh, acc[mi][ni], 0, 0, 0);
            }
        }
        __syncthreads();
    }

    // ---- epilogue ----
    for (int mi = 0; mi < MI; ++mi) {
        for (int i = 0; i < 4; ++i) {
            int row = m0 + wr * (BM / 2) + mi * 16 + lg * 4 + i;
            for (int ni = 0; ni < NI; ++ni) {
                int col = n0 + wc * (BN / 2) + ni * 16 + lr;
                float v = acc[mi][ni][i] * scale;
                if (bias) v += bias[col];
                if (EPI == 0) {
                    outF[(long)row * ldo + col + oOff] = v;
                } else if (EPI == 1) {
                    __hip_bfloat16 h, l;
                    split2(v, h, l);
                    outHi[(long)row * ldo + col + oOff] = h;
                    outLo[(long)row * ldo + col + oOff] = l;
                } else {
                    // qkv: z = dirb; cols 0..511 -> qk planes [dirb*1024+row][512];
                    //            cols 512..767 -> vT planes [dirb*256 + (col-512)][row]
                    int dirb = z;
                    __hip_bfloat16 h, l;
                    split2(v, h, l);
                    if (col < 512) {
                        long a = ((long)dirb * 1024 + row) * 512 + col;
                        outHi[a] = h; outLo[a] = l;
                    } else {
                        long a = ((long)dirb * 256 + (col - 512)) * 1024 + row;
                        outHi2[a] = h; outLo2[a] = l;
                    }
                }
            }
        }
    }
}

// =======================================================================
// Fused scores + softmax: S = q(dir)·k(1-dir)^T / 8 per (dir,b,h), row softmax,
// write P hi/lo planes [dir][b][h][q][n]. Block: 16 q-rows, wave w owns cols w*256..+255.
// =======================================================================
__global__ __launch_bounds__(256) void attn_scores_softmax(
    const __hip_bfloat16* __restrict__ qkHi, const __hip_bfloat16* __restrict__ qkLo,
    __hip_bfloat16* __restrict__ pHi, __hip_bfloat16* __restrict__ pLo)
{
    __shared__ float redm[4][16], reds[4][16];
    const int y = blockIdx.y;
    const int dir = y >> 3, b = (y >> 2) & 1, h = y & 3;
    const int q0 = blockIdx.x * 16;
    const int t = threadIdx.x, lane = t & 63, w = t >> 6;
    const int lr = lane & 15, lg = lane >> 4;
    const short* qh = (const short*)qkHi;
    const short* ql = (const short*)qkLo;
    const long R0 = (long)dir * 2048 + (long)b * 1024 + q0;
    const long KB = (long)(1 - dir) * 2048 + (long)b * 1024 + w * 256;

    bf16x8 ah[2], al[2];
    #pragma unroll
    for (int kc = 0; kc < 2; ++kc) {
        long a = (R0 + lr) * 512 + h * 64 + kc * 32 + lg * 8;
        ah[kc] = *(const bf16x8*)(qh + a);
        al[kc] = *(const bf16x8*)(ql + a);
    }

    f32x4 acc[16];
    #pragma unroll
    for (int ni = 0; ni < 16; ++ni) acc[ni] = f32x4{0.f, 0.f, 0.f, 0.f};

    #pragma unroll
    for (int ni = 0; ni < 16; ++ni) {
        long kr = (KB + ni * 16 + lr) * 512 + 256 + h * 64 + lg * 8;
        bf16x8 bh0 = *(const bf16x8*)(qh + kr);
        bf16x8 bl0 = *(const bf16x8*)(ql + kr);
        bf16x8 bh1 = *(const bf16x8*)(qh + kr + 32);
        bf16x8 bl1 = *(const bf16x8*)(ql + kr + 32);
        acc[ni] = __builtin_amdgcn_mfma_f32_16x16x32_bf16(ah[0], bh0, acc[ni], 0, 0, 0);
        acc[ni] = __builtin_amdgcn_mfma_f32_16x16x32_bf16(ah[0], bl0, acc[ni], 0, 0, 0);
        acc[ni] = __builtin_amdgcn_mfma_f32_16x16x32_bf16(al[0], bh0, acc[ni], 0, 0, 0);
        acc[ni] = __builtin_amdgcn_mfma_f32_16x16x32_bf16(ah[1], bh1, acc[ni], 0, 0, 0);
        acc[ni] = __builtin_amdgcn_mfma_f32_16x16x32_bf16(ah[1], bl1, acc[ni], 0, 0, 0);
        acc[ni] = __builtin_amdgcn_mfma_f32_16x16x32_bf16(al[1], bh1, acc[ni], 0, 0, 0);
    }

    // scale + per-lane row max (lane holds rows lg*4+i, cols ni*16+lr)
    float mx[4] = {-1e30f, -1e30f, -1e30f, -1e30f};
    #pragma unroll
    for (int ni = 0; ni < 16; ++ni) {
        #pragma unroll
        for (int i = 0; i < 4; ++i) {
            float v = acc[ni][i] * 0.125f;
            acc[ni][i] = v;
            mx[i] = fmaxf(mx[i], v);
        }
    }
    #pragma unroll
    for (int off = 1; off < 16; off <<= 1) {
        #pragma unroll
        for (int i = 0; i < 4; ++i) mx[i] = fmaxf(mx[i], __shfl_xor(mx[i], off));
    }
    if (lr == 0) {
        #pragma unroll
        for (int i = 0; i < 4; ++i) redm[w][lg * 4 + i] = mx[i];
    }
    __syncthreads();
    float Mv[4];
    #pragma unroll
    for (int i = 0; i < 4; ++i)
        Mv[i] = fmaxf(fmaxf(redm[0][lg*4+i], redm[1][lg*4+i]),
                      fmaxf(redm[2][lg*4+i], redm[3][lg*4+i]));
    float sm[4] = {0.f, 0.f, 0.f, 0.f};
    #pragma unroll
    for (int ni = 0; ni < 16; ++ni) {
        #pragma unroll
        for (int i = 0; i < 4; ++i) {
            float e = __expf(acc[ni][i] - Mv[i]);
            acc[ni][i] = e;
            sm[i] += e;
        }
    }
    #pragma unroll
    for (int off = 1; off < 16; off <<= 1) {
        #pragma unroll
        for (int i = 0; i < 4; ++i) sm[i] += __shfl_xor(sm[i], off);
    }
    if (lr == 0) {
        #pragma unroll
        for (int i = 0; i < 4; ++i) reds[w][lg * 4 + i] = sm[i];
    }
    __syncthreads();
    float inv[4];
    #pragma unroll
    for (int i = 0; i < 4; ++i)
        inv[i] = 1.f / (reds[0][lg*4+i] + reds[1][lg*4+i] + reds[2][lg*4+i] + reds[3][lg*4+i]);

    const long pbase = ((((long)dir * 2 + b) * 4 + h) << 20);
    #pragma unroll
    for (int ni = 0; ni < 16; ++ni) {
        #pragma unroll
        for (int i = 0; i < 4; ++i) {
            long a = pbase + (long)(q0 + lg * 4 + i) * 1024 + w * 256 + ni * 16 + lr;
            __hip_bfloat16 hh, ll;
            split2(acc[ni][i] * inv[i], hh, ll);
            pHi[a] = hh; pLo[a] = ll;
        }
    }
}

// ---------------- fp32 rows -> bf16 hi/lo planes ----------------
__global__ __launch_bounds__(256) void rows_to_planes(
    const float* __restrict__ src, int ldsrc, int C,
    __hip_bfloat16* __restrict__ hi, __hip_bfloat16* __restrict__ lo, int ldp, long total)
{
    long idx = (long)blockIdx.x * 256 + threadIdx.x;
    if (idx >= total) return;
    long row = idx / C; int c = (int)(idx % C);
    float v = src[row * ldsrc + c];
    __hip_bfloat16 h, l; split2(v, h, l);
    hi[row * ldp + c] = h; lo[row * ldp + c] = l;
}

// ---------------- PV split-K reduce -> msg planes ----------------
__global__ __launch_bounds__(256) void pv_reduce_planes(
    const float* __restrict__ part, __hip_bfloat16* __restrict__ hi, __hip_bfloat16* __restrict__ lo)
{
    const long CH = (long)Bc * Nc * Dc; // 524288
    long i = (long)blockIdx.x * 256 + threadIdx.x;
    if (i >= CH) return;
    float v = part[i] + part[CH + i] + part[2 * CH + i] + part[3 * CH + i];
    __hip_bfloat16 h, l; split2(v, h, l);
    hi[i] = h; lo[i] = l;
}

// ---------------- LN(channel,ddof=1,eps-on-std)+ReLU; write planes ----------------
__global__ __launch_bounds__(256) void ln_relu_planes(
    const float* __restrict__ y, const float* __restrict__ g, const float* __restrict__ be,
    __hip_bfloat16* __restrict__ hi, __hip_bfloat16* __restrict__ lo)
{
    __shared__ float s1[256], s2[256];
    const long row = blockIdx.x;
    const int t = threadIdx.x;
    const float* src = y + row * 512;
    float a = src[t], b = src[t + 256];
    s1[t] = a + b; s2[t] = a * a + b * b;
    __syncthreads();
    for (int s = 128; s > 0; s >>= 1) {
        if (t < s) { s1[t] += s1[t + s]; s2[t] += s2[t + s]; }
        __syncthreads();
    }
    float mean = s1[0] / 512.f;
    float var = fmaxf((s2[0] - 512.f * mean * mean) / 511.f, 0.f);
    float rstd = 1.f / (sqrtf(var) + LN_EPS);
    float v1 = fmaxf(g[t] * (a - mean) * rstd + be[t], 0.f);
    float v2 = fmaxf(g[t + 256] * (b - mean) * rstd + be[t + 256], 0.f);
    __hip_bfloat16 h, l;
    split2(v1, h, l); hi[row * 512 + t] = h;       lo[row * 512 + t] = l;
    split2(v2, h, l); hi[row * 512 + t + 256] = h; lo[row * 512 + t + 256] = l;
}

// ---------------- residual add + refresh catbuf planes ----------------
__global__ __launch_bounds__(256) void resid_convert(
    float* __restrict__ descF, const float* __restrict__ delta,
    __hip_bfloat16* __restrict__ hi, __hip_bfloat16* __restrict__ lo)
{
    long i = (long)blockIdx.x * 256 + threadIdx.x;
    float v = descF[i] + delta[i];
    descF[i] = v;
    long row = i >> 8; int c = (int)(i & 255);
    __hip_bfloat16 h, l; split2(v, h, l);
    hi[row * 512 + c] = h; lo[row * 512 + c] = l;
}

// ---------------- weight converts ----------------
__global__ __launch_bounds__(256) void wconv_plain(
    const float* __restrict__ w, __hip_bfloat16* __restrict__ hi, __hip_bfloat16* __restrict__ lo, long total)
{
    long i = (long)blockIdx.x * 256 + threadIdx.x;
    if (i >= total) return;
    __hip_bfloat16 h, l; split2(w[i], h, l);
    hi[i] = h; lo[i] = l;
}

__global__ __launch_bounds__(256) void wconv_proj(
    const float* __restrict__ w, __hip_bfloat16* __restrict__ hi, __hip_bfloat16* __restrict__ lo)
{
    long i = (long)blockIdx.x * 256 + threadIdx.x;
    if (i >= 9L * 768 * 256) return;
    long l9 = i / (768 * 256);
    int rem = (int)(i % (768 * 256));
    int op = rem / 256, c = rem % 256;
    int tq = op / 256, within = op % 256;
    int h = within / 64, hd = within % 64;
    int o = tq * 256 + hd * 4 + h;
    float v = w[(l9 * 768 + o) * 256 + c];
    __hip_bfloat16 hh, ll; split2(v, hh, ll);
    hi[i] = hh; lo[i] = ll;
}

__global__ void wconv_proj_bias(const float* __restrict__ b, float* __restrict__ bp)
{
    int i = blockIdx.x * 256 + threadIdx.x;
    if (i >= 9 * 768) return;
    int l9 = i / 768, op = i % 768;
    int tq = op / 256, within = op % 256;
    int h = within / 64, hd = within % 64;
    bp[i] = b[(l9 * 3 + tq) * 256 + hd * 4 + h];
}

__global__ __launch_bounds__(256) void wconv_merge(
    const float* __restrict__ w, __hip_bfloat16* __restrict__ hi, __hip_bfloat16* __restrict__ lo)
{
    long i = (long)blockIdx.x * 256 + threadIdx.x;
    if (i >= 9L * 256 * 256) return;
    long l9 = i / (256 * 256);
    int rem = (int)(i % (256 * 256));
    int o = rem / 256, cp = rem % 256;
    int h = cp / 64, hd = cp % 64;
    float v = w[(l9 * 256 + o) * 256 + hd * 4 + h];
    __hip_bfloat16 hh, ll; split2(v, hh, ll);
    hi[i] = hh; lo[i] = ll;
}

// ---------------- Sinkhorn pieces ----------------
__global__ void bins_fill(float* __restrict__ Z, const float* __restrict__ alpha_p)
{
    float alpha = alpha_p[0];
    int idx = blockIdx.x * 256 + threadIdx.x;
    int b = blockIdx.y;
    float* Zb = Z + (long)b * NP1c * NP1c;
    if (idx < NP1c) Zb[(long)1024 * NP1c + idx] = alpha;
    else { int i = idx - NP1c; if (i < 1024) Zb[(long)i * NP1c + 1024] = alpha; }
}

__global__ void transpose_np1(const float* __restrict__ Z, float* __restrict__ ZT)
{
    __shared__ float tile[32][33];
    int b = blockIdx.z;
    int i0 = blockIdx.y * 32, j0 = blockIdx.x * 32;
    int tx = threadIdx.x, ty = threadIdx.y;
    const float* Zb = Z + (long)b * NP1c * NP1c;
    float* Tb = ZT + (long)b * NP1c * NP1c;
    for (int ii = ty; ii < 32; ii += 8) {
        int i = i0 + ii, j = j0 + tx;
        if (i < NP1c && j < NP1c) tile[ii][tx] = Zb[(long)i * NP1c + j];
    }
    __syncthreads();
    for (int jj = ty; jj < 32; jj += 8) {
        int j = j0 + jj, i = i0 + tx;
        if (j < NP1c && i < NP1c) Tb[(long)j * NP1c + i] = tile[tx][jj];
    }
}

__global__ void zero_vec(float* __restrict__ v, int n)
{
    int i = blockIdx.x * 256 + threadIdx.x;
    if (i < n) v[i] = 0.f;
}

__global__ __launch_bounds__(256) void sinkhorn_lse(
    const float* __restrict__ M, const float* __restrict__ addv, float* __restrict__ outv)
{
    __shared__ float sm[256], ss[256];
    const int i = blockIdx.x, b = blockIdx.y, t = threadIdx.x;
    const float* row = M + ((long)b * NP1c + i) * NP1c;
    const float* av = addv + b * NP1c;
    float m = -1e30f, s = 0.f;
    for (int j = t; j < NP1c; j += 256) {
        float xv = row[j] + av[j];
        if (xv > m) { s = s * __expf(m - xv) + 1.f; m = xv; }
        else s += __expf(xv - m);
    }
    sm[t] = m; ss[t] = s;
    __syncthreads();
    for (int st = 128; st > 0; st >>= 1) {
        if (t < st) {
            float m1 = sm[t], s1 = ss[t], m2 = sm[t + st], s2 = ss[t + st];
            float mm = fmaxf(m1, m2);
            sm[t] = mm;
            ss[t] = s1 * __expf(m1 - mm) + s2 * __expf(m2 - mm);
        }
        __syncthreads();
    }
    if (t == 0) {
        float lse = sm[0] + __logf(ss[0]);
        float lmu = (i < 1024) ? NORMV : (LOGNV + NORMV);
        outv[b * NP1c + i] = lmu - lse;
    }
}

__global__ __launch_bounds__(256) void final_out_k(
    const float* __restrict__ Z, const float* __restrict__ u,
    const float* __restrict__ v, float* __restrict__ outp)
{
    const int i = blockIdx.x, b = blockIdx.y, t = threadIdx.x;
    const float* row = Z + ((long)b * NP1c + i) * NP1c;
    float* orow = outp + ((long)b * NP1c + i) * NP1c;
    float ui = u[b * NP1c + i];
    for (int j = t; j < NP1c; j += 256)
        orow[j] = row[j] + ui + v[b * NP1c + j] - NORMV;
}

// =======================================================================
extern "C" void kernel_launch(void* const* d_in, const int* in_sizes, int n_in,
                              void* d_out, int out_size, void* d_ws, size_t ws_size,
                              hipStream_t stream)
{
    (void)in_sizes; (void)n_in; (void)out_size; (void)ws_size;
    const float* kpts0   = (const float*)d_in[0];
    const float* kpts1   = (const float*)d_in[1];
    const float* scores0 = (const float*)d_in[2];
    const float* scores1 = (const float*)d_in[3];
    const float* desc0   = (const float*)d_in[4];
    const float* desc1   = (const float*)d_in[5];
    const float* kw0 = (const float*)d_in[6];  const float* kb0 = (const float*)d_in[7];
    const float* kg0 = (const float*)d_in[8];  const float* ke0 = (const float*)d_in[9];
    const float* kw1 = (const float*)d_in[10]; const float* kb1 = (const float*)d_in[11];
    const float* kg1 = (const float*)d_in[12]; const float* ke1 = (const float*)d_in[13];
    const float* kw2 = (const float*)d_in[14]; const float* kb2 = (const float*)d_in[15];
    const float* kg2 = (const float*)d_in[16]; const float* ke2 = (const float*)d_in[17];
    const float* kw3 = (const float*)d_in[18]; const float* kb3 = (const float*)d_in[19];
    const float* gnn_proj_w  = (const float*)d_in[20];
    const float* gnn_proj_b  = (const float*)d_in[21];
    const float* gnn_merge_w = (const float*)d_in[22];
    const float* gnn_merge_b = (const float*)d_in[23];
    const float* gnn_mlp1_w  = (const float*)d_in[24];
    const float* gnn_mlp1_b  = (const float*)d_in[25];
    const float* gnn_ln_g    = (const float*)d_in[26];
    const float* gnn_ln_b    = (const float*)d_in[27];
    const float* gnn_mlp2_w  = (const float*)d_in[28];
    const float* gnn_mlp2_b  = (const float*)d_in[29];
    const float* final_w     = (const float*)d_in[30];
    const float* final_b     = (const float*)d_in[31];
    const float* bin_score   = (const float*)d_in[32];

    char* wsb = (char*)d_ws;
    size_t off = 0;
    auto alloc = [&](size_t bytes) -> void* {
        void* p = wsb + off;
        off = (off + bytes + 255) & ~(size_t)255;
        return p;
    };
    typedef __hip_bfloat16 bf;
    const long ROWS = 4L * Nc;               // (dir,b,n) rows = 4096
    // fp32 buffers
    float* descF  = (float*)alloc(ROWS * 256 * 4);
    float* deltaF = (float*)alloc(ROWS * 256 * 4);
    float* ybufF  = (float*)alloc(ROWS * 512 * 4);
    float* msgpart= (float*)alloc(4L * Bc * Nc * 256 * 4);
    float* Zm     = (float*)alloc((long)Bc * NP1c * NP1c * 4);
    float* uvec   = (float*)alloc(Bc * NP1c * 4);
    float* vvec   = (float*)alloc(Bc * NP1c * 4);
    float* projBp = (float*)alloc(9L * 768 * 4);
    // bf16 plane buffers
    bf* catHi = (bf*)alloc(ROWS * 512 * 2);  bf* catLo = (bf*)alloc(ROWS * 512 * 2);
    bf* qkHi  = (bf*)alloc(ROWS * 512 * 2);  bf* qkLo  = (bf*)alloc(ROWS * 512 * 2);
    bf* vTHi  = (bf*)alloc(4L * 256 * Nc * 2); bf* vTLo = (bf*)alloc(4L * 256 * Nc * 2);
    bf* PPHi  = (bf*)alloc(16L * 1024 * 1024 * 2); // [dir][b][h][q][n] 32MB
    bf* PPLo  = (bf*)alloc(16L * 1024 * 1024 * 2);
    bf* ybHi  = PPHi; bf* ybLo = PPLo;       // ybuf planes alias (P dead by mlp1)
    bf* msgHi = (bf*)alloc(ROWS * 256 * 2);  bf* msgLo = (bf*)alloc(ROWS * 256 * 2);
    bf* mdHi  = (bf*)alloc(ROWS * 256 * 2);  bf* mdLo  = (bf*)alloc(ROWS * 256 * 2);
    // weight planes
    bf* projHi = (bf*)alloc(9L*768*256*2);   bf* projLo = (bf*)alloc(9L*768*256*2);
    bf* mrgHi  = (bf*)alloc(9L*256*256*2);   bf* mrgLo  = (bf*)alloc(9L*256*256*2);
    bf* m1Hi   = (bf*)alloc(9L*512*512*2);   bf* m1Lo   = (bf*)alloc(9L*512*512*2);
    bf* m2Hi   = (bf*)alloc(9L*256*512*2);   bf* m2Lo   = (bf*)alloc(9L*256*512*2);
    bf* finHi  = (bf*)alloc(256L*256*2);     bf* finLo  = (bf*)alloc(256L*256*2);

    // ---- weight conversion ----
    wconv_proj<<<dim3((9*768*256+255)/256), 256, 0, stream>>>(gnn_proj_w, projHi, projLo);
    wconv_proj_bias<<<dim3(27), 256, 0, stream>>>(gnn_proj_b, projBp);
    wconv_merge<<<dim3((9*256*256+255)/256), 256, 0, stream>>>(gnn_merge_w, mrgHi, mrgLo);
    wconv_plain<<<dim3((9*512*512+255)/256), 256, 0, stream>>>(gnn_mlp1_w, m1Hi, m1Lo, 9L*512*512);
    wconv_plain<<<dim3((9*256*512+255)/256), 256, 0, stream>>>(gnn_mlp2_w, m2Hi, m2Lo, 9L*256*512);
    wconv_plain<<<dim3((256*256+255)/256), 256, 0, stream>>>(final_w, finHi, finLo, 256L*256);

    // ---- keypoint encoder -> descF (n-major) ----
    kenc_kernel<<<dim3(Nc, Bc), 256, 0, stream>>>(kpts0, scores0, desc0, descF,
        kw0, kb0, kg0, ke0, kw1, kb1, kg1, ke1, kw2, kb2, kg2, ke2, kw3, kb3);
    kenc_kernel<<<dim3(Nc, Bc), 256, 0, stream>>>(kpts1, scores1, desc1, descF + 2L*Nc*256,
        kw0, kb0, kg0, ke0, kw1, kb1, kg1, ke1, kw2, kb2, kg2, ke2, kw3, kb3);
    rows_to_planes<<<dim3((unsigned)((ROWS*256+255)/256)), 256, 0, stream>>>(
        descF, 256, 256, catHi, catLo, 512, ROWS * 256);

    const long dirCat = 2L * Nc * 512;
    const long bCat   = (long)Nc * 512;

    // ---- GNN layers ----
    for (int l = 0; l < 9; ++l) {
        // 1) qkv GEMM -> qk planes + vT planes directly (EPI=2), z = dirb
        mfma_nt<128,128,2><<<dim3(6,8,4), 256, 0, stream>>>(
            (const short*)catHi, (const short*)catLo, 512,
            (const short*)(projHi + (long)l*768*256), (const short*)(projLo + (long)l*768*256), 256,
            256, 1.f, projBp + (long)l*768,
            nullptr, qkHi, qkLo, vTHi, vTLo, 0,
            2, 1,
            dirCat, bCat, 0,  0, 0, 0,
            0, 0, 0);
        // 2) fused scores+softmax -> P planes (both dirs)
        attn_scores_softmax<<<dim3(64, 16), 256, 0, stream>>>(qkHi, qkLo, PPHi, PPLo);
        // 3) PV per direction (split K=1024 into 4 chunks)
        for (int d = 0; d < 2; ++d) {
            const long pOff = (long)d * 8 * 1024 * 1024;   // per-dir P slab = 8M elements
            const long vOff = (long)(1 - d) * 2 * 256 * Nc;
            mfma_nt<128,64,0><<<dim3(1,8,32), 256, 0, stream>>>(
                (const short*)PPHi + pOff, (const short*)PPLo + pOff, 1024,
                (const short*)vTHi + vOff, (const short*)vTLo + vOff, 1024,
                256, 1.f, nullptr,
                msgpart, nullptr, nullptr, nullptr, nullptr, 256,
                2, 4,
                256, 4L*1024*1024, 1024L*1024,
                256, 256L*1024, 64L*1024,
                2L*1024*256, 1024L*256, 64);
            pv_reduce_planes<<<dim3((unsigned)((2L*Nc*256+255)/256)), 256, 0, stream>>>(
                msgpart, msgHi + (long)d*2*Nc*256, msgLo + (long)d*2*Nc*256);
        }
        // 4) merge GEMM -> catbuf cols 256..511
        mfma_nt<128,128,1><<<dim3(2,8,4), 256, 0, stream>>>(
            (const short*)msgHi, (const short*)msgLo, 256,
            (const short*)(mrgHi + (long)l*256*256), (const short*)(mrgLo + (long)l*256*256), 256,
            256, 1.f, gnn_merge_b + (long)l*256,
            nullptr, catHi + 256, catLo + 256, nullptr, nullptr, 512,
            2, 1,
            2L*Nc*256, (long)Nc*256, 0,  0, 0, 0,
            dirCat, bCat, 0);
        // 5) mlp1 -> ybufF
        mfma_nt<128,128,0><<<dim3(4,8,4), 256, 0, stream>>>(
            (const short*)catHi, (const short*)catLo, 512,
            (const short*)(m1Hi + (long)l*512*512), (const short*)(m1Lo + (long)l*512*512), 512,
            512, 1.f, gnn_mlp1_b + (long)l*512,
            ybufF, nullptr, nullptr, nullptr, nullptr, 512,
            2, 1,
            dirCat, bCat, 0,  0, 0, 0,
            2L*Nc*512, (long)Nc*512, 0);
        // 6) LN+ReLU -> ybuf planes
        ln_relu_planes<<<dim3((unsigned)ROWS), 256, 0, stream>>>(
            ybufF, gnn_ln_g + (long)l*512, gnn_ln_b + (long)l*512, ybHi, ybLo);
        // 7) mlp2 -> deltaF
        mfma_nt<128,128,0><<<dim3(2,8,4), 256, 0, stream>>>(
            (const short*)ybHi, (const short*)ybLo, 512,
            (const short*)(m2Hi + (long)l*256*512), (const short*)(m2Lo + (long)l*256*512), 512,
            512, 1.f, gnn_mlp2_b + (long)l*256,
            deltaF, nullptr, nullptr, nullptr, nullptr, 256,
            2, 1,
            2L*Nc*512, (long)Nc*512, 0,  0, 0, 0,
            2L*Nc*256, (long)Nc*256, 0);
        // 8) residual + refresh catbuf planes
        resid_convert<<<dim3((unsigned)((ROWS*256+255)/256)), 256, 0, stream>>>(
            descF, deltaF, catHi, catLo);
    }

    // ---- final projection -> mdesc planes ----
    mfma_nt<128,128,1><<<dim3(2,8,4), 256, 0, stream>>>(
        (const short*)catHi, (const short*)catLo, 512,
        (const short*)finHi, (const short*)finLo, 256,
        256, 1.f, final_b,
        nullptr, mdHi, mdLo, nullptr, nullptr, 256,
        2, 1,
        dirCat, bCat, 0,  0, 0, 0,
        2L*Nc*256, (long)Nc*256, 0);
    // ---- score matrix into Z ----
    mfma_nt<128,128,0><<<dim3(8,8,2), 256, 0, stream>>>(
        (const short*)mdHi, (const short*)mdLo, 256,
        (const short*)mdHi + 2L*Nc*256, (const short*)mdLo + 2L*Nc*256, 256,
        256, 1.f/16.f, nullptr,
        Zm, nullptr, nullptr, nullptr, nullptr, NP1c,
        1, 1,
        (long)Nc*256, 0, 0,  (long)Nc*256, 0, 0,
        (long)NP1c*NP1c, 0, 0);
    bins_fill<<<dim3(9,2), 256, 0, stream>>>(Zm, bin_score);

    // ---- Sinkhorn (log-space), 20 iterations ----
    float* ZT = (float*)PPHi; // reuse (P planes dead)
    transpose_np1<<<dim3(33,33,2), dim3(32,8), 0, stream>>>(Zm, ZT);
    zero_vec<<<dim3(9), 256, 0, stream>>>(vvec, Bc * NP1c);
    for (int it = 0; it < 20; ++it) {
        sinkhorn_lse<<<dim3(NP1c, Bc), 256, 0, stream>>>(Zm, vvec, uvec);
        sinkhorn_lse<<<dim3(NP1c, Bc), 256, 0, stream>>>(ZT, uvec, vvec);
    }
    final_out_k<<<dim3(NP1c, Bc), 256, 0, stream>>>(Zm, uvec, vvec, (float*)d_out);
}

// Round 5
// 1799.188 us; speedup vs baseline: 3.2567x; 1.4089x over previous
//
#include <hip/hip_runtime.h>
#include <hip/hip_bf16.h>
#include <math.h>

#define DEVI static __device__ __forceinline__

namespace {
constexpr int Bc   = 2;
constexpr int Nc   = 1024;
constexpr int Dc   = 256;
constexpr int NP1c = 1025;
constexpr float LN_EPS = 1e-6f;
constexpr float NORMV  = -7.6246189861593985f; // -log(2048)
constexpr float LOGNV  =  6.9314718055994531f; // log(1024)
}

typedef __attribute__((ext_vector_type(8))) short bf16x8;
typedef __attribute__((ext_vector_type(4))) float f32x4;

DEVI void split2(float v, __hip_bfloat16& h, __hip_bfloat16& l) {
    h = __float2bfloat16(v);
    l = __float2bfloat16(v - __bfloat162float(h));
}

// async global->LDS, 16B per lane: lds dest = base + lane*16 (HW), global src per-lane
#define GLDS16(gp, lp) __builtin_amdgcn_global_load_lds( \
    (const __attribute__((address_space(1))) void*)(gp), \
    (__attribute__((address_space(3))) void*)(lp), 16, 0, 0)

// ---------------- helpers ----------------
DEVI float block_sum_256(float v, float* scratch) {
    int t = threadIdx.x;
    scratch[t] = v;
    __syncthreads();
    for (int s = 128; s > 0; s >>= 1) {
        if (t < s) scratch[t] += scratch[t + s];
        __syncthreads();
    }
    float r = scratch[0];
    __syncthreads();
    return r;
}

DEVI void ln_relu_inplace(float* x, const float* g, const float* be, int C, float* scratch) {
    int t = threadIdx.x;
    float v = (t < C) ? x[t] : 0.f;
    float mean = block_sum_256(v, scratch) / (float)C;
    float dv = (t < C) ? (x[t] - mean) : 0.f;
    float var = block_sum_256(dv * dv, scratch) / (float)(C - 1);
    float rstd = 1.f / (sqrtf(var) + LN_EPS);
    if (t < C) x[t] = fmaxf(g[t] * dv * rstd + be[t], 0.f);
    __syncthreads();
}

// ---------------- keypoint encoder ----------------
__global__ __launch_bounds__(256) void kenc_kernel(
    const float* __restrict__ kpts, const float* __restrict__ scr,
    const float* __restrict__ desc_in, float* __restrict__ desc_out,
    const float* __restrict__ w0, const float* __restrict__ b0,
    const float* __restrict__ g0, const float* __restrict__ be0,
    const float* __restrict__ w1, const float* __restrict__ b1,
    const float* __restrict__ g1, const float* __restrict__ be1,
    const float* __restrict__ w2, const float* __restrict__ b2,
    const float* __restrict__ g2, const float* __restrict__ be2,
    const float* __restrict__ w3, const float* __restrict__ b3)
{
    __shared__ float xa[256], xb[256], scratch[256];
    const int n = blockIdx.x, b = blockIdx.y, t = threadIdx.x;
    if (t == 0) {
        float kx = kpts[((long)b * Nc + n) * 2 + 0];
        float ky = kpts[((long)b * Nc + n) * 2 + 1];
        xa[0] = (kx - 320.f) * (1.f / 448.f);
        xa[1] = (ky - 240.f) * (1.f / 448.f);
        xa[2] = scr[b * Nc + n];
    }
    __syncthreads();
    if (t < 32) { float a = b0[t]; for (int c = 0; c < 3;   ++c) a += w0[t*3   + c] * xa[c]; xb[t] = a; }
    __syncthreads();
    ln_relu_inplace(xb, g0, be0, 32, scratch);
    if (t < 64) { float a = b1[t]; for (int c = 0; c < 32;  ++c) a += w1[t*32  + c] * xb[c]; xa[t] = a; }
    __syncthreads();
    ln_relu_inplace(xa, g1, be1, 64, scratch);
    if (t < 128){ float a = b2[t]; for (int c = 0; c < 64;  ++c) a += w2[t*64  + c] * xa[c]; xb[t] = a; }
    __syncthreads();
    ln_relu_inplace(xb, g2, be2, 128, scratch);
    {   float a = b3[t]; for (int c = 0; c < 128; ++c) a += w3[t*128 + c] * xb[c];
        desc_out[((long)b * Nc + n) * Dc + t] = desc_in[((long)b * Dc + t) * Nc + n] + a; }
}

// =======================================================================
// MFMA NT GEMM, hi/lo split. out[m][n] = scale*sum_k A[m][k]B[n][k] (+bias[n])
// EPI: 0 fp32 out; 1 bf16 planes; 2 qkv (qk planes + vT planes, dirb=row>>10);
//      3 mlp2 fused (v += descF, write descF + cat planes cols 0..255)
// =======================================================================
template<int BM, int BN, int EPI>
__global__ __launch_bounds__(256) void mfma_nt(
    const short* __restrict__ Ahi0, const short* __restrict__ Alo0, int lda,
    const short* __restrict__ Bhi0, const short* __restrict__ Blo0, int ldb,
    int K, float scale, const float* __restrict__ bias,
    float* __restrict__ outF, __hip_bfloat16* __restrict__ outHi,
    __hip_bfloat16* __restrict__ outLo,
    __hip_bfloat16* __restrict__ outHi2, __hip_bfloat16* __restrict__ outLo2,
    int ldo,
    long aS1, long bS1, long oS1)
{
    constexpr int MI = BM / 32;
    constexpr int NI = BN / 32;
    constexpr int instA = BM / 16, instB = BN / 16;
    constexpr int OFF_AH = 0;
    constexpr int OFF_AL = BM * 32;
    constexpr int OFF_BH = 2 * BM * 32;
    constexpr int OFF_BL = 2 * BM * 32 + BN * 32;
    __shared__ short smem[(2 * BM + 2 * BN) * 32];

    const int z = blockIdx.z;
    const long aOff = z * aS1, bOff = z * bS1, oOff = z * oS1;
    const short* Ah = Ahi0 + aOff; const short* Al = Alo0 + aOff;
    const short* Bh = Bhi0 + bOff; const short* Bl = Blo0 + bOff;

    const int m0 = blockIdx.y * BM, n0 = blockIdx.x * BN;
    const int t = threadIdx.x, lane = t & 63, wid = t >> 6;
    const int lr = lane & 15, lg = lane >> 4;
    const int wr = wid >> 1, wc = wid & 1;

    f32x4 acc[MI][NI];
    for (int mi = 0; mi < MI; ++mi)
        for (int ni = 0; ni < NI; ++ni)
            acc[mi][ni] = f32x4{0.f, 0.f, 0.f, 0.f};

    for (int k0 = 0; k0 < K; k0 += 32) {
        constexpr int total = 2 * instA + 2 * instB;
        for (int q = wid; q < total; q += 4) {
            const short* gsrc; int ldg, mi, ploff, row0;
            if (q < instA)               { gsrc = Ah; ldg = lda; mi = q;                 ploff = OFF_AH; row0 = m0; }
            else if (q < 2*instA)        { gsrc = Al; ldg = lda; mi = q - instA;         ploff = OFF_AL; row0 = m0; }
            else if (q < 2*instA+instB)  { gsrc = Bh; ldg = ldb; mi = q - 2*instA;       ploff = OFF_BH; row0 = n0; }
            else                         { gsrc = Bl; ldg = ldb; mi = q - 2*instA-instB; ploff = OFF_BL; row0 = n0; }
            const short* g = gsrc + (long)(row0 + mi * 16 + lr) * ldg + (k0 + lg * 8);
            GLDS16(g, smem + ploff + mi * 512);
        }
        __syncthreads();
        bf16x8 ah[MI], al[MI];
        #pragma unroll
        for (int mi = 0; mi < MI; ++mi) {
            ah[mi] = *(const bf16x8*)(smem + OFF_AH + ((wr * MI + mi) * 64 + lane) * 8);
            al[mi] = *(const bf16x8*)(smem + OFF_AL + ((wr * MI + mi) * 64 + lane) * 8);
        }
        #pragma unroll
        for (int ni = 0; ni < NI; ++ni) {
            bf16x8 bh = *(const bf16x8*)(smem + OFF_BH + ((wc * NI + ni) * 64 + lane) * 8);
            bf16x8 bl = *(const bf16x8*)(smem + OFF_BL + ((wc * NI + ni) * 64 + lane) * 8);
            #pragma unroll
            for (int mi = 0; mi < MI; ++mi) {
                acc[mi][ni] = __builtin_amdgcn_mfma_f32_16x16x32_bf16(ah[mi], bh, acc[mi][ni], 0, 0, 0);
                acc[mi][ni] = __builtin_amdgcn_mfma_f32_16x16x32_bf16(ah[mi], bl, acc[mi][ni], 0, 0, 0);
                acc[mi][ni] = __builtin_amdgcn_mfma_f32_16x16x32_bf16(al[mi], bh, acc[mi][ni], 0, 0, 0);
            }
        }
        __syncthreads();
    }

    for (int mi = 0; mi < MI; ++mi) {
        for (int i = 0; i < 4; ++i) {
            int row = m0 + wr * (BM / 2) + mi * 16 + lg * 4 + i;
            for (int ni = 0; ni < NI; ++ni) {
                int col = n0 + wc * (BN / 2) + ni * 16 + lr;
                float v = acc[mi][ni][i] * scale;
                if (bias) v += bias[col];
                if (EPI == 0) {
                    outF[(long)row * ldo + col + oOff] = v;
                } else if (EPI == 1) {
                    __hip_bfloat16 h, l;
                    split2(v, h, l);
                    outHi[(long)row * ldo + col + oOff] = h;
                    outLo[(long)row * ldo + col + oOff] = l;
                } else if (EPI == 2) {
                    int dirb = row >> 10, rloc = row & 1023;
                    __hip_bfloat16 h, l;
                    split2(v, h, l);
                    if (col < 512) {
                        long a = (long)row * 512 + col;
                        outHi[a] = h; outLo[a] = l;
                    } else {
                        long a = ((long)dirb * 256 + (col - 512)) * 1024 + rloc;
                        outHi2[a] = h; outLo2[a] = l;
                    }
                } else { // EPI==3: fused residual (descF) + cat planes cols 0..255
                    long i256 = (long)row * 256 + col;
                    v += outF[i256];
                    outF[i256] = v;
                    __hip_bfloat16 h, l;
                    split2(v, h, l);
                    outHi[(long)row * 512 + col] = h;
                    outLo[(long)row * 512 + col] = l;
                }
            }
        }
    }
}

// =======================================================================
// Fully fused attention: scores (K=64 hi/lo MFMA) + row softmax + PV + write
// msg directly into catbuf cols 256..511. Block = 16 q rows of one (dir,b,h);
// wave w owns m-chunk w*256..+255. P kept bf16(hi) in swizzled LDS.
// =======================================================================
__global__ __launch_bounds__(256) void attn_fused(
    const __hip_bfloat16* __restrict__ qkHi, const __hip_bfloat16* __restrict__ qkLo,
    const __hip_bfloat16* __restrict__ vTHi, const __hip_bfloat16* __restrict__ vTLo,
    __hip_bfloat16* __restrict__ catHi, __hip_bfloat16* __restrict__ catLo)
{
    __shared__ short pLds[4 * 16 * 256];   // 32KB: P per wave [16 q][256 m] swizzled; reused as f32 partials
    __shared__ float redm[4][16], reds[4][16];
    const int y = blockIdx.y;
    const int dir = y >> 3, b = (y >> 2) & 1, h = y & 3;
    const int q0 = blockIdx.x * 16;
    const int t = threadIdx.x, lane = t & 63, w = t >> 6;
    const int lr = lane & 15, lg = lane >> 4;
    const short* qh = (const short*)qkHi;
    const short* ql = (const short*)qkLo;
    const long R0 = (long)dir * 2048 + (long)b * 1024 + q0;
    const long KB = (long)(1 - dir) * 2048 + (long)b * 1024 + w * 256;
    const int srcdb = (1 - dir) * 2 + b;

    bf16x8 ah[2], al[2];
    #pragma unroll
    for (int kc = 0; kc < 2; ++kc) {
        long a = (R0 + lr) * 512 + h * 64 + kc * 32 + lg * 8;
        ah[kc] = *(const bf16x8*)(qh + a);
        al[kc] = *(const bf16x8*)(ql + a);
    }

    f32x4 acc[16];
    #pragma unroll
    for (int ni = 0; ni < 16; ++ni) acc[ni] = f32x4{0.f, 0.f, 0.f, 0.f};

    #pragma unroll
    for (int ni = 0; ni < 16; ++ni) {
        long kr = (KB + ni * 16 + lr) * 512 + 256 + h * 64 + lg * 8;
        bf16x8 bh0 = *(const bf16x8*)(qh + kr);
        bf16x8 bl0 = *(const bf16x8*)(ql + kr);
        bf16x8 bh1 = *(const bf16x8*)(qh + kr + 32);
        bf16x8 bl1 = *(const bf16x8*)(ql + kr + 32);
        acc[ni] = __builtin_amdgcn_mfma_f32_16x16x32_bf16(ah[0], bh0, acc[ni], 0, 0, 0);
        acc[ni] = __builtin_amdgcn_mfma_f32_16x16x32_bf16(ah[0], bl0, acc[ni], 0, 0, 0);
        acc[ni] = __builtin_amdgcn_mfma_f32_16x16x32_bf16(al[0], bh0, acc[ni], 0, 0, 0);
        acc[ni] = __builtin_amdgcn_mfma_f32_16x16x32_bf16(ah[1], bh1, acc[ni], 0, 0, 0);
        acc[ni] = __builtin_amdgcn_mfma_f32_16x16x32_bf16(ah[1], bl1, acc[ni], 0, 0, 0);
        acc[ni] = __builtin_amdgcn_mfma_f32_16x16x32_bf16(al[1], bh1, acc[ni], 0, 0, 0);
    }

    // softmax (rows q = lg*4+i, cols m = ni*16+lr per wave chunk)
    float mx[4] = {-1e30f, -1e30f, -1e30f, -1e30f};
    #pragma unroll
    for (int ni = 0; ni < 16; ++ni)
        #pragma unroll
        for (int i = 0; i < 4; ++i) {
            float v = acc[ni][i] * 0.125f;
            acc[ni][i] = v;
            mx[i] = fmaxf(mx[i], v);
        }
    #pragma unroll
    for (int off = 1; off < 16; off <<= 1)
        #pragma unroll
        for (int i = 0; i < 4; ++i) mx[i] = fmaxf(mx[i], __shfl_xor(mx[i], off));
    if (lr == 0)
        #pragma unroll
        for (int i = 0; i < 4; ++i) redm[w][lg * 4 + i] = mx[i];
    __syncthreads();
    float Mv[4];
    #pragma unroll
    for (int i = 0; i < 4; ++i)
        Mv[i] = fmaxf(fmaxf(redm[0][lg*4+i], redm[1][lg*4+i]),
                      fmaxf(redm[2][lg*4+i], redm[3][lg*4+i]));
    float sm[4] = {0.f, 0.f, 0.f, 0.f};
    #pragma unroll
    for (int ni = 0; ni < 16; ++ni)
        #pragma unroll
        for (int i = 0; i < 4; ++i) {
            float e = __expf(acc[ni][i] - Mv[i]);
            acc[ni][i] = e;
            sm[i] += e;
        }
    #pragma unroll
    for (int off = 1; off < 16; off <<= 1)
        #pragma unroll
        for (int i = 0; i < 4; ++i) sm[i] += __shfl_xor(sm[i], off);
    if (lr == 0)
        #pragma unroll
        for (int i = 0; i < 4; ++i) reds[w][lg * 4 + i] = sm[i];
    __syncthreads();
    float inv[4];
    #pragma unroll
    for (int i = 0; i < 4; ++i)
        inv[i] = 1.f / (reds[0][lg*4+i] + reds[1][lg*4+i] + reds[2][lg*4+i] + reds[3][lg*4+i]);

    // P -> bf16 -> swizzled LDS (wave-private region)
    char* pB = (char*)pLds + w * 8192;
    #pragma unroll
    for (int ni = 0; ni < 16; ++ni)
        #pragma unroll
        for (int i = 0; i < 4; ++i) {
            int q = lg * 4 + i, m = ni * 16 + lr;
            int byte = (q * 512 + m * 2) ^ ((q & 7) << 4);
            *(short*)(pB + byte) = (short)__bfloat16_as_ushort(__float2bfloat16(acc[ni][i] * inv[i]));
        }
    __syncthreads();

    // PV: partial msg[16 q][64 d] over this wave's m-chunk; V from vT planes (L2)
    f32x4 acc2[4];
    #pragma unroll
    for (int bi = 0; bi < 4; ++bi) acc2[bi] = f32x4{0.f, 0.f, 0.f, 0.f};
    const short* vh = (const short*)vTHi;
    const short* vl = (const short*)vTLo;
    #pragma unroll
    for (int km = 0; km < 8; ++km) {
        int rb = (lr * 512 + km * 64 + lg * 16) ^ ((lr & 7) << 4);
        bf16x8 pa = *(const bf16x8*)(pB + rb);
        #pragma unroll
        for (int bi = 0; bi < 4; ++bi) {
            long vr = ((long)srcdb * 256 + h * 64 + bi * 16 + lr) * 1024 + (w * 256 + km * 32 + lg * 8);
            bf16x8 vhf = *(const bf16x8*)(vh + vr);
            bf16x8 vlf = *(const bf16x8*)(vl + vr);
            acc2[bi] = __builtin_amdgcn_mfma_f32_16x16x32_bf16(pa, vhf, acc2[bi], 0, 0, 0);
            acc2[bi] = __builtin_amdgcn_mfma_f32_16x16x32_bf16(pa, vlf, acc2[bi], 0, 0, 0);
        }
    }
    __syncthreads();          // all P reads done; reuse pLds as f32 partials
    float* pr = (float*)pLds; // [w][16 q][64 d]
    #pragma unroll
    for (int bi = 0; bi < 4; ++bi)
        #pragma unroll
        for (int i = 0; i < 4; ++i)
            pr[w * 1024 + (lg * 4 + i) * 64 + bi * 16 + lr] = acc2[bi][i];
    __syncthreads();
    const int dbOut = dir * 2 + b;
    #pragma unroll
    for (int k = 0; k < 4; ++k) {
        int e = t + k * 256;
        float v = pr[e] + pr[1024 + e] + pr[2048 + e] + pr[3072 + e];
        int q = e >> 6, d = e & 63;
        long a = ((long)dbOut * 1024 + q0 + q) * 512 + 256 + h * 64 + d;
        __hip_bfloat16 hh, ll; split2(v, hh, ll);
        catHi[a] = hh; catLo[a] = ll;
    }
}

// ---------------- fp32 rows -> bf16 hi/lo planes ----------------
__global__ __launch_bounds__(256) void rows_to_planes(
    const float* __restrict__ src, int ldsrc, int C,
    __hip_bfloat16* __restrict__ hi, __hip_bfloat16* __restrict__ lo, int ldp, long total)
{
    long idx = (long)blockIdx.x * 256 + threadIdx.x;
    if (idx >= total) return;
    long row = idx / C; int c = (int)(idx % C);
    float v = src[row * ldsrc + c];
    __hip_bfloat16 h, l; split2(v, h, l);
    hi[row * ldp + c] = h; lo[row * ldp + c] = l;
}

// ---------------- LN(channel,ddof=1,eps-on-std)+ReLU; write planes ----------------
__global__ __launch_bounds__(256) void ln_relu_planes(
    const float* __restrict__ y, const float* __restrict__ g, const float* __restrict__ be,
    __hip_bfloat16* __restrict__ hi, __hip_bfloat16* __restrict__ lo)
{
    __shared__ float s1[256], s2[256];
    const long row = blockIdx.x;
    const int t = threadIdx.x;
    const float* src = y + row * 512;
    float a = src[t], b = src[t + 256];
    s1[t] = a + b; s2[t] = a * a + b * b;
    __syncthreads();
    for (int s = 128; s > 0; s >>= 1) {
        if (t < s) { s1[t] += s1[t + s]; s2[t] += s2[t + s]; }
        __syncthreads();
    }
    float mean = s1[0] / 512.f;
    float var = fmaxf((s2[0] - 512.f * mean * mean) / 511.f, 0.f);
    float rstd = 1.f / (sqrtf(var) + LN_EPS);
    float v1 = fmaxf(g[t] * (a - mean) * rstd + be[t], 0.f);
    float v2 = fmaxf(g[t + 256] * (b - mean) * rstd + be[t + 256], 0.f);
    __hip_bfloat16 h, l;
    split2(v1, h, l); hi[row * 512 + t] = h;       lo[row * 512 + t] = l;
    split2(v2, h, l); hi[row * 512 + t + 256] = h; lo[row * 512 + t + 256] = l;
}

// ---------------- weight converts ----------------
__global__ __launch_bounds__(256) void wconv_plain(
    const float* __restrict__ w, __hip_bfloat16* __restrict__ hi, __hip_bfloat16* __restrict__ lo, long total)
{
    long i = (long)blockIdx.x * 256 + threadIdx.x;
    if (i >= total) return;
    __hip_bfloat16 h, l; split2(w[i], h, l);
    hi[i] = h; lo[i] = l;
}

__global__ __launch_bounds__(256) void wconv_proj(
    const float* __restrict__ w, __hip_bfloat16* __restrict__ hi, __hip_bfloat16* __restrict__ lo)
{
    long i = (long)blockIdx.x * 256 + threadIdx.x;
    if (i >= 9L * 768 * 256) return;
    long l9 = i / (768 * 256);
    int rem = (int)(i % (768 * 256));
    int op = rem / 256, c = rem % 256;
    int tq = op / 256, within = op % 256;
    int h = within / 64, hd = within % 64;
    int o = tq * 256 + hd * 4 + h;
    float v = w[(l9 * 768 + o) * 256 + c];
    __hip_bfloat16 hh, ll; split2(v, hh, ll);
    hi[i] = hh; lo[i] = ll;
}

__global__ void wconv_proj_bias(const float* __restrict__ b, float* __restrict__ bp)
{
    int i = blockIdx.x * 256 + threadIdx.x;
    if (i >= 9 * 768) return;
    int l9 = i / 768, op = i % 768;
    int tq = op / 256, within = op % 256;
    int h = within / 64, hd = within % 64;
    bp[i] = b[(l9 * 3 + tq) * 256 + hd * 4 + h];
}

// WmT planes: [l][c=h*64+hd][j] = Wm[l][j][hd*4+h]  (transposed + col-permuted)
__global__ __launch_bounds__(256) void wconv_mergeT(
    const float* __restrict__ w, __hip_bfloat16* __restrict__ hi, __hip_bfloat16* __restrict__ lo)
{
    long i = (long)blockIdx.x * 256 + threadIdx.x;
    if (i >= 9L * 256 * 256) return;
    long l9 = i / (256 * 256);
    int rem = (int)(i % (256 * 256));
    int c = rem / 256, j = rem % 256;
    int h = c / 64, hd = c % 64;
    float v = w[(l9 * 256 + j) * 256 + (hd * 4 + h)];
    __hip_bfloat16 hh, ll; split2(v, hh, ll);
    hi[i] = hh; lo[i] = ll;
}

// mlp1 W cols 0..255 -> m1c planes [l*512+o][512] cols 0..255
__global__ __launch_bounds__(256) void wconv_m1a(
    const float* __restrict__ w, __hip_bfloat16* __restrict__ hi, __hip_bfloat16* __restrict__ lo)
{
    long i = (long)blockIdx.x * 256 + threadIdx.x;
    if (i >= 9L * 512 * 256) return;
    long lo9 = i / 256;       // l*512+o
    int c = (int)(i % 256);
    float v = w[lo9 * 512 + c];
    __hip_bfloat16 hh, ll; split2(v, hh, ll);
    hi[lo9 * 512 + c] = hh; lo[lo9 * 512 + c] = ll;
}

// mlp1 W cols 256..511 -> m1b planes [l*512+o][256]
__global__ __launch_bounds__(256) void wconv_m1b(
    const float* __restrict__ w, __hip_bfloat16* __restrict__ hi, __hip_bfloat16* __restrict__ lo)
{
    long i = (long)blockIdx.x * 256 + threadIdx.x;
    if (i >= 9L * 512 * 256) return;
    long lo9 = i / 256;
    int c = (int)(i % 256);
    float v = w[lo9 * 512 + 256 + c];
    __hip_bfloat16 hh, ll; split2(v, hh, ll);
    hi[i] = hh; lo[i] = ll;
}

// b1c[l*512+o] = b1[l][o] + sum_j W1[l][o][256+j]*bm[l][j]  (1 wave per output)
__global__ __launch_bounds__(64) void bias_fold(
    const float* __restrict__ w1, const float* __restrict__ b1,
    const float* __restrict__ bm, float* __restrict__ out)
{
    int og = blockIdx.x;             // 0..4607
    int l = og >> 9, o = og & 511;
    int t = threadIdx.x;
    float s = 0.f;
    for (int j = t; j < 256; j += 64)
        s += w1[((long)l * 512 + o) * 512 + 256 + j] * bm[l * 256 + j];
    for (int off = 32; off > 0; off >>= 1) s += __shfl_down(s, off);
    if (t == 0) out[og] = b1[(long)l * 512 + o] + s;
}

// ---------------- Sinkhorn pieces ----------------
__global__ void bins_fill(float* __restrict__ Z, const float* __restrict__ alpha_p)
{
    float alpha = alpha_p[0];
    int idx = blockIdx.x * 256 + threadIdx.x;
    int b = blockIdx.y;
    float* Zb = Z + (long)b * NP1c * NP1c;
    if (idx < NP1c) Zb[(long)1024 * NP1c + idx] = alpha;
    else { int i = idx - NP1c; if (i < 1024) Zb[(long)i * NP1c + 1024] = alpha; }
}

__global__ void transpose_np1(const float* __restrict__ Z, float* __restrict__ ZT)
{
    __shared__ float tile[32][33];
    int b = blockIdx.z;
    int i0 = blockIdx.y * 32, j0 = blockIdx.x * 32;
    int tx = threadIdx.x, ty = threadIdx.y;
    const float* Zb = Z + (long)b * NP1c * NP1c;
    float* Tb = ZT + (long)b * NP1c * NP1c;
    for (int ii = ty; ii < 32; ii += 8) {
        int i = i0 + ii, j = j0 + tx;
        if (i < NP1c && j < NP1c) tile[ii][tx] = Zb[(long)i * NP1c + j];
    }
    __syncthreads();
    for (int jj = ty; jj < 32; jj += 8) {
        int j = j0 + jj, i = i0 + tx;
        if (j < NP1c && i < NP1c) Tb[(long)j * NP1c + i] = tile[tx][jj];
    }
}

__global__ void zero_vec(float* __restrict__ v, int n)
{
    int i = blockIdx.x * 256 + threadIdx.x;
    if (i < n) v[i] = 0.f;
}

__global__ __launch_bounds__(256) void sinkhorn_lse(
    const float* __restrict__ M, const float* __restrict__ addv, float* __restrict__ outv)
{
    __shared__ float sm[256], ss[256];
    const int i = blockIdx.x, b = blockIdx.y, t = threadIdx.x;
    const float* row = M + ((long)b * NP1c + i) * NP1c;
    const float* av = addv + b * NP1c;
    float m = -1e30f, s = 0.f;
    for (int j = t; j < NP1c; j += 256) {
        float xv = row[j] + av[j];
        if (xv > m) { s = s * __expf(m - xv) + 1.f; m = xv; }
        else s += __expf(xv - m);
    }
    sm[t] = m; ss[t] = s;
    __syncthreads();
    for (int st = 128; st > 0; st >>= 1) {
        if (t < st) {
            float m1 = sm[t], s1 = ss[t], m2 = sm[t + st], s2 = ss[t + st];
            float mm = fmaxf(m1, m2);
            sm[t] = mm;
            ss[t] = s1 * __expf(m1 - mm) + s2 * __expf(m2 - mm);
        }
        __syncthreads();
    }
    if (t == 0) {
        float lse = sm[0] + __logf(ss[0]);
        float lmu = (i < 1024) ? NORMV : (LOGNV + NORMV);
        outv[b * NP1c + i] = lmu - lse;
    }
}

__global__ __launch_bounds__(256) void final_out_k(
    const float* __restrict__ Z, const float* __restrict__ u,
    const float* __restrict__ v, float* __restrict__ outp)
{
    const int i = blockIdx.x, b = blockIdx.y, t = threadIdx.x;
    const float* row = Z + ((long)b * NP1c + i) * NP1c;
    float* orow = outp + ((long)b * NP1c + i) * NP1c;
    float ui = u[b * NP1c + i];
    for (int j = t; j < NP1c; j += 256)
        orow[j] = row[j] + ui + v[b * NP1c + j] - NORMV;
}

// =======================================================================
extern "C" void kernel_launch(void* const* d_in, const int* in_sizes, int n_in,
                              void* d_out, int out_size, void* d_ws, size_t ws_size,
                              hipStream_t stream)
{
    (void)in_sizes; (void)n_in; (void)out_size; (void)ws_size;
    const float* kpts0   = (const float*)d_in[0];
    const float* kpts1   = (const float*)d_in[1];
    const float* scores0 = (const float*)d_in[2];
    const float* scores1 = (const float*)d_in[3];
    const float* desc0   = (const float*)d_in[4];
    const float* desc1   = (const float*)d_in[5];
    const float* kw0 = (const float*)d_in[6];  const float* kb0 = (const float*)d_in[7];
    const float* kg0 = (const float*)d_in[8];  const float* ke0 = (const float*)d_in[9];
    const float* kw1 = (const float*)d_in[10]; const float* kb1 = (const float*)d_in[11];
    const float* kg1 = (const float*)d_in[12]; const float* ke1 = (const float*)d_in[13];
    const float* kw2 = (const float*)d_in[14]; const float* kb2 = (const float*)d_in[15];
    const float* kg2 = (const float*)d_in[16]; const float* ke2 = (const float*)d_in[17];
    const float* kw3 = (const float*)d_in[18]; const float* kb3 = (const float*)d_in[19];
    const float* gnn_proj_w  = (const float*)d_in[20];
    const float* gnn_proj_b  = (const float*)d_in[21];
    const float* gnn_merge_w = (const float*)d_in[22];
    const float* gnn_merge_b = (const float*)d_in[23];
    const float* gnn_mlp1_w  = (const float*)d_in[24];
    const float* gnn_mlp1_b  = (const float*)d_in[25];
    const float* gnn_ln_g    = (const float*)d_in[26];
    const float* gnn_ln_b    = (const float*)d_in[27];
    const float* gnn_mlp2_w  = (const float*)d_in[28];
    const float* gnn_mlp2_b  = (const float*)d_in[29];
    const float* final_w     = (const float*)d_in[30];
    const float* final_b     = (const float*)d_in[31];
    const float* bin_score   = (const float*)d_in[32];

    char* wsb = (char*)d_ws;
    size_t off = 0;
    auto alloc = [&](size_t bytes) -> void* {
        void* p = wsb + off;
        off = (off + bytes + 255) & ~(size_t)255;
        return p;
    };
    typedef __hip_bfloat16 bf;
    const long ROWS = 4L * Nc;               // (dir,b,n) rows = 4096
    // fp32
    float* descF  = (float*)alloc(ROWS * 256 * 4);
    float* ybufF  = (float*)alloc(ROWS * 512 * 4);
    float* Zm     = (float*)alloc((long)Bc * NP1c * NP1c * 4);
    float* ZT     = (float*)alloc((long)Bc * NP1c * NP1c * 4);
    float* uvec   = (float*)alloc(Bc * NP1c * 4);
    float* vvec   = (float*)alloc(Bc * NP1c * 4);
    float* projBp = (float*)alloc(9L * 768 * 4);
    float* b1c    = (float*)alloc(9L * 512 * 4);
    // activation planes
    bf* catHi = (bf*)alloc(ROWS * 512 * 2);  bf* catLo = (bf*)alloc(ROWS * 512 * 2);
    bf* qkHi  = (bf*)alloc(ROWS * 512 * 2);  bf* qkLo  = (bf*)alloc(ROWS * 512 * 2);
    bf* vTHi  = (bf*)alloc(4L * 256 * Nc * 2); bf* vTLo = (bf*)alloc(4L * 256 * Nc * 2);
    bf* ybHi  = (bf*)alloc(ROWS * 512 * 2);  bf* ybLo  = (bf*)alloc(ROWS * 512 * 2);
    bf* mdHi  = (bf*)alloc(ROWS * 256 * 2);  bf* mdLo  = (bf*)alloc(ROWS * 256 * 2);
    // weight planes
    bf* projHi = (bf*)alloc(9L*768*256*2);   bf* projLo = (bf*)alloc(9L*768*256*2);
    bf* mrgTHi = (bf*)alloc(9L*256*256*2);   bf* mrgTLo = (bf*)alloc(9L*256*256*2);
    bf* m1bHi  = (bf*)alloc(9L*512*256*2);   bf* m1bLo  = (bf*)alloc(9L*512*256*2);
    bf* m1cHi  = (bf*)alloc(9L*512*512*2);   bf* m1cLo  = (bf*)alloc(9L*512*512*2);
    bf* m2Hi   = (bf*)alloc(9L*256*512*2);   bf* m2Lo   = (bf*)alloc(9L*256*512*2);
    bf* finHi  = (bf*)alloc(256L*256*2);     bf* finLo  = (bf*)alloc(256L*256*2);

    // ---- weight prep ----
    wconv_proj<<<dim3((9*768*256+255)/256), 256, 0, stream>>>(gnn_proj_w, projHi, projLo);
    wconv_proj_bias<<<dim3(27), 256, 0, stream>>>(gnn_proj_b, projBp);
    wconv_mergeT<<<dim3((9*256*256+255)/256), 256, 0, stream>>>(gnn_merge_w, mrgTHi, mrgTLo);
    wconv_m1a<<<dim3((9*512*256+255)/256), 256, 0, stream>>>(gnn_mlp1_w, m1cHi, m1cLo);
    wconv_m1b<<<dim3((9*512*256+255)/256), 256, 0, stream>>>(gnn_mlp1_w, m1bHi, m1bLo);
    wconv_plain<<<dim3((9*256*512+255)/256), 256, 0, stream>>>(gnn_mlp2_w, m2Hi, m2Lo, 9L*256*512);
    wconv_plain<<<dim3((256*256+255)/256), 256, 0, stream>>>(final_w, finHi, finLo, 256L*256);
    bias_fold<<<dim3(9*512), 64, 0, stream>>>(gnn_mlp1_w, gnn_mlp1_b, gnn_merge_b, b1c);
    // combined mlp1 cols 256..511 = W1b (512x256) x WmT^T : per-layer z
    mfma_nt<128,128,1><<<dim3(2,4,9), 256, 0, stream>>>(
        (const short*)m1bHi, (const short*)m1bLo, 256,
        (const short*)mrgTHi, (const short*)mrgTLo, 256,
        256, 1.f, nullptr,
        nullptr, m1cHi + 256, m1cLo + 256, nullptr, nullptr, 512,
        512L*256, 256L*256, 512L*512);

    // ---- keypoint encoder -> descF (n-major) -> cat planes cols 0..255 ----
    kenc_kernel<<<dim3(Nc, Bc), 256, 0, stream>>>(kpts0, scores0, desc0, descF,
        kw0, kb0, kg0, ke0, kw1, kb1, kg1, ke1, kw2, kb2, kg2, ke2, kw3, kb3);
    kenc_kernel<<<dim3(Nc, Bc), 256, 0, stream>>>(kpts1, scores1, desc1, descF + 2L*Nc*256,
        kw0, kb0, kg0, ke0, kw1, kb1, kg1, ke1, kw2, kb2, kg2, ke2, kw3, kb3);
    rows_to_planes<<<dim3((unsigned)((ROWS*256+255)/256)), 256, 0, stream>>>(
        descF, 256, 256, catHi, catLo, 512, ROWS * 256);

    // ---- GNN layers ----
    for (int l = 0; l < 9; ++l) {
        // 1) qkv GEMM (M=4096 rows, N=768, K=256) -> qk + vT planes
        mfma_nt<64,128,2><<<dim3(6,64,1), 256, 0, stream>>>(
            (const short*)catHi, (const short*)catLo, 512,
            (const short*)(projHi + (long)l*768*256), (const short*)(projLo + (long)l*768*256), 256,
            256, 1.f, projBp + (long)l*768,
            nullptr, qkHi, qkLo, vTHi, vTLo, 0,
            0, 0, 0);
        // 2) fused attention -> catbuf cols 256..511 (raw msg; merge folded into mlp1)
        attn_fused<<<dim3(64, 16), 256, 0, stream>>>(qkHi, qkLo, vTHi, vTLo, catHi, catLo);
        // 3) mlp1 (M=4096, N=512, K=512) with combined weights -> ybufF
        mfma_nt<64,128,0><<<dim3(4,64,1), 256, 0, stream>>>(
            (const short*)catHi, (const short*)catLo, 512,
            (const short*)(m1cHi + (long)l*512*512), (const short*)(m1cLo + (long)l*512*512), 512,
            512, 1.f, b1c + (long)l*512,
            ybufF, nullptr, nullptr, nullptr, nullptr, 512,
            0, 0, 0);
        // 4) LN+ReLU -> yb planes
        ln_relu_planes<<<dim3((unsigned)ROWS), 256, 0, stream>>>(
            ybufF, gnn_ln_g + (long)l*512, gnn_ln_b + (long)l*512, ybHi, ybLo);
        // 5) mlp2 (M=4096, N=256, K=512) fused residual -> descF + cat cols 0..255
        mfma_nt<64,64,3><<<dim3(4,64,1), 256, 0, stream>>>(
            (const short*)ybHi, (const short*)ybLo, 512,
            (const short*)(m2Hi + (long)l*256*512), (const short*)(m2Lo + (long)l*256*512), 512,
            512, 1.f, gnn_mlp2_b + (long)l*256,
            descF, catHi, catLo, nullptr, nullptr, 0,
            0, 0, 0);
    }

    // ---- final projection -> mdesc planes ----
    mfma_nt<64,64,1><<<dim3(4,64,1), 256, 0, stream>>>(
        (const short*)catHi, (const short*)catLo, 512,
        (const short*)finHi, (const short*)finLo, 256,
        256, 1.f, final_b,
        nullptr, mdHi, mdLo, nullptr, nullptr, 256,
        0, 0, 0);
    // ---- score matrix into Z (z = b) ----
    mfma_nt<128,128,0><<<dim3(8,8,2), 256, 0, stream>>>(
        (const short*)mdHi, (const short*)mdLo, 256,
        (const short*)mdHi + 2048L*256, (const short*)mdLo + 2048L*256, 256,
        256, 1.f/16.f, nullptr,
        Zm, nullptr, nullptr, nullptr, nullptr, NP1c,
        1024L*256, 1024L*256, (long)NP1c*NP1c);
    bins_fill<<<dim3(9,2), 256, 0, stream>>>(Zm, bin_score);

    // ---- Sinkhorn (log-space), 20 iterations ----
    transpose_np1<<<dim3(33,33,2), dim3(32,8), 0, stream>>>(Zm, ZT);
    zero_vec<<<dim3(9), 256, 0, stream>>>(vvec, Bc * NP1c);
    for (int it = 0; it < 20; ++it) {
        sinkhorn_lse<<<dim3(NP1c, Bc), 256, 0, stream>>>(Zm, vvec, uvec);
        sinkhorn_lse<<<dim3(NP1c, Bc), 256, 0, stream>>>(ZT, uvec, vvec);
    }
    final_out_k<<<dim3(NP1c, Bc), 256, 0, stream>>>(Zm, uvec, vvec, (float*)d_out);
}

// Round 6
// 1440.249 us; speedup vs baseline: 4.0684x; 1.2492x over previous
//
#include <hip/hip_runtime.h>
#include <hip/hip_bf16.h>
#include <math.h>

#define DEVI static __device__ __forceinline__

namespace {
constexpr int Bc   = 2;
constexpr int Nc   = 1024;
constexpr int Dc   = 256;
constexpr int NP1c = 1025;
constexpr float LN_EPS = 1e-6f;
constexpr float NORMV  = -7.6246189861593985f; // -log(2048)
constexpr float LOGNV  =  6.9314718055994531f; // log(1024)
}

typedef __attribute__((ext_vector_type(8))) short bf16x8;
typedef __attribute__((ext_vector_type(4))) float f32x4;

DEVI void split2(float v, __hip_bfloat16& h, __hip_bfloat16& l) {
    h = __float2bfloat16(v);
    l = __float2bfloat16(v - __bfloat162float(h));
}

// async global->LDS, 16B per lane
#define GLDS16(gp, lp) __builtin_amdgcn_global_load_lds( \
    (const __attribute__((address_space(1))) void*)(gp), \
    (__attribute__((address_space(3))) void*)(lp), 16, 0, 0)

// ---------------- helpers ----------------
DEVI float block_sum_256(float v, float* scratch) {
    int t = threadIdx.x;
    scratch[t] = v;
    __syncthreads();
    for (int s = 128; s > 0; s >>= 1) {
        if (t < s) scratch[t] += scratch[t + s];
        __syncthreads();
    }
    float r = scratch[0];
    __syncthreads();
    return r;
}

DEVI void ln_relu_inplace(float* x, const float* g, const float* be, int C, float* scratch) {
    int t = threadIdx.x;
    float v = (t < C) ? x[t] : 0.f;
    float mean = block_sum_256(v, scratch) / (float)C;
    float dv = (t < C) ? (x[t] - mean) : 0.f;
    float var = block_sum_256(dv * dv, scratch) / (float)(C - 1);
    float rstd = 1.f / (sqrtf(var) + LN_EPS);
    if (t < C) x[t] = fmaxf(g[t] * dv * rstd + be[t], 0.f);
    __syncthreads();
}

// ---------------- keypoint encoder ----------------
__global__ __launch_bounds__(256) void kenc_kernel(
    const float* __restrict__ kpts, const float* __restrict__ scr,
    const float* __restrict__ desc_in, float* __restrict__ desc_out,
    const float* __restrict__ w0, const float* __restrict__ b0,
    const float* __restrict__ g0, const float* __restrict__ be0,
    const float* __restrict__ w1, const float* __restrict__ b1,
    const float* __restrict__ g1, const float* __restrict__ be1,
    const float* __restrict__ w2, const float* __restrict__ b2,
    const float* __restrict__ g2, const float* __restrict__ be2,
    const float* __restrict__ w3, const float* __restrict__ b3)
{
    __shared__ float xa[256], xb[256], scratch[256];
    const int n = blockIdx.x, b = blockIdx.y, t = threadIdx.x;
    if (t == 0) {
        float kx = kpts[((long)b * Nc + n) * 2 + 0];
        float ky = kpts[((long)b * Nc + n) * 2 + 1];
        xa[0] = (kx - 320.f) * (1.f / 448.f);
        xa[1] = (ky - 240.f) * (1.f / 448.f);
        xa[2] = scr[b * Nc + n];
    }
    __syncthreads();
    if (t < 32) { float a = b0[t]; for (int c = 0; c < 3;   ++c) a += w0[t*3   + c] * xa[c]; xb[t] = a; }
    __syncthreads();
    ln_relu_inplace(xb, g0, be0, 32, scratch);
    if (t < 64) { float a = b1[t]; for (int c = 0; c < 32;  ++c) a += w1[t*32  + c] * xb[c]; xa[t] = a; }
    __syncthreads();
    ln_relu_inplace(xa, g1, be1, 64, scratch);
    if (t < 128){ float a = b2[t]; for (int c = 0; c < 64;  ++c) a += w2[t*64  + c] * xa[c]; xb[t] = a; }
    __syncthreads();
    ln_relu_inplace(xb, g2, be2, 128, scratch);
    {   float a = b3[t]; for (int c = 0; c < 128; ++c) a += w3[t*128 + c] * xb[c];
        desc_out[((long)b * Nc + n) * Dc + t] = desc_in[((long)b * Dc + t) * Nc + n] + a; }
}

// =======================================================================
// MFMA NT GEMM, hi/lo split. out[m][n] = scale*sum_k A[m][k]B[n][k] (+bias[n])
// EPI: 0 fp32 out; 1 bf16 planes; 2 qkv -> Q/K/V FRAGMENT-ORDER buffers;
//      3 mlp2 fused (v += descF, write descF + cat planes cols 0..255)
// EPI==2 pointer use: outHi/outLo = qF, outHi2/outLo2 = vF, outHi3/outLo3 = kF
// =======================================================================
template<int BM, int BN, int EPI>
__global__ __launch_bounds__(256) void mfma_nt(
    const short* __restrict__ Ahi0, const short* __restrict__ Alo0, int lda,
    const short* __restrict__ Bhi0, const short* __restrict__ Blo0, int ldb,
    int K, float scale, const float* __restrict__ bias,
    float* __restrict__ outF, __hip_bfloat16* __restrict__ outHi,
    __hip_bfloat16* __restrict__ outLo,
    __hip_bfloat16* __restrict__ outHi2, __hip_bfloat16* __restrict__ outLo2,
    __hip_bfloat16* __restrict__ outHi3, __hip_bfloat16* __restrict__ outLo3,
    int ldo,
    long aS1, long bS1, long oS1)
{
    constexpr int MI = BM / 32;
    constexpr int NI = BN / 32;
    constexpr int instA = BM / 16, instB = BN / 16;
    constexpr int OFF_AH = 0;
    constexpr int OFF_AL = BM * 32;
    constexpr int OFF_BH = 2 * BM * 32;
    constexpr int OFF_BL = 2 * BM * 32 + BN * 32;
    __shared__ short smem[(2 * BM + 2 * BN) * 32];

    const int z = blockIdx.z;
    const long aOff = z * aS1, bOff = z * bS1, oOff = z * oS1;
    const short* Ah = Ahi0 + aOff; const short* Al = Alo0 + aOff;
    const short* Bh = Bhi0 + bOff; const short* Bl = Blo0 + bOff;

    const int m0 = blockIdx.y * BM, n0 = blockIdx.x * BN;
    const int t = threadIdx.x, lane = t & 63, wid = t >> 6;
    const int lr = lane & 15, lg = lane >> 4;
    const int wr = wid >> 1, wc = wid & 1;

    f32x4 acc[MI][NI];
    for (int mi = 0; mi < MI; ++mi)
        for (int ni = 0; ni < NI; ++ni)
            acc[mi][ni] = f32x4{0.f, 0.f, 0.f, 0.f};

    for (int k0 = 0; k0 < K; k0 += 32) {
        constexpr int total = 2 * instA + 2 * instB;
        for (int q = wid; q < total; q += 4) {
            const short* gsrc; int ldg, mi, ploff, row0;
            if (q < instA)               { gsrc = Ah; ldg = lda; mi = q;                 ploff = OFF_AH; row0 = m0; }
            else if (q < 2*instA)        { gsrc = Al; ldg = lda; mi = q - instA;         ploff = OFF_AL; row0 = m0; }
            else if (q < 2*instA+instB)  { gsrc = Bh; ldg = ldb; mi = q - 2*instA;       ploff = OFF_BH; row0 = n0; }
            else                         { gsrc = Bl; ldg = ldb; mi = q - 2*instA-instB; ploff = OFF_BL; row0 = n0; }
            const short* g = gsrc + (long)(row0 + mi * 16 + lr) * ldg + (k0 + lg * 8);
            GLDS16(g, smem + ploff + mi * 512);
        }
        __syncthreads();
        bf16x8 ah[MI], al[MI];
        #pragma unroll
        for (int mi = 0; mi < MI; ++mi) {
            ah[mi] = *(const bf16x8*)(smem + OFF_AH + ((wr * MI + mi) * 64 + lane) * 8);
            al[mi] = *(const bf16x8*)(smem + OFF_AL + ((wr * MI + mi) * 64 + lane) * 8);
        }
        #pragma unroll
        for (int ni = 0; ni < NI; ++ni) {
            bf16x8 bh = *(const bf16x8*)(smem + OFF_BH + ((wc * NI + ni) * 64 + lane) * 8);
            bf16x8 bl = *(const bf16x8*)(smem + OFF_BL + ((wc * NI + ni) * 64 + lane) * 8);
            #pragma unroll
            for (int mi = 0; mi < MI; ++mi) {
                acc[mi][ni] = __builtin_amdgcn_mfma_f32_16x16x32_bf16(ah[mi], bh, acc[mi][ni], 0, 0, 0);
                acc[mi][ni] = __builtin_amdgcn_mfma_f32_16x16x32_bf16(ah[mi], bl, acc[mi][ni], 0, 0, 0);
                acc[mi][ni] = __builtin_amdgcn_mfma_f32_16x16x32_bf16(al[mi], bh, acc[mi][ni], 0, 0, 0);
            }
        }
        __syncthreads();
    }

    for (int mi = 0; mi < MI; ++mi) {
        for (int i = 0; i < 4; ++i) {
            int row = m0 + wr * (BM / 2) + mi * 16 + lg * 4 + i;
            for (int ni = 0; ni < NI; ++ni) {
                int col = n0 + wc * (BN / 2) + ni * 16 + lr;
                float v = acc[mi][ni][i] * scale;
                if (bias) v += bias[col];
                if (EPI == 0) {
                    outF[(long)row * ldo + col + oOff] = v;
                } else if (EPI == 1) {
                    __hip_bfloat16 h, l;
                    split2(v, h, l);
                    outHi[(long)row * ldo + col + oOff] = h;
                    outLo[(long)row * ldo + col + oOff] = l;
                } else if (EPI == 2) {
                    // fragment-order scatter: Q/K -> [dh][nb][kc][lane][8]; V -> [dh][w][km][bi][lane][8]
                    int dirb = row >> 10, rloc = row & 1023;
                    int tq = col >> 8, within = col & 255;
                    int h4 = within >> 6, hd = within & 63;
                    __hip_bfloat16 hh, ll;
                    split2(v, hh, ll);
                    if (tq == 2) {
                        int w2 = rloc >> 8, mloc = rloc & 255;
                        int lane2 = ((mloc & 31) >> 3) * 16 + (hd & 15);
                        long idx = ((((long)(dirb*4+h4)*4 + w2)*8 + (mloc>>5))*4 + (hd>>4))*512 + lane2*8 + (mloc&7);
                        outHi2[idx] = hh; outLo2[idx] = ll;
                    } else {
                        int lane2 = ((hd & 31) >> 3) * 16 + (rloc & 15);
                        long idx = (((long)(dirb*4+h4)*64 + (rloc>>4))*2 + (hd>>5))*512 + lane2*8 + (hd&7);
                        if (tq == 0) { outHi[idx] = hh; outLo[idx] = ll; }
                        else         { outHi3[idx] = hh; outLo3[idx] = ll; }
                    }
                } else { // EPI==3: fused residual (descF) + cat planes cols 0..255
                    long i256 = (long)row * 256 + col;
                    v += outF[i256];
                    outF[i256] = v;
                    __hip_bfloat16 h, l;
                    split2(v, h, l);
                    outHi[(long)row * 512 + col] = h;
                    outLo[(long)row * 512 + col] = l;
                }
            }
        }
    }
}

// =======================================================================
// Fully fused attention, fragment-order Q/K/V inputs (all loads coalesced:
// base + lane*16B). Block = 16 q rows of one (dir,b,h); wave w owns m-chunk
// w*256..+255. P kept bf16(hi) in swizzled LDS.
// =======================================================================
__global__ __launch_bounds__(256) void attn_fused(
    const __hip_bfloat16* __restrict__ qFh, const __hip_bfloat16* __restrict__ qFl,
    const __hip_bfloat16* __restrict__ kFh, const __hip_bfloat16* __restrict__ kFl,
    const __hip_bfloat16* __restrict__ vFh, const __hip_bfloat16* __restrict__ vFl,
    __hip_bfloat16* __restrict__ catHi, __hip_bfloat16* __restrict__ catLo)
{
    __shared__ short pLds[4 * 16 * 256];   // 32KB; reused as f32 partials
    __shared__ float redm[4][16], reds[4][16];
    const int y = blockIdx.y;
    const int dir = y >> 3, b = (y >> 2) & 1, h = y & 3;
    const int q0 = blockIdx.x * 16;
    const int t = threadIdx.x, lane = t & 63, w = t >> 6;
    const int lr = lane & 15, lg = lane >> 4;
    const int dbQ = dir * 2 + b;
    const int srcdb = (1 - dir) * 2 + b;
    const short* qh = (const short*)qFh; const short* ql = (const short*)qFl;
    const short* kh = (const short*)kFh; const short* kl = (const short*)kFl;
    const short* vh = (const short*)vFh; const short* vl = (const short*)vFl;

    // Q frag (coalesced)
    const long qbase = (((long)(dbQ * 4 + h)) * 64 + (q0 >> 4)) * 2;
    bf16x8 ah[2], al[2];
    #pragma unroll
    for (int kc = 0; kc < 2; ++kc) {
        ah[kc] = *(const bf16x8*)(qh + (qbase + kc) * 512 + lane * 8);
        al[kc] = *(const bf16x8*)(ql + (qbase + kc) * 512 + lane * 8);
    }

    f32x4 acc[16];
    #pragma unroll
    for (int ni = 0; ni < 16; ++ni) acc[ni] = f32x4{0.f, 0.f, 0.f, 0.f};

    const long kbase0 = (((long)(srcdb * 4 + h)) * 64 + w * 16) * 2;
    #pragma unroll
    for (int ni = 0; ni < 16; ++ni) {
        long kb = (kbase0 + ni * 2) * 512 + lane * 8;
        bf16x8 bh0 = *(const bf16x8*)(kh + kb);
        bf16x8 bl0 = *(const bf16x8*)(kl + kb);
        bf16x8 bh1 = *(const bf16x8*)(kh + kb + 512);
        bf16x8 bl1 = *(const bf16x8*)(kl + kb + 512);
        acc[ni] = __builtin_amdgcn_mfma_f32_16x16x32_bf16(ah[0], bh0, acc[ni], 0, 0, 0);
        acc[ni] = __builtin_amdgcn_mfma_f32_16x16x32_bf16(ah[0], bl0, acc[ni], 0, 0, 0);
        acc[ni] = __builtin_amdgcn_mfma_f32_16x16x32_bf16(al[0], bh0, acc[ni], 0, 0, 0);
        acc[ni] = __builtin_amdgcn_mfma_f32_16x16x32_bf16(ah[1], bh1, acc[ni], 0, 0, 0);
        acc[ni] = __builtin_amdgcn_mfma_f32_16x16x32_bf16(ah[1], bl1, acc[ni], 0, 0, 0);
        acc[ni] = __builtin_amdgcn_mfma_f32_16x16x32_bf16(al[1], bh1, acc[ni], 0, 0, 0);
    }

    // softmax (rows q = lg*4+i, cols m = ni*16+lr per wave chunk)
    float mx[4] = {-1e30f, -1e30f, -1e30f, -1e30f};
    #pragma unroll
    for (int ni = 0; ni < 16; ++ni)
        #pragma unroll
        for (int i = 0; i < 4; ++i) {
            float v = acc[ni][i] * 0.125f;
            acc[ni][i] = v;
            mx[i] = fmaxf(mx[i], v);
        }
    #pragma unroll
    for (int off = 1; off < 16; off <<= 1)
        #pragma unroll
        for (int i = 0; i < 4; ++i) mx[i] = fmaxf(mx[i], __shfl_xor(mx[i], off));
    if (lr == 0)
        #pragma unroll
        for (int i = 0; i < 4; ++i) redm[w][lg * 4 + i] = mx[i];
    __syncthreads();
    float Mv[4];
    #pragma unroll
    for (int i = 0; i < 4; ++i)
        Mv[i] = fmaxf(fmaxf(redm[0][lg*4+i], redm[1][lg*4+i]),
                      fmaxf(redm[2][lg*4+i], redm[3][lg*4+i]));
    float sm[4] = {0.f, 0.f, 0.f, 0.f};
    #pragma unroll
    for (int ni = 0; ni < 16; ++ni)
        #pragma unroll
        for (int i = 0; i < 4; ++i) {
            float e = __expf(acc[ni][i] - Mv[i]);
            acc[ni][i] = e;
            sm[i] += e;
        }
    #pragma unroll
    for (int off = 1; off < 16; off <<= 1)
        #pragma unroll
        for (int i = 0; i < 4; ++i) sm[i] += __shfl_xor(sm[i], off);
    if (lr == 0)
        #pragma unroll
        for (int i = 0; i < 4; ++i) reds[w][lg * 4 + i] = sm[i];
    __syncthreads();
    float inv[4];
    #pragma unroll
    for (int i = 0; i < 4; ++i)
        inv[i] = 1.f / (reds[0][lg*4+i] + reds[1][lg*4+i] + reds[2][lg*4+i] + reds[3][lg*4+i]);

    // P -> bf16 -> swizzled LDS (wave-private region)
    char* pB = (char*)pLds + w * 8192;
    #pragma unroll
    for (int ni = 0; ni < 16; ++ni)
        #pragma unroll
        for (int i = 0; i < 4; ++i) {
            int q = lg * 4 + i, m = ni * 16 + lr;
            int byte = (q * 512 + m * 2) ^ ((q & 7) << 4);
            *(short*)(pB + byte) = (short)__bfloat16_as_ushort(__float2bfloat16(acc[ni][i] * inv[i]));
        }
    __syncthreads();

    // PV: partial msg[16 q][64 d] over this wave's m-chunk; V frag coalesced
    f32x4 acc2[4];
    #pragma unroll
    for (int bi = 0; bi < 4; ++bi) acc2[bi] = f32x4{0.f, 0.f, 0.f, 0.f};
    const long vbase0 = (((long)(srcdb * 4 + h)) * 4 + w) * 8;
    #pragma unroll
    for (int km = 0; km < 8; ++km) {
        int rb = (lr * 512 + km * 64 + lg * 16) ^ ((lr & 7) << 4);
        bf16x8 pa = *(const bf16x8*)(pB + rb);
        #pragma unroll
        for (int bi = 0; bi < 4; ++bi) {
            long vr = ((vbase0 + km) * 4 + bi) * 512 + lane * 8;
            bf16x8 vhf = *(const bf16x8*)(vh + vr);
            bf16x8 vlf = *(const bf16x8*)(vl + vr);
            acc2[bi] = __builtin_amdgcn_mfma_f32_16x16x32_bf16(pa, vhf, acc2[bi], 0, 0, 0);
            acc2[bi] = __builtin_amdgcn_mfma_f32_16x16x32_bf16(pa, vlf, acc2[bi], 0, 0, 0);
        }
    }
    __syncthreads();          // all P reads done; reuse pLds as f32 partials
    float* pr = (float*)pLds; // [w][16 q][64 d]
    #pragma unroll
    for (int bi = 0; bi < 4; ++bi)
        #pragma unroll
        for (int i = 0; i < 4; ++i)
            pr[w * 1024 + (lg * 4 + i) * 64 + bi * 16 + lr] = acc2[bi][i];
    __syncthreads();
    #pragma unroll
    for (int k = 0; k < 4; ++k) {
        int e = t + k * 256;
        float v = pr[e] + pr[1024 + e] + pr[2048 + e] + pr[3072 + e];
        int q = e >> 6, d = e & 63;
        long a = ((long)dbQ * 1024 + q0 + q) * 512 + 256 + h * 64 + d;
        __hip_bfloat16 hh, ll; split2(v, hh, ll);
        catHi[a] = hh; catLo[a] = ll;
    }
}

// ---------------- fp32 rows -> bf16 hi/lo planes ----------------
__global__ __launch_bounds__(256) void rows_to_planes(
    const float* __restrict__ src, int ldsrc, int C,
    __hip_bfloat16* __restrict__ hi, __hip_bfloat16* __restrict__ lo, int ldp, long total)
{
    long idx = (long)blockIdx.x * 256 + threadIdx.x;
    if (idx >= total) return;
    long row = idx / C; int c = (int)(idx % C);
    float v = src[row * ldsrc + c];
    __hip_bfloat16 h, l; split2(v, h, l);
    hi[row * ldp + c] = h; lo[row * ldp + c] = l;
}

// ---------------- LN(channel,ddof=1,eps-on-std)+ReLU; write planes ----------------
__global__ __launch_bounds__(256) void ln_relu_planes(
    const float* __restrict__ y, const float* __restrict__ g, const float* __restrict__ be,
    __hip_bfloat16* __restrict__ hi, __hip_bfloat16* __restrict__ lo)
{
    __shared__ float s1[256], s2[256];
    const long row = blockIdx.x;
    const int t = threadIdx.x;
    const float* src = y + row * 512;
    float a = src[t], b = src[t + 256];
    s1[t] = a + b; s2[t] = a * a + b * b;
    __syncthreads();
    for (int s = 128; s > 0; s >>= 1) {
        if (t < s) { s1[t] += s1[t + s]; s2[t] += s2[t + s]; }
        __syncthreads();
    }
    float mean = s1[0] / 512.f;
    float var = fmaxf((s2[0] - 512.f * mean * mean) / 511.f, 0.f);
    float rstd = 1.f / (sqrtf(var) + LN_EPS);
    float v1 = fmaxf(g[t] * (a - mean) * rstd + be[t], 0.f);
    float v2 = fmaxf(g[t + 256] * (b - mean) * rstd + be[t + 256], 0.f);
    __hip_bfloat16 h, l;
    split2(v1, h, l); hi[row * 512 + t] = h;       lo[row * 512 + t] = l;
    split2(v2, h, l); hi[row * 512 + t + 256] = h; lo[row * 512 + t + 256] = l;
}

// ---------------- weight converts ----------------
__global__ __launch_bounds__(256) void wconv_plain(
    const float* __restrict__ w, __hip_bfloat16* __restrict__ hi, __hip_bfloat16* __restrict__ lo, long total)
{
    long i = (long)blockIdx.x * 256 + threadIdx.x;
    if (i >= total) return;
    __hip_bfloat16 h, l; split2(w[i], h, l);
    hi[i] = h; lo[i] = l;
}

__global__ __launch_bounds__(256) void wconv_proj(
    const float* __restrict__ w, __hip_bfloat16* __restrict__ hi, __hip_bfloat16* __restrict__ lo)
{
    long i = (long)blockIdx.x * 256 + threadIdx.x;
    if (i >= 9L * 768 * 256) return;
    long l9 = i / (768 * 256);
    int rem = (int)(i % (768 * 256));
    int op = rem / 256, c = rem % 256;
    int tq = op / 256, within = op % 256;
    int h = within / 64, hd = within % 64;
    int o = tq * 256 + hd * 4 + h;
    float v = w[(l9 * 768 + o) * 256 + c];
    __hip_bfloat16 hh, ll; split2(v, hh, ll);
    hi[i] = hh; lo[i] = ll;
}

__global__ void wconv_proj_bias(const float* __restrict__ b, float* __restrict__ bp)
{
    int i = blockIdx.x * 256 + threadIdx.x;
    if (i >= 9 * 768) return;
    int l9 = i / 768, op = i % 768;
    int tq = op / 256, within = op % 256;
    int h = within / 64, hd = within % 64;
    bp[i] = b[(l9 * 3 + tq) * 256 + hd * 4 + h];
}

// WmT planes: [l][c=h*64+hd][j] = Wm[l][j][hd*4+h]
__global__ __launch_bounds__(256) void wconv_mergeT(
    const float* __restrict__ w, __hip_bfloat16* __restrict__ hi, __hip_bfloat16* __restrict__ lo)
{
    long i = (long)blockIdx.x * 256 + threadIdx.x;
    if (i >= 9L * 256 * 256) return;
    long l9 = i / (256 * 256);
    int rem = (int)(i % (256 * 256));
    int c = rem / 256, j = rem % 256;
    int h = c / 64, hd = c % 64;
    float v = w[(l9 * 256 + j) * 256 + (hd * 4 + h)];
    __hip_bfloat16 hh, ll; split2(v, hh, ll);
    hi[i] = hh; lo[i] = ll;
}

// mlp1 W cols 0..255 -> m1c planes [l*512+o][512] cols 0..255
__global__ __launch_bounds__(256) void wconv_m1a(
    const float* __restrict__ w, __hip_bfloat16* __restrict__ hi, __hip_bfloat16* __restrict__ lo)
{
    long i = (long)blockIdx.x * 256 + threadIdx.x;
    if (i >= 9L * 512 * 256) return;
    long lo9 = i / 256;
    int c = (int)(i % 256);
    float v = w[lo9 * 512 + c];
    __hip_bfloat16 hh, ll; split2(v, hh, ll);
    hi[lo9 * 512 + c] = hh; lo[lo9 * 512 + c] = ll;
}

// mlp1 W cols 256..511 -> m1b planes [l*512+o][256]
__global__ __launch_bounds__(256) void wconv_m1b(
    const float* __restrict__ w, __hip_bfloat16* __restrict__ hi, __hip_bfloat16* __restrict__ lo)
{
    long i = (long)blockIdx.x * 256 + threadIdx.x;
    if (i >= 9L * 512 * 256) return;
    long lo9 = i / 256;
    int c = (int)(i % 256);
    float v = w[lo9 * 512 + 256 + c];
    __hip_bfloat16 hh, ll; split2(v, hh, ll);
    hi[i] = hh; lo[i] = ll;
}

// b1c[l*512+o] = b1[l][o] + sum_j W1[l][o][256+j]*bm[l][j]
__global__ __launch_bounds__(64) void bias_fold(
    const float* __restrict__ w1, const float* __restrict__ b1,
    const float* __restrict__ bm, float* __restrict__ out)
{
    int og = blockIdx.x;
    int l = og >> 9, o = og & 511;
    int t = threadIdx.x;
    float s = 0.f;
    for (int j = t; j < 256; j += 64)
        s += w1[((long)l * 512 + o) * 512 + 256 + j] * bm[l * 256 + j];
    for (int off = 32; off > 0; off >>= 1) s += __shfl_down(s, off);
    if (t == 0) out[og] = b1[(long)l * 512 + o] + s;
}

// ---------------- Sinkhorn pieces ----------------
__global__ void bins_fill(float* __restrict__ Z, const float* __restrict__ alpha_p)
{
    float alpha = alpha_p[0];
    int idx = blockIdx.x * 256 + threadIdx.x;
    int b = blockIdx.y;
    float* Zb = Z + (long)b * NP1c * NP1c;
    if (idx < NP1c) Zb[(long)1024 * NP1c + idx] = alpha;
    else { int i = idx - NP1c; if (i < 1024) Zb[(long)i * NP1c + 1024] = alpha; }
}

__global__ void transpose_np1(const float* __restrict__ Z, float* __restrict__ ZT)
{
    __shared__ float tile[32][33];
    int b = blockIdx.z;
    int i0 = blockIdx.y * 32, j0 = blockIdx.x * 32;
    int tx = threadIdx.x, ty = threadIdx.y;
    const float* Zb = Z + (long)b * NP1c * NP1c;
    float* Tb = ZT + (long)b * NP1c * NP1c;
    for (int ii = ty; ii < 32; ii += 8) {
        int i = i0 + ii, j = j0 + tx;
        if (i < NP1c && j < NP1c) tile[ii][tx] = Zb[(long)i * NP1c + j];
    }
    __syncthreads();
    for (int jj = ty; jj < 32; jj += 8) {
        int j = j0 + jj, i = i0 + tx;
        if (j < NP1c && i < NP1c) Tb[(long)j * NP1c + i] = tile[tx][jj];
    }
}

__global__ void zero_vec(float* __restrict__ v, int n)
{
    int i = blockIdx.x * 256 + threadIdx.x;
    if (i < n) v[i] = 0.f;
}

__global__ __launch_bounds__(256) void sinkhorn_lse(
    const float* __restrict__ M, const float* __restrict__ addv, float* __restrict__ outv)
{
    __shared__ float sm[256], ss[256];
    const int i = blockIdx.x, b = blockIdx.y, t = threadIdx.x;
    const float* row = M + ((long)b * NP1c + i) * NP1c;
    const float* av = addv + b * NP1c;
    float m = -1e30f, s = 0.f;
    for (int j = t; j < NP1c; j += 256) {
        float xv = row[j] + av[j];
        if (xv > m) { s = s * __expf(m - xv) + 1.f; m = xv; }
        else s += __expf(xv - m);
    }
    sm[t] = m; ss[t] = s;
    __syncthreads();
    for (int st = 128; st > 0; st >>= 1) {
        if (t < st) {
            float m1 = sm[t], s1 = ss[t], m2 = sm[t + st], s2 = ss[t + st];
            float mm = fmaxf(m1, m2);
            sm[t] = mm;
            ss[t] = s1 * __expf(m1 - mm) + s2 * __expf(m2 - mm);
        }
        __syncthreads();
    }
    if (t == 0) {
        float lse = sm[0] + __logf(ss[0]);
        float lmu = (i < 1024) ? NORMV : (LOGNV + NORMV);
        outv[b * NP1c + i] = lmu - lse;
    }
}

__global__ __launch_bounds__(256) void final_out_k(
    const float* __restrict__ Z, const float* __restrict__ u,
    const float* __restrict__ v, float* __restrict__ outp)
{
    const int i = blockIdx.x, b = blockIdx.y, t = threadIdx.x;
    const float* row = Z + ((long)b * NP1c + i) * NP1c;
    float* orow = outp + ((long)b * NP1c + i) * NP1c;
    float ui = u[b * NP1c + i];
    for (int j = t; j < NP1c; j += 256)
        orow[j] = row[j] + ui + v[b * NP1c + j] - NORMV;
}

// =======================================================================
extern "C" void kernel_launch(void* const* d_in, const int* in_sizes, int n_in,
                              void* d_out, int out_size, void* d_ws, size_t ws_size,
                              hipStream_t stream)
{
    (void)in_sizes; (void)n_in; (void)out_size; (void)ws_size;
    const float* kpts0   = (const float*)d_in[0];
    const float* kpts1   = (const float*)d_in[1];
    const float* scores0 = (const float*)d_in[2];
    const float* scores1 = (const float*)d_in[3];
    const float* desc0   = (const float*)d_in[4];
    const float* desc1   = (const float*)d_in[5];
    const float* kw0 = (const float*)d_in[6];  const float* kb0 = (const float*)d_in[7];
    const float* kg0 = (const float*)d_in[8];  const float* ke0 = (const float*)d_in[9];
    const float* kw1 = (const float*)d_in[10]; const float* kb1 = (const float*)d_in[11];
    const float* kg1 = (const float*)d_in[12]; const float* ke1 = (const float*)d_in[13];
    const float* kw2 = (const float*)d_in[14]; const float* kb2 = (const float*)d_in[15];
    const float* kg2 = (const float*)d_in[16]; const float* ke2 = (const float*)d_in[17];
    const float* kw3 = (const float*)d_in[18]; const float* kb3 = (const float*)d_in[19];
    const float* gnn_proj_w  = (const float*)d_in[20];
    const float* gnn_proj_b  = (const float*)d_in[21];
    const float* gnn_merge_w = (const float*)d_in[22];
    const float* gnn_merge_b = (const float*)d_in[23];
    const float* gnn_mlp1_w  = (const float*)d_in[24];
    const float* gnn_mlp1_b  = (const float*)d_in[25];
    const float* gnn_ln_g    = (const float*)d_in[26];
    const float* gnn_ln_b    = (const float*)d_in[27];
    const float* gnn_mlp2_w  = (const float*)d_in[28];
    const float* gnn_mlp2_b  = (const float*)d_in[29];
    const float* final_w     = (const float*)d_in[30];
    const float* final_b     = (const float*)d_in[31];
    const float* bin_score   = (const float*)d_in[32];

    char* wsb = (char*)d_ws;
    size_t off = 0;
    auto alloc = [&](size_t bytes) -> void* {
        void* p = wsb + off;
        off = (off + bytes + 255) & ~(size_t)255;
        return p;
    };
    typedef __hip_bfloat16 bf;
    const long ROWS = 4L * Nc;
    // fp32
    float* descF  = (float*)alloc(ROWS * 256 * 4);
    float* ybufF  = (float*)alloc(ROWS * 512 * 4);
    float* Zm     = (float*)alloc((long)Bc * NP1c * NP1c * 4);
    float* ZT     = (float*)alloc((long)Bc * NP1c * NP1c * 4);
    float* uvec   = (float*)alloc(Bc * NP1c * 4);
    float* vvec   = (float*)alloc(Bc * NP1c * 4);
    float* projBp = (float*)alloc(9L * 768 * 4);
    float* b1c    = (float*)alloc(9L * 512 * 4);
    // activation planes
    bf* catHi = (bf*)alloc(ROWS * 512 * 2);  bf* catLo = (bf*)alloc(ROWS * 512 * 2);
    // fragment-order attention operands: 1M shorts each
    bf* qFh = (bf*)alloc(1048576 * 2); bf* qFl = (bf*)alloc(1048576 * 2);
    bf* kFh = (bf*)alloc(1048576 * 2); bf* kFl = (bf*)alloc(1048576 * 2);
    bf* vFh = (bf*)alloc(1048576 * 2); bf* vFl = (bf*)alloc(1048576 * 2);
    bf* ybHi  = (bf*)alloc(ROWS * 512 * 2);  bf* ybLo  = (bf*)alloc(ROWS * 512 * 2);
    bf* mdHi  = (bf*)alloc(ROWS * 256 * 2);  bf* mdLo  = (bf*)alloc(ROWS * 256 * 2);
    // weight planes
    bf* projHi = (bf*)alloc(9L*768*256*2);   bf* projLo = (bf*)alloc(9L*768*256*2);
    bf* mrgTHi = (bf*)alloc(9L*256*256*2);   bf* mrgTLo = (bf*)alloc(9L*256*256*2);
    bf* m1bHi  = (bf*)alloc(9L*512*256*2);   bf* m1bLo  = (bf*)alloc(9L*512*256*2);
    bf* m1cHi  = (bf*)alloc(9L*512*512*2);   bf* m1cLo  = (bf*)alloc(9L*512*512*2);
    bf* m2Hi   = (bf*)alloc(9L*256*512*2);   bf* m2Lo   = (bf*)alloc(9L*256*512*2);
    bf* finHi  = (bf*)alloc(256L*256*2);     bf* finLo  = (bf*)alloc(256L*256*2);

    // ---- weight prep ----
    wconv_proj<<<dim3((9*768*256+255)/256), 256, 0, stream>>>(gnn_proj_w, projHi, projLo);
    wconv_proj_bias<<<dim3(27), 256, 0, stream>>>(gnn_proj_b, projBp);
    wconv_mergeT<<<dim3((9*256*256+255)/256), 256, 0, stream>>>(gnn_merge_w, mrgTHi, mrgTLo);
    wconv_m1a<<<dim3((9*512*256+255)/256), 256, 0, stream>>>(gnn_mlp1_w, m1cHi, m1cLo);
    wconv_m1b<<<dim3((9*512*256+255)/256), 256, 0, stream>>>(gnn_mlp1_w, m1bHi, m1bLo);
    wconv_plain<<<dim3((9*256*512+255)/256), 256, 0, stream>>>(gnn_mlp2_w, m2Hi, m2Lo, 9L*256*512);
    wconv_plain<<<dim3((256*256+255)/256), 256, 0, stream>>>(final_w, finHi, finLo, 256L*256);
    bias_fold<<<dim3(9*512), 64, 0, stream>>>(gnn_mlp1_w, gnn_mlp1_b, gnn_merge_b, b1c);
    // combined mlp1 cols 256..511 = W1b x WmT^T per layer
    mfma_nt<128,128,1><<<dim3(2,4,9), 256, 0, stream>>>(
        (const short*)m1bHi, (const short*)m1bLo, 256,
        (const short*)mrgTHi, (const short*)mrgTLo, 256,
        256, 1.f, nullptr,
        nullptr, m1cHi + 256, m1cLo + 256, nullptr, nullptr, nullptr, nullptr, 512,
        512L*256, 256L*256, 512L*512);

    // ---- keypoint encoder -> descF (n-major) -> cat planes cols 0..255 ----
    kenc_kernel<<<dim3(Nc, Bc), 256, 0, stream>>>(kpts0, scores0, desc0, descF,
        kw0, kb0, kg0, ke0, kw1, kb1, kg1, ke1, kw2, kb2, kg2, ke2, kw3, kb3);
    kenc_kernel<<<dim3(Nc, Bc), 256, 0, stream>>>(kpts1, scores1, desc1, descF + 2L*Nc*256,
        kw0, kb0, kg0, ke0, kw1, kb1, kg1, ke1, kw2, kb2, kg2, ke2, kw3, kb3);
    rows_to_planes<<<dim3((unsigned)((ROWS*256+255)/256)), 256, 0, stream>>>(
        descF, 256, 256, catHi, catLo, 512, ROWS * 256);

    // ---- GNN layers ----
    for (int l = 0; l < 9; ++l) {
        // 1) qkv GEMM -> fragment-order Q/K/V
        mfma_nt<64,128,2><<<dim3(6,64,1), 256, 0, stream>>>(
            (const short*)catHi, (const short*)catLo, 512,
            (const short*)(projHi + (long)l*768*256), (const short*)(projLo + (long)l*768*256), 256,
            256, 1.f, projBp + (long)l*768,
            nullptr, qFh, qFl, vFh, vFl, kFh, kFl, 0,
            0, 0, 0);
        // 2) fused attention -> catbuf cols 256..511
        attn_fused<<<dim3(64, 16), 256, 0, stream>>>(qFh, qFl, kFh, kFl, vFh, vFl, catHi, catLo);
        // 3) mlp1 (M=4096, N=512, K=512) combined weights -> ybufF
        mfma_nt<64,128,0><<<dim3(4,64,1), 256, 0, stream>>>(
            (const short*)catHi, (const short*)catLo, 512,
            (const short*)(m1cHi + (long)l*512*512), (const short*)(m1cLo + (long)l*512*512), 512,
            512, 1.f, b1c + (long)l*512,
            ybufF, nullptr, nullptr, nullptr, nullptr, nullptr, nullptr, 512,
            0, 0, 0);
        // 4) LN+ReLU -> yb planes
        ln_relu_planes<<<dim3((unsigned)ROWS), 256, 0, stream>>>(
            ybufF, gnn_ln_g + (long)l*512, gnn_ln_b + (long)l*512, ybHi, ybLo);
        // 5) mlp2 fused residual -> descF + cat cols 0..255
        mfma_nt<64,64,3><<<dim3(4,64,1), 256, 0, stream>>>(
            (const short*)ybHi, (const short*)ybLo, 512,
            (const short*)(m2Hi + (long)l*256*512), (const short*)(m2Lo + (long)l*256*512), 512,
            512, 1.f, gnn_mlp2_b + (long)l*256,
            descF, catHi, catLo, nullptr, nullptr, nullptr, nullptr, 0,
            0, 0, 0);
    }

    // ---- final projection -> mdesc planes ----
    mfma_nt<64,64,1><<<dim3(4,64,1), 256, 0, stream>>>(
        (const short*)catHi, (const short*)catLo, 512,
        (const short*)finHi, (const short*)finLo, 256,
        256, 1.f, final_b,
        nullptr, mdHi, mdLo, nullptr, nullptr, nullptr, nullptr, 256,
        0, 0, 0);
    // ---- score matrix into Z (z = b) ----
    mfma_nt<128,128,0><<<dim3(8,8,2), 256, 0, stream>>>(
        (const short*)mdHi, (const short*)mdLo, 256,
        (const short*)mdHi + 2048L*256, (const short*)mdLo + 2048L*256, 256,
        256, 1.f/16.f, nullptr,
        Zm, nullptr, nullptr, nullptr, nullptr, nullptr, nullptr, NP1c,
        1024L*256, 1024L*256, (long)NP1c*NP1c);
    bins_fill<<<dim3(9,2), 256, 0, stream>>>(Zm, bin_score);

    // ---- Sinkhorn (log-space), 20 iterations ----
    transpose_np1<<<dim3(33,33,2), dim3(32,8), 0, stream>>>(Zm, ZT);
    zero_vec<<<dim3(9), 256, 0, stream>>>(vvec, Bc * NP1c);
    for (int it = 0; it < 20; ++it) {
        sinkhorn_lse<<<dim3(NP1c, Bc), 256, 0, stream>>>(Zm, vvec, uvec);
        sinkhorn_lse<<<dim3(NP1c, Bc), 256, 0, stream>>>(ZT, uvec, vvec);
    }
    final_out_k<<<dim3(NP1c, Bc), 256, 0, stream>>>(Zm, uvec, vvec, (float*)d_out);
}

// Round 7
// 1292.181 us; speedup vs baseline: 4.5346x; 1.1146x over previous
//
#include <hip/hip_runtime.h>
#include <hip/hip_bf16.h>
#include <math.h>

#define DEVI static __device__ __forceinline__

namespace {
constexpr int Bc   = 2;
constexpr int Nc   = 1024;
constexpr int Dc   = 256;
constexpr int NP1c = 1025;
constexpr float LN_EPS = 1e-6f;
constexpr float NORMV  = -7.6246189861593985f; // -log(2048)
constexpr float LOGNV  =  6.9314718055994531f; // log(1024)
}

typedef __attribute__((ext_vector_type(8))) short bf16x8;
typedef __attribute__((ext_vector_type(4))) float f32x4;

DEVI void split2(float v, __hip_bfloat16& h, __hip_bfloat16& l) {
    h = __float2bfloat16(v);
    l = __float2bfloat16(v - __bfloat162float(h));
}

// async global->LDS, 16B per lane
#define GLDS16(gp, lp) __builtin_amdgcn_global_load_lds( \
    (const __attribute__((address_space(1))) void*)(gp), \
    (__attribute__((address_space(3))) void*)(lp), 16, 0, 0)

// ---------------- helpers ----------------
DEVI float block_sum_256(float v, float* scratch) {
    int t = threadIdx.x;
    scratch[t] = v;
    __syncthreads();
    for (int s = 128; s > 0; s >>= 1) {
        if (t < s) scratch[t] += scratch[t + s];
        __syncthreads();
    }
    float r = scratch[0];
    __syncthreads();
    return r;
}

DEVI void ln_relu_inplace(float* x, const float* g, const float* be, int C, float* scratch) {
    int t = threadIdx.x;
    float v = (t < C) ? x[t] : 0.f;
    float mean = block_sum_256(v, scratch) / (float)C;
    float dv = (t < C) ? (x[t] - mean) : 0.f;
    float var = block_sum_256(dv * dv, scratch) / (float)(C - 1);
    float rstd = 1.f / (sqrtf(var) + LN_EPS);
    if (t < C) x[t] = fmaxf(g[t] * dv * rstd + be[t], 0.f);
    __syncthreads();
}

// ---------------- keypoint encoder (transposed, coalesced weights) ----------------
__global__ __launch_bounds__(256) void kenc_kernel(
    const float* __restrict__ kpts, const float* __restrict__ scr,
    const float* __restrict__ desc_in, float* __restrict__ desc_out,
    const float* __restrict__ w0, const float* __restrict__ b0,
    const float* __restrict__ g0, const float* __restrict__ be0,
    const float* __restrict__ w1T, const float* __restrict__ b1,
    const float* __restrict__ g1, const float* __restrict__ be1,
    const float* __restrict__ w2T, const float* __restrict__ b2,
    const float* __restrict__ g2, const float* __restrict__ be2,
    const float* __restrict__ w3T, const float* __restrict__ b3)
{
    __shared__ float xa[256], xb[256], scratch[256];
    const int n = blockIdx.x, b = blockIdx.y, t = threadIdx.x;
    if (t == 0) {
        float kx = kpts[((long)b * Nc + n) * 2 + 0];
        float ky = kpts[((long)b * Nc + n) * 2 + 1];
        xa[0] = (kx - 320.f) * (1.f / 448.f);
        xa[1] = (ky - 240.f) * (1.f / 448.f);
        xa[2] = scr[b * Nc + n];
    }
    __syncthreads();
    if (t < 32) { float a = b0[t]; for (int c = 0; c < 3;  ++c) a += w0[t*3 + c] * xa[c]; xb[t] = a; }
    __syncthreads();
    ln_relu_inplace(xb, g0, be0, 32, scratch);
    if (t < 64) {
        float a = b1[t];
        #pragma unroll 8
        for (int c = 0; c < 32;  ++c) a += w1T[c*64 + t] * xb[c];
        xa[t] = a;
    }
    __syncthreads();
    ln_relu_inplace(xa, g1, be1, 64, scratch);
    if (t < 128) {
        float a = b2[t];
        #pragma unroll 8
        for (int c = 0; c < 64;  ++c) a += w2T[c*128 + t] * xa[c];
        xb[t] = a;
    }
    __syncthreads();
    ln_relu_inplace(xb, g2, be2, 128, scratch);
    {   float a = b3[t];
        #pragma unroll 8
        for (int c = 0; c < 128; ++c) a += w3T[c*256 + t] * xb[c];
        desc_out[((long)b * Nc + n) * Dc + t] = desc_in[((long)b * Dc + t) * Nc + n] + a; }
}

__global__ __launch_bounds__(256) void transposeW(
    const float* __restrict__ src, float* __restrict__ dst, int O, int C)
{
    long i = (long)blockIdx.x * 256 + threadIdx.x;
    if (i >= (long)O * C) return;
    int o = (int)(i / C), c = (int)(i % C);
    dst[(long)c * O + o] = src[i];
}

// =======================================================================
// MFMA NT GEMM, hi/lo split A; B hi/lo (BLO=1, 3 MFMA) or hi-only (BLO=0, 2 MFMA).
// out[m][n] = scale*sum_k A[m][k]B[n][k] (+bias[n])
// EPI: 0 fp32 out; 1 bf16 planes; 2 qkv -> Q/K/V fragment-order; 3 mlp2 fused resid
// =======================================================================
template<int BM, int BN, int EPI, int BLO>
__global__ __launch_bounds__(256) void mfma_nt(
    const short* __restrict__ Ahi0, const short* __restrict__ Alo0, int lda,
    const short* __restrict__ Bhi0, const short* __restrict__ Blo0, int ldb,
    int K, float scale, const float* __restrict__ bias,
    float* __restrict__ outF, __hip_bfloat16* __restrict__ outHi,
    __hip_bfloat16* __restrict__ outLo,
    __hip_bfloat16* __restrict__ outHi2, __hip_bfloat16* __restrict__ outLo2,
    __hip_bfloat16* __restrict__ outHi3, __hip_bfloat16* __restrict__ outLo3,
    int ldo,
    long aS1, long bS1, long oS1)
{
    constexpr int MI = BM / 32;
    constexpr int NI = BN / 32;
    constexpr int instA = BM / 16, instB = BN / 16;
    constexpr int OFF_AH = 0;
    constexpr int OFF_AL = BM * 32;
    constexpr int OFF_BH = 2 * BM * 32;
    constexpr int OFF_BL = 2 * BM * 32 + BN * 32;  // used only when BLO
    __shared__ short smem[(2 * BM + (BLO ? 2 : 1) * BN) * 32];

    const int z = blockIdx.z;
    const long aOff = z * aS1, bOff = z * bS1, oOff = z * oS1;
    const short* Ah = Ahi0 + aOff; const short* Al = Alo0 + aOff;
    const short* Bh = Bhi0 + bOff; const short* Bl = BLO ? (Blo0 + bOff) : nullptr;

    const int m0 = blockIdx.y * BM, n0 = blockIdx.x * BN;
    const int t = threadIdx.x, lane = t & 63, wid = t >> 6;
    const int lr = lane & 15, lg = lane >> 4;
    const int wr = wid >> 1, wc = wid & 1;

    f32x4 acc[MI][NI];
    for (int mi = 0; mi < MI; ++mi)
        for (int ni = 0; ni < NI; ++ni)
            acc[mi][ni] = f32x4{0.f, 0.f, 0.f, 0.f};

    for (int k0 = 0; k0 < K; k0 += 32) {
        constexpr int total = 2 * instA + (BLO ? 2 : 1) * instB;
        for (int q = wid; q < total; q += 4) {
            const short* gsrc; int ldg, mi, ploff, row0;
            if (q < instA)               { gsrc = Ah; ldg = lda; mi = q;                 ploff = OFF_AH; row0 = m0; }
            else if (q < 2*instA)        { gsrc = Al; ldg = lda; mi = q - instA;         ploff = OFF_AL; row0 = m0; }
            else if (q < 2*instA+instB)  { gsrc = Bh; ldg = ldb; mi = q - 2*instA;       ploff = OFF_BH; row0 = n0; }
            else                         { gsrc = Bl; ldg = ldb; mi = q - 2*instA-instB; ploff = OFF_BL; row0 = n0; }
            const short* g = gsrc + (long)(row0 + mi * 16 + lr) * ldg + (k0 + lg * 8);
            GLDS16(g, smem + ploff + mi * 512);
        }
        __syncthreads();
        bf16x8 ah[MI], al[MI];
        #pragma unroll
        for (int mi = 0; mi < MI; ++mi) {
            ah[mi] = *(const bf16x8*)(smem + OFF_AH + ((wr * MI + mi) * 64 + lane) * 8);
            al[mi] = *(const bf16x8*)(smem + OFF_AL + ((wr * MI + mi) * 64 + lane) * 8);
        }
        #pragma unroll
        for (int ni = 0; ni < NI; ++ni) {
            bf16x8 bh = *(const bf16x8*)(smem + OFF_BH + ((wc * NI + ni) * 64 + lane) * 8);
            #pragma unroll
            for (int mi = 0; mi < MI; ++mi) {
                acc[mi][ni] = __builtin_amdgcn_mfma_f32_16x16x32_bf16(ah[mi], bh, acc[mi][ni], 0, 0, 0);
                acc[mi][ni] = __builtin_amdgcn_mfma_f32_16x16x32_bf16(al[mi], bh, acc[mi][ni], 0, 0, 0);
            }
            if (BLO) {
                bf16x8 bl = *(const bf16x8*)(smem + OFF_BL + ((wc * NI + ni) * 64 + lane) * 8);
                #pragma unroll
                for (int mi = 0; mi < MI; ++mi)
                    acc[mi][ni] = __builtin_amdgcn_mfma_f32_16x16x32_bf16(ah[mi], bl, acc[mi][ni], 0, 0, 0);
            }
        }
        __syncthreads();
    }

    for (int mi = 0; mi < MI; ++mi) {
        for (int i = 0; i < 4; ++i) {
            int row = m0 + wr * (BM / 2) + mi * 16 + lg * 4 + i;
            for (int ni = 0; ni < NI; ++ni) {
                int col = n0 + wc * (BN / 2) + ni * 16 + lr;
                float v = acc[mi][ni][i] * scale;
                if (bias) v += bias[col];
                if (EPI == 0) {
                    outF[(long)row * ldo + col + oOff] = v;
                } else if (EPI == 1) {
                    __hip_bfloat16 h, l;
                    split2(v, h, l);
                    outHi[(long)row * ldo + col + oOff] = h;
                    outLo[(long)row * ldo + col + oOff] = l;
                } else if (EPI == 2) {
                    // fragment-order scatter: Q/K -> [dh][nb][kc][lane][8]; V -> [dh][w][km][bi][lane][8]
                    int dirb = row >> 10, rloc = row & 1023;
                    int tq = col >> 8, within = col & 255;
                    int h4 = within >> 6, hd = within & 63;
                    __hip_bfloat16 hh, ll;
                    split2(v, hh, ll);
                    if (tq == 2) {
                        int w2 = rloc >> 8, mloc = rloc & 255;
                        int lane2 = ((mloc & 31) >> 3) * 16 + (hd & 15);
                        long idx = ((((long)(dirb*4+h4)*4 + w2)*8 + (mloc>>5))*4 + (hd>>4))*512 + lane2*8 + (mloc&7);
                        outHi2[idx] = hh; outLo2[idx] = ll;
                    } else {
                        int lane2 = ((hd & 31) >> 3) * 16 + (rloc & 15);
                        long idx = (((long)(dirb*4+h4)*64 + (rloc>>4))*2 + (hd>>5))*512 + lane2*8 + (hd&7);
                        if (tq == 0) { outHi[idx] = hh; outLo[idx] = ll; }
                        else         { outHi3[idx] = hh; outLo3[idx] = ll; }
                    }
                } else { // EPI==3: fused residual (descF) + cat planes cols 0..255
                    long i256 = (long)row * 256 + col;
                    v += outF[i256];
                    outF[i256] = v;
                    __hip_bfloat16 h, l;
                    split2(v, h, l);
                    outHi[(long)row * 512 + col] = h;
                    outLo[(long)row * 512 + col] = l;
                }
            }
        }
    }
}

// =======================================================================
// Fully fused attention, fragment-order Q/K/V inputs (coalesced base+lane*16B).
// =======================================================================
__global__ __launch_bounds__(256) void attn_fused(
    const __hip_bfloat16* __restrict__ qFh, const __hip_bfloat16* __restrict__ qFl,
    const __hip_bfloat16* __restrict__ kFh, const __hip_bfloat16* __restrict__ kFl,
    const __hip_bfloat16* __restrict__ vFh, const __hip_bfloat16* __restrict__ vFl,
    __hip_bfloat16* __restrict__ catHi, __hip_bfloat16* __restrict__ catLo)
{
    __shared__ short pLds[4 * 16 * 256];   // 32KB; reused as f32 partials
    __shared__ float redm[4][16], reds[4][16];
    const int y = blockIdx.y;
    const int dir = y >> 3, b = (y >> 2) & 1, h = y & 3;
    const int q0 = blockIdx.x * 16;
    const int t = threadIdx.x, lane = t & 63, w = t >> 6;
    const int lr = lane & 15, lg = lane >> 4;
    const int dbQ = dir * 2 + b;
    const int srcdb = (1 - dir) * 2 + b;
    const short* qh = (const short*)qFh; const short* ql = (const short*)qFl;
    const short* kh = (const short*)kFh; const short* kl = (const short*)kFl;
    const short* vh = (const short*)vFh; const short* vl = (const short*)vFl;

    const long qbase = (((long)(dbQ * 4 + h)) * 64 + (q0 >> 4)) * 2;
    bf16x8 ah[2], al[2];
    #pragma unroll
    for (int kc = 0; kc < 2; ++kc) {
        ah[kc] = *(const bf16x8*)(qh + (qbase + kc) * 512 + lane * 8);
        al[kc] = *(const bf16x8*)(ql + (qbase + kc) * 512 + lane * 8);
    }

    f32x4 acc[16];
    #pragma unroll
    for (int ni = 0; ni < 16; ++ni) acc[ni] = f32x4{0.f, 0.f, 0.f, 0.f};

    const long kbase0 = (((long)(srcdb * 4 + h)) * 64 + w * 16) * 2;
    #pragma unroll
    for (int ni = 0; ni < 16; ++ni) {
        long kb = (kbase0 + ni * 2) * 512 + lane * 8;
        bf16x8 bh0 = *(const bf16x8*)(kh + kb);
        bf16x8 bl0 = *(const bf16x8*)(kl + kb);
        bf16x8 bh1 = *(const bf16x8*)(kh + kb + 512);
        bf16x8 bl1 = *(const bf16x8*)(kl + kb + 512);
        acc[ni] = __builtin_amdgcn_mfma_f32_16x16x32_bf16(ah[0], bh0, acc[ni], 0, 0, 0);
        acc[ni] = __builtin_amdgcn_mfma_f32_16x16x32_bf16(ah[0], bl0, acc[ni], 0, 0, 0);
        acc[ni] = __builtin_amdgcn_mfma_f32_16x16x32_bf16(al[0], bh0, acc[ni], 0, 0, 0);
        acc[ni] = __builtin_amdgcn_mfma_f32_16x16x32_bf16(ah[1], bh1, acc[ni], 0, 0, 0);
        acc[ni] = __builtin_amdgcn_mfma_f32_16x16x32_bf16(ah[1], bl1, acc[ni], 0, 0, 0);
        acc[ni] = __builtin_amdgcn_mfma_f32_16x16x32_bf16(al[1], bh1, acc[ni], 0, 0, 0);
    }

    float mx[4] = {-1e30f, -1e30f, -1e30f, -1e30f};
    #pragma unroll
    for (int ni = 0; ni < 16; ++ni)
        #pragma unroll
        for (int i = 0; i < 4; ++i) {
            float v = acc[ni][i] * 0.125f;
            acc[ni][i] = v;
            mx[i] = fmaxf(mx[i], v);
        }
    #pragma unroll
    for (int off = 1; off < 16; off <<= 1)
        #pragma unroll
        for (int i = 0; i < 4; ++i) mx[i] = fmaxf(mx[i], __shfl_xor(mx[i], off));
    if (lr == 0)
        #pragma unroll
        for (int i = 0; i < 4; ++i) redm[w][lg * 4 + i] = mx[i];
    __syncthreads();
    float Mv[4];
    #pragma unroll
    for (int i = 0; i < 4; ++i)
        Mv[i] = fmaxf(fmaxf(redm[0][lg*4+i], redm[1][lg*4+i]),
                      fmaxf(redm[2][lg*4+i], redm[3][lg*4+i]));
    float sm[4] = {0.f, 0.f, 0.f, 0.f};
    #pragma unroll
    for (int ni = 0; ni < 16; ++ni)
        #pragma unroll
        for (int i = 0; i < 4; ++i) {
            float e = __expf(acc[ni][i] - Mv[i]);
            acc[ni][i] = e;
            sm[i] += e;
        }
    #pragma unroll
    for (int off = 1; off < 16; off <<= 1)
        #pragma unroll
        for (int i = 0; i < 4; ++i) sm[i] += __shfl_xor(sm[i], off);
    if (lr == 0)
        #pragma unroll
        for (int i = 0; i < 4; ++i) reds[w][lg * 4 + i] = sm[i];
    __syncthreads();
    float inv[4];
    #pragma unroll
    for (int i = 0; i < 4; ++i)
        inv[i] = 1.f / (reds[0][lg*4+i] + reds[1][lg*4+i] + reds[2][lg*4+i] + reds[3][lg*4+i]);

    char* pB = (char*)pLds + w * 8192;
    #pragma unroll
    for (int ni = 0; ni < 16; ++ni)
        #pragma unroll
        for (int i = 0; i < 4; ++i) {
            int q = lg * 4 + i, m = ni * 16 + lr;
            int byte = (q * 512 + m * 2) ^ ((q & 7) << 4);
            *(short*)(pB + byte) = (short)__bfloat16_as_ushort(__float2bfloat16(acc[ni][i] * inv[i]));
        }
    __syncthreads();

    f32x4 acc2[4];
    #pragma unroll
    for (int bi = 0; bi < 4; ++bi) acc2[bi] = f32x4{0.f, 0.f, 0.f, 0.f};
    const long vbase0 = (((long)(srcdb * 4 + h)) * 4 + w) * 8;
    #pragma unroll
    for (int km = 0; km < 8; ++km) {
        int rb = (lr * 512 + km * 64 + lg * 16) ^ ((lr & 7) << 4);
        bf16x8 pa = *(const bf16x8*)(pB + rb);
        #pragma unroll
        for (int bi = 0; bi < 4; ++bi) {
            long vr = ((vbase0 + km) * 4 + bi) * 512 + lane * 8;
            bf16x8 vhf = *(const bf16x8*)(vh + vr);
            bf16x8 vlf = *(const bf16x8*)(vl + vr);
            acc2[bi] = __builtin_amdgcn_mfma_f32_16x16x32_bf16(pa, vhf, acc2[bi], 0, 0, 0);
            acc2[bi] = __builtin_amdgcn_mfma_f32_16x16x32_bf16(pa, vlf, acc2[bi], 0, 0, 0);
        }
    }
    __syncthreads();
    float* pr = (float*)pLds;
    #pragma unroll
    for (int bi = 0; bi < 4; ++bi)
        #pragma unroll
        for (int i = 0; i < 4; ++i)
            pr[w * 1024 + (lg * 4 + i) * 64 + bi * 16 + lr] = acc2[bi][i];
    __syncthreads();
    #pragma unroll
    for (int k = 0; k < 4; ++k) {
        int e = t + k * 256;
        float v = pr[e] + pr[1024 + e] + pr[2048 + e] + pr[3072 + e];
        int q = e >> 6, d = e & 63;
        long a = ((long)dbQ * 1024 + q0 + q) * 512 + 256 + h * 64 + d;
        __hip_bfloat16 hh, ll; split2(v, hh, ll);
        catHi[a] = hh; catLo[a] = ll;
    }
}

// ---------------- fp32 rows -> bf16 hi/lo planes ----------------
__global__ __launch_bounds__(256) void rows_to_planes(
    const float* __restrict__ src, int ldsrc, int C,
    __hip_bfloat16* __restrict__ hi, __hip_bfloat16* __restrict__ lo, int ldp, long total)
{
    long idx = (long)blockIdx.x * 256 + threadIdx.x;
    if (idx >= total) return;
    long row = idx / C; int c = (int)(idx % C);
    float v = src[row * ldsrc + c];
    __hip_bfloat16 h, l; split2(v, h, l);
    hi[row * ldp + c] = h; lo[row * ldp + c] = l;
}

// ---------------- LN(channel,ddof=1,eps-on-std)+ReLU; write planes ----------------
__global__ __launch_bounds__(256) void ln_relu_planes(
    const float* __restrict__ y, const float* __restrict__ g, const float* __restrict__ be,
    __hip_bfloat16* __restrict__ hi, __hip_bfloat16* __restrict__ lo)
{
    __shared__ float s1[256], s2[256];
    const long row = blockIdx.x;
    const int t = threadIdx.x;
    const float* src = y + row * 512;
    float a = src[t], b = src[t + 256];
    s1[t] = a + b; s2[t] = a * a + b * b;
    __syncthreads();
    for (int s = 128; s > 0; s >>= 1) {
        if (t < s) { s1[t] += s1[t + s]; s2[t] += s2[t + s]; }
        __syncthreads();
    }
    float mean = s1[0] / 512.f;
    float var = fmaxf((s2[0] - 512.f * mean * mean) / 511.f, 0.f);
    float rstd = 1.f / (sqrtf(var) + LN_EPS);
    float v1 = fmaxf(g[t] * (a - mean) * rstd + be[t], 0.f);
    float v2 = fmaxf(g[t + 256] * (b - mean) * rstd + be[t + 256], 0.f);
    __hip_bfloat16 h, l;
    split2(v1, h, l); hi[row * 512 + t] = h;       lo[row * 512 + t] = l;
    split2(v2, h, l); hi[row * 512 + t + 256] = h; lo[row * 512 + t + 256] = l;
}

// ---------------- weight converts ----------------
__global__ __launch_bounds__(256) void wconv_plain(
    const float* __restrict__ w, __hip_bfloat16* __restrict__ hi, __hip_bfloat16* __restrict__ lo, long total)
{
    long i = (long)blockIdx.x * 256 + threadIdx.x;
    if (i >= total) return;
    __hip_bfloat16 h, l; split2(w[i], h, l);
    hi[i] = h; lo[i] = l;
}

__global__ __launch_bounds__(256) void wconv_proj(
    const float* __restrict__ w, __hip_bfloat16* __restrict__ hi, __hip_bfloat16* __restrict__ lo)
{
    long i = (long)blockIdx.x * 256 + threadIdx.x;
    if (i >= 9L * 768 * 256) return;
    long l9 = i / (768 * 256);
    int rem = (int)(i % (768 * 256));
    int op = rem / 256, c = rem % 256;
    int tq = op / 256, within = op % 256;
    int h = within / 64, hd = within % 64;
    int o = tq * 256 + hd * 4 + h;
    float v = w[(l9 * 768 + o) * 256 + c];
    __hip_bfloat16 hh, ll; split2(v, hh, ll);
    hi[i] = hh; lo[i] = ll;
}

__global__ void wconv_proj_bias(const float* __restrict__ b, float* __restrict__ bp)
{
    int i = blockIdx.x * 256 + threadIdx.x;
    if (i >= 9 * 768) return;
    int l9 = i / 768, op = i % 768;
    int tq = op / 256, within = op % 256;
    int h = within / 64, hd = within % 64;
    bp[i] = b[(l9 * 3 + tq) * 256 + hd * 4 + h];
}

// WmT planes: [l][c=h*64+hd][j] = Wm[l][j][hd*4+h]
__global__ __launch_bounds__(256) void wconv_mergeT(
    const float* __restrict__ w, __hip_bfloat16* __restrict__ hi, __hip_bfloat16* __restrict__ lo)
{
    long i = (long)blockIdx.x * 256 + threadIdx.x;
    if (i >= 9L * 256 * 256) return;
    long l9 = i / (256 * 256);
    int rem = (int)(i % (256 * 256));
    int c = rem / 256, j = rem % 256;
    int h = c / 64, hd = c % 64;
    float v = w[(l9 * 256 + j) * 256 + (hd * 4 + h)];
    __hip_bfloat16 hh, ll; split2(v, hh, ll);
    hi[i] = hh; lo[i] = ll;
}

// mlp1 W cols 0..255 -> m1c planes [l*512+o][512] cols 0..255
__global__ __launch_bounds__(256) void wconv_m1a(
    const float* __restrict__ w, __hip_bfloat16* __restrict__ hi, __hip_bfloat16* __restrict__ lo)
{
    long i = (long)blockIdx.x * 256 + threadIdx.x;
    if (i >= 9L * 512 * 256) return;
    long lo9 = i / 256;
    int c = (int)(i % 256);
    float v = w[lo9 * 512 + c];
    __hip_bfloat16 hh, ll; split2(v, hh, ll);
    hi[lo9 * 512 + c] = hh; lo[lo9 * 512 + c] = ll;
}

// mlp1 W cols 256..511 -> m1b planes [l*512+o][256]
__global__ __launch_bounds__(256) void wconv_m1b(
    const float* __restrict__ w, __hip_bfloat16* __restrict__ hi, __hip_bfloat16* __restrict__ lo)
{
    long i = (long)blockIdx.x * 256 + threadIdx.x;
    if (i >= 9L * 512 * 256) return;
    long lo9 = i / 256;
    int c = (int)(i % 256);
    float v = w[lo9 * 512 + 256 + c];
    __hip_bfloat16 hh, ll; split2(v, hh, ll);
    hi[i] = hh; lo[i] = ll;
}

// b1c[l*512+o] = b1[l][o] + sum_j W1[l][o][256+j]*bm[l][j]
__global__ __launch_bounds__(64) void bias_fold(
    const float* __restrict__ w1, const float* __restrict__ b1,
    const float* __restrict__ bm, float* __restrict__ out)
{
    int og = blockIdx.x;
    int l = og >> 9, o = og & 511;
    int t = threadIdx.x;
    float s = 0.f;
    for (int j = t; j < 256; j += 64)
        s += w1[((long)l * 512 + o) * 512 + 256 + j] * bm[l * 256 + j];
    for (int off = 32; off > 0; off >>= 1) s += __shfl_down(s, off);
    if (t == 0) out[og] = b1[(long)l * 512 + o] + s;
}

// ---------------- Sinkhorn pieces ----------------
__global__ void bins_fill(float* __restrict__ Z, const float* __restrict__ alpha_p)
{
    float alpha = alpha_p[0];
    int idx = blockIdx.x * 256 + threadIdx.x;
    int b = blockIdx.y;
    float* Zb = Z + (long)b * NP1c * NP1c;
    if (idx < NP1c) Zb[(long)1024 * NP1c + idx] = alpha;
    else { int i = idx - NP1c; if (i < 1024) Zb[(long)i * NP1c + 1024] = alpha; }
}

__global__ void transpose_np1(const float* __restrict__ Z, float* __restrict__ ZT)
{
    __shared__ float tile[32][33];
    int b = blockIdx.z;
    int i0 = blockIdx.y * 32, j0 = blockIdx.x * 32;
    int tx = threadIdx.x, ty = threadIdx.y;
    const float* Zb = Z + (long)b * NP1c * NP1c;
    float* Tb = ZT + (long)b * NP1c * NP1c;
    for (int ii = ty; ii < 32; ii += 8) {
        int i = i0 + ii, j = j0 + tx;
        if (i < NP1c && j < NP1c) tile[ii][tx] = Zb[(long)i * NP1c + j];
    }
    __syncthreads();
    for (int jj = ty; jj < 32; jj += 8) {
        int j = j0 + jj, i = i0 + tx;
        if (j < NP1c && i < NP1c) Tb[(long)j * NP1c + i] = tile[tx][jj];
    }
}

__global__ void zero_vec(float* __restrict__ v, int n)
{
    int i = blockIdx.x * 256 + threadIdx.x;
    if (i < n) v[i] = 0.f;
}

__global__ __launch_bounds__(256) void sinkhorn_lse(
    const float* __restrict__ M, const float* __restrict__ addv, float* __restrict__ outv)
{
    __shared__ float sm[256], ss[256];
    const int i = blockIdx.x, b = blockIdx.y, t = threadIdx.x;
    const float* row = M + ((long)b * NP1c + i) * NP1c;
    const float* av = addv + b * NP1c;
    float m = -1e30f, s = 0.f;
    for (int j = t; j < NP1c; j += 256) {
        float xv = row[j] + av[j];
        if (xv > m) { s = s * __expf(m - xv) + 1.f; m = xv; }
        else s += __expf(xv - m);
    }
    sm[t] = m; ss[t] = s;
    __syncthreads();
    for (int st = 128; st > 0; st >>= 1) {
        if (t < st) {
            float m1 = sm[t], s1 = ss[t], m2 = sm[t + st], s2 = ss[t + st];
            float mm = fmaxf(m1, m2);
            sm[t] = mm;
            ss[t] = s1 * __expf(m1 - mm) + s2 * __expf(m2 - mm);
        }
        __syncthreads();
    }
    if (t == 0) {
        float lse = sm[0] + __logf(ss[0]);
        float lmu = (i < 1024) ? NORMV : (LOGNV + NORMV);
        outv[b * NP1c + i] = lmu - lse;
    }
}

__global__ __launch_bounds__(256) void final_out_k(
    const float* __restrict__ Z, const float* __restrict__ u,
    const float* __restrict__ v, float* __restrict__ outp)
{
    const int i = blockIdx.x, b = blockIdx.y, t = threadIdx.x;
    const float* row = Z + ((long)b * NP1c + i) * NP1c;
    float* orow = outp + ((long)b * NP1c + i) * NP1c;
    float ui = u[b * NP1c + i];
    for (int j = t; j < NP1c; j += 256)
        orow[j] = row[j] + ui + v[b * NP1c + j] - NORMV;
}

// =======================================================================
extern "C" void kernel_launch(void* const* d_in, const int* in_sizes, int n_in,
                              void* d_out, int out_size, void* d_ws, size_t ws_size,
                              hipStream_t stream)
{
    (void)in_sizes; (void)n_in; (void)out_size; (void)ws_size;
    const float* kpts0   = (const float*)d_in[0];
    const float* kpts1   = (const float*)d_in[1];
    const float* scores0 = (const float*)d_in[2];
    const float* scores1 = (const float*)d_in[3];
    const float* desc0   = (const float*)d_in[4];
    const float* desc1   = (const float*)d_in[5];
    const float* kw0 = (const float*)d_in[6];  const float* kb0 = (const float*)d_in[7];
    const float* kg0 = (const float*)d_in[8];  const float* ke0 = (const float*)d_in[9];
    const float* kw1 = (const float*)d_in[10]; const float* kb1 = (const float*)d_in[11];
    const float* kg1 = (const float*)d_in[12]; const float* ke1 = (const float*)d_in[13];
    const float* kw2 = (const float*)d_in[14]; const float* kb2 = (const float*)d_in[15];
    const float* kg2 = (const float*)d_in[16]; const float* ke2 = (const float*)d_in[17];
    const float* kw3 = (const float*)d_in[18]; const float* kb3 = (const float*)d_in[19];
    const float* gnn_proj_w  = (const float*)d_in[20];
    const float* gnn_proj_b  = (const float*)d_in[21];
    const float* gnn_merge_w = (const float*)d_in[22];
    const float* gnn_merge_b = (const float*)d_in[23];
    const float* gnn_mlp1_w  = (const float*)d_in[24];
    const float* gnn_mlp1_b  = (const float*)d_in[25];
    const float* gnn_ln_g    = (const float*)d_in[26];
    const float* gnn_ln_b    = (const float*)d_in[27];
    const float* gnn_mlp2_w  = (const float*)d_in[28];
    const float* gnn_mlp2_b  = (const float*)d_in[29];
    const float* final_w     = (const float*)d_in[30];
    const float* final_b     = (const float*)d_in[31];
    const float* bin_score   = (const float*)d_in[32];

    char* wsb = (char*)d_ws;
    size_t off = 0;
    auto alloc = [&](size_t bytes) -> void* {
        void* p = wsb + off;
        off = (off + bytes + 255) & ~(size_t)255;
        return p;
    };
    typedef __hip_bfloat16 bf;
    const long ROWS = 4L * Nc;
    // fp32
    float* descF  = (float*)alloc(ROWS * 256 * 4);
    float* ybufF  = (float*)alloc(ROWS * 512 * 4);
    float* Zm     = (float*)alloc((long)Bc * NP1c * NP1c * 4);
    float* ZT     = (float*)alloc((long)Bc * NP1c * NP1c * 4);
    float* uvec   = (float*)alloc(Bc * NP1c * 4);
    float* vvec   = (float*)alloc(Bc * NP1c * 4);
    float* projBp = (float*)alloc(9L * 768 * 4);
    float* b1c    = (float*)alloc(9L * 512 * 4);
    float* kw1T   = (float*)alloc(32L * 64 * 4);
    float* kw2T   = (float*)alloc(64L * 128 * 4);
    float* kw3T   = (float*)alloc(128L * 256 * 4);
    // activation planes
    bf* catHi = (bf*)alloc(ROWS * 512 * 2);  bf* catLo = (bf*)alloc(ROWS * 512 * 2);
    bf* qFh = (bf*)alloc(1048576 * 2); bf* qFl = (bf*)alloc(1048576 * 2);
    bf* kFh = (bf*)alloc(1048576 * 2); bf* kFl = (bf*)alloc(1048576 * 2);
    bf* vFh = (bf*)alloc(1048576 * 2); bf* vFl = (bf*)alloc(1048576 * 2);
    bf* ybHi  = (bf*)alloc(ROWS * 512 * 2);  bf* ybLo  = (bf*)alloc(ROWS * 512 * 2);
    bf* mdHi  = (bf*)alloc(ROWS * 256 * 2);  bf* mdLo  = (bf*)alloc(ROWS * 256 * 2);
    // weight planes
    bf* projHi = (bf*)alloc(9L*768*256*2);   bf* projLo = (bf*)alloc(9L*768*256*2);
    bf* mrgTHi = (bf*)alloc(9L*256*256*2);   bf* mrgTLo = (bf*)alloc(9L*256*256*2);
    bf* m1bHi  = (bf*)alloc(9L*512*256*2);   bf* m1bLo  = (bf*)alloc(9L*512*256*2);
    bf* m1cHi  = (bf*)alloc(9L*512*512*2);   bf* m1cLo  = (bf*)alloc(9L*512*512*2);
    bf* m2Hi   = (bf*)alloc(9L*256*512*2);   bf* m2Lo   = (bf*)alloc(9L*256*512*2);
    bf* finHi  = (bf*)alloc(256L*256*2);     bf* finLo  = (bf*)alloc(256L*256*2);

    // ---- weight prep ----
    wconv_proj<<<dim3((9*768*256+255)/256), 256, 0, stream>>>(gnn_proj_w, projHi, projLo);
    wconv_proj_bias<<<dim3(27), 256, 0, stream>>>(gnn_proj_b, projBp);
    wconv_mergeT<<<dim3((9*256*256+255)/256), 256, 0, stream>>>(gnn_merge_w, mrgTHi, mrgTLo);
    wconv_m1a<<<dim3((9*512*256+255)/256), 256, 0, stream>>>(gnn_mlp1_w, m1cHi, m1cLo);
    wconv_m1b<<<dim3((9*512*256+255)/256), 256, 0, stream>>>(gnn_mlp1_w, m1bHi, m1bLo);
    wconv_plain<<<dim3((9*256*512+255)/256), 256, 0, stream>>>(gnn_mlp2_w, m2Hi, m2Lo, 9L*256*512);
    wconv_plain<<<dim3((256*256+255)/256), 256, 0, stream>>>(final_w, finHi, finLo, 256L*256);
    bias_fold<<<dim3(9*512), 64, 0, stream>>>(gnn_mlp1_w, gnn_mlp1_b, gnn_merge_b, b1c);
    transposeW<<<dim3((64*32+255)/256), 256, 0, stream>>>(kw1, kw1T, 64, 32);
    transposeW<<<dim3((128*64+255)/256), 256, 0, stream>>>(kw2, kw2T, 128, 64);
    transposeW<<<dim3((256*128+255)/256), 256, 0, stream>>>(kw3, kw3T, 256, 128);
    // combined mlp1 cols 256..511 = W1b x WmT^T per layer (full hi/lo accuracy)
    mfma_nt<128,128,1,1><<<dim3(2,4,9), 256, 0, stream>>>(
        (const short*)m1bHi, (const short*)m1bLo, 256,
        (const short*)mrgTHi, (const short*)mrgTLo, 256,
        256, 1.f, nullptr,
        nullptr, m1cHi + 256, m1cLo + 256, nullptr, nullptr, nullptr, nullptr, 512,
        512L*256, 256L*256, 512L*512);

    // ---- keypoint encoder -> descF (n-major) -> cat planes cols 0..255 ----
    kenc_kernel<<<dim3(Nc, Bc), 256, 0, stream>>>(kpts0, scores0, desc0, descF,
        kw0, kb0, kg0, ke0, kw1T, kb1, kg1, ke1, kw2T, kb2, kg2, ke2, kw3T, kb3);
    kenc_kernel<<<dim3(Nc, Bc), 256, 0, stream>>>(kpts1, scores1, desc1, descF + 2L*Nc*256,
        kw0, kb0, kg0, ke0, kw1T, kb1, kg1, ke1, kw2T, kb2, kg2, ke2, kw3T, kb3);
    rows_to_planes<<<dim3((unsigned)((ROWS*256+255)/256)), 256, 0, stream>>>(
        descF, 256, 256, catHi, catLo, 512, ROWS * 256);

    // ---- GNN layers ----
    for (int l = 0; l < 9; ++l) {
        // 1) qkv GEMM (W hi-only) -> fragment-order Q/K/V
        mfma_nt<64,128,2,0><<<dim3(6,64,1), 256, 0, stream>>>(
            (const short*)catHi, (const short*)catLo, 512,
            (const short*)(projHi + (long)l*768*256), nullptr, 256,
            256, 1.f, projBp + (long)l*768,
            nullptr, qFh, qFl, vFh, vFl, kFh, kFl, 0,
            0, 0, 0);
        // 2) fused attention -> catbuf cols 256..511
        attn_fused<<<dim3(64, 16), 256, 0, stream>>>(qFh, qFl, kFh, kFl, vFh, vFl, catHi, catLo);
        // 3) mlp1 (W hi-only, combined weights) -> ybufF
        mfma_nt<64,128,0,0><<<dim3(4,64,1), 256, 0, stream>>>(
            (const short*)catHi, (const short*)catLo, 512,
            (const short*)(m1cHi + (long)l*512*512), nullptr, 512,
            512, 1.f, b1c + (long)l*512,
            ybufF, nullptr, nullptr, nullptr, nullptr, nullptr, nullptr, 512,
            0, 0, 0);
        // 4) LN+ReLU -> yb planes
        ln_relu_planes<<<dim3((unsigned)ROWS), 256, 0, stream>>>(
            ybufF, gnn_ln_g + (long)l*512, gnn_ln_b + (long)l*512, ybHi, ybLo);
        // 5) mlp2 (W hi-only) fused residual -> descF + cat cols 0..255
        mfma_nt<64,64,3,0><<<dim3(4,64,1), 256, 0, stream>>>(
            (const short*)ybHi, (const short*)ybLo, 512,
            (const short*)(m2Hi + (long)l*256*512), nullptr, 512,
            512, 1.f, gnn_mlp2_b + (long)l*256,
            descF, catHi, catLo, nullptr, nullptr, nullptr, nullptr, 0,
            0, 0, 0);
    }

    // ---- final projection (W hi-only) -> mdesc planes ----
    mfma_nt<64,64,1,0><<<dim3(4,64,1), 256, 0, stream>>>(
        (const short*)catHi, (const short*)catLo, 512,
        (const short*)finHi, nullptr, 256,
        256, 1.f, final_b,
        nullptr, mdHi, mdLo, nullptr, nullptr, nullptr, nullptr, 256,
        0, 0, 0);
    // ---- score matrix into Z (activation x activation: full hi/lo) ----
    mfma_nt<128,128,0,1><<<dim3(8,8,2), 256, 0, stream>>>(
        (const short*)mdHi, (const short*)mdLo, 256,
        (const short*)mdHi + 2048L*256, (const short*)mdLo + 2048L*256, 256,
        256, 1.f/16.f, nullptr,
        Zm, nullptr, nullptr, nullptr, nullptr, nullptr, nullptr, NP1c,
        1024L*256, 1024L*256, (long)NP1c*NP1c);
    bins_fill<<<dim3(9,2), 256, 0, stream>>>(Zm, bin_score);

    // ---- Sinkhorn (log-space), 20 iterations ----
    transpose_np1<<<dim3(33,33,2), dim3(32,8), 0, stream>>>(Zm, ZT);
    zero_vec<<<dim3(9), 256, 0, stream>>>(vvec, Bc * NP1c);
    for (int it = 0; it < 20; ++it) {
        sinkhorn_lse<<<dim3(NP1c, Bc), 256, 0, stream>>>(Zm, vvec, uvec);
        sinkhorn_lse<<<dim3(NP1c, Bc), 256, 0, stream>>>(ZT, uvec, vvec);
    }
    final_out_k<<<dim3(NP1c, Bc), 256, 0, stream>>>(Zm, uvec, vvec, (float*)d_out);
}

// Round 8
// 1106.745 us; speedup vs baseline: 5.2943x; 1.1676x over previous
//
#include <hip/hip_runtime.h>
#include <hip/hip_bf16.h>
#include <math.h>

#define DEVI static __device__ __forceinline__

namespace {
constexpr int Bc   = 2;
constexpr int Nc   = 1024;
constexpr int Dc   = 256;
constexpr int NP1c = 1025;
constexpr float LN_EPS = 1e-6f;
constexpr float NORMV  = -7.6246189861593985f; // -log(2048)
constexpr float LOGNV  =  6.9314718055994531f; // log(1024)
}

typedef __attribute__((ext_vector_type(8))) short bf16x8;
typedef __attribute__((ext_vector_type(4))) float f32x4;

DEVI void split2(float v, __hip_bfloat16& h, __hip_bfloat16& l) {
    h = __float2bfloat16(v);
    l = __float2bfloat16(v - __bfloat162float(h));
}

// async global->LDS, 16B per lane
#define GLDS16(gp, lp) __builtin_amdgcn_global_load_lds( \
    (const __attribute__((address_space(1))) void*)(gp), \
    (__attribute__((address_space(3))) void*)(lp), 16, 0, 0)

// ---------------- helpers ----------------
DEVI float block_sum_256(float v, float* scratch) {
    int t = threadIdx.x;
    scratch[t] = v;
    __syncthreads();
    for (int s = 128; s > 0; s >>= 1) {
        if (t < s) scratch[t] += scratch[t + s];
        __syncthreads();
    }
    float r = scratch[0];
    __syncthreads();
    return r;
}

DEVI void ln_relu_inplace(float* x, const float* g, const float* be, int C, float* scratch) {
    int t = threadIdx.x;
    float v = (t < C) ? x[t] : 0.f;
    float mean = block_sum_256(v, scratch) / (float)C;
    float dv = (t < C) ? (x[t] - mean) : 0.f;
    float var = block_sum_256(dv * dv, scratch) / (float)(C - 1);
    float rstd = 1.f / (sqrtf(var) + LN_EPS);
    if (t < C) x[t] = fmaxf(g[t] * dv * rstd + be[t], 0.f);
    __syncthreads();
}

// ---------------- keypoint encoder (coalesced weights; writes cat planes) ----------------
__global__ __launch_bounds__(256) void kenc_kernel(
    const float* __restrict__ kpts, const float* __restrict__ scr,
    const float* __restrict__ desc_in, float* __restrict__ desc_out,
    __hip_bfloat16* __restrict__ catHi, __hip_bfloat16* __restrict__ catLo,
    const float* __restrict__ w0, const float* __restrict__ b0,
    const float* __restrict__ g0, const float* __restrict__ be0,
    const float* __restrict__ w1T, const float* __restrict__ b1,
    const float* __restrict__ g1, const float* __restrict__ be1,
    const float* __restrict__ w2T, const float* __restrict__ b2,
    const float* __restrict__ g2, const float* __restrict__ be2,
    const float* __restrict__ w3T, const float* __restrict__ b3)
{
    __shared__ float xa[256], xb[256], scratch[256];
    const int n = blockIdx.x, b = blockIdx.y, t = threadIdx.x;
    if (t == 0) {
        float kx = kpts[((long)b * Nc + n) * 2 + 0];
        float ky = kpts[((long)b * Nc + n) * 2 + 1];
        xa[0] = (kx - 320.f) * (1.f / 448.f);
        xa[1] = (ky - 240.f) * (1.f / 448.f);
        xa[2] = scr[b * Nc + n];
    }
    __syncthreads();
    if (t < 32) { float a = b0[t]; for (int c = 0; c < 3;  ++c) a += w0[t*3 + c] * xa[c]; xb[t] = a; }
    __syncthreads();
    ln_relu_inplace(xb, g0, be0, 32, scratch);
    if (t < 64) {
        float a = b1[t];
        #pragma unroll 8
        for (int c = 0; c < 32;  ++c) a += w1T[c*64 + t] * xb[c];
        xa[t] = a;
    }
    __syncthreads();
    ln_relu_inplace(xa, g1, be1, 64, scratch);
    if (t < 128) {
        float a = b2[t];
        #pragma unroll 8
        for (int c = 0; c < 64;  ++c) a += w2T[c*128 + t] * xa[c];
        xb[t] = a;
    }
    __syncthreads();
    ln_relu_inplace(xb, g2, be2, 128, scratch);
    {   float a = b3[t];
        #pragma unroll 8
        for (int c = 0; c < 128; ++c) a += w3T[c*256 + t] * xb[c];
        float v = desc_in[((long)b * Dc + t) * Nc + n] + a;
        desc_out[((long)b * Nc + n) * Dc + t] = v;
        __hip_bfloat16 h, l; split2(v, h, l);
        long cr = ((long)b * Nc + n) * 512 + t;
        catHi[cr] = h; catLo[cr] = l;
    }
}

__global__ __launch_bounds__(256) void transposeW(
    const float* __restrict__ src, float* __restrict__ dst, int O, int C)
{
    long i = (long)blockIdx.x * 256 + threadIdx.x;
    if (i >= (long)O * C) return;
    int o = (int)(i / C), c = (int)(i % C);
    dst[(long)c * O + o] = src[i];
}

// =======================================================================
// MFMA NT GEMM, BK=64 double-chunk K-loop. A hi/lo; B hi/lo (BLO=1) or hi (BLO=0).
// EPI: 0 fp32 out; 1 bf16 planes; 2 qkv -> Q(hi/lo)/K(hi)/V(hi) fragment-order;
//      3 mlp2 fused resid. K must be a multiple of 64.
// =======================================================================
template<int BM, int BN, int EPI, int BLO>
__global__ __launch_bounds__(256) void mfma_nt(
    const short* __restrict__ Ahi0, const short* __restrict__ Alo0, int lda,
    const short* __restrict__ Bhi0, const short* __restrict__ Blo0, int ldb,
    int K, float scale, const float* __restrict__ bias,
    float* __restrict__ outF, __hip_bfloat16* __restrict__ outHi,
    __hip_bfloat16* __restrict__ outLo,
    __hip_bfloat16* __restrict__ outHi2, __hip_bfloat16* __restrict__ outHi3,
    int ldo,
    long aS1, long bS1, long oS1)
{
    constexpr int MI = BM / 32;
    constexpr int NI = BN / 32;
    constexpr int instA = BM / 16, instB = BN / 16;
    constexpr int OFF_AH = 0;
    constexpr int OFF_AL = BM * 32;
    constexpr int OFF_BH = 2 * BM * 32;
    constexpr int OFF_BL = 2 * BM * 32 + BN * 32;  // used only when BLO
    constexpr int CHUNK = (2 * BM + (BLO ? 2 : 1) * BN) * 32;
    __shared__ short smem[2 * CHUNK];

    const int z = blockIdx.z;
    const long aOff = z * aS1, bOff = z * bS1, oOff = z * oS1;
    const short* Ah = Ahi0 + aOff; const short* Al = Alo0 + aOff;
    const short* Bh = Bhi0 + bOff; const short* Bl = BLO ? (Blo0 + bOff) : nullptr;

    const int m0 = blockIdx.y * BM, n0 = blockIdx.x * BN;
    const int t = threadIdx.x, lane = t & 63, wid = t >> 6;
    const int lr = lane & 15, lg = lane >> 4;
    const int wr = wid >> 1, wc = wid & 1;

    f32x4 acc[MI][NI];
    for (int mi = 0; mi < MI; ++mi)
        for (int ni = 0; ni < NI; ++ni)
            acc[mi][ni] = f32x4{0.f, 0.f, 0.f, 0.f};

    for (int k0 = 0; k0 < K; k0 += 64) {
        constexpr int total = 2 * instA + (BLO ? 2 : 1) * instB;
        for (int q = wid; q < total; q += 4) {
            const short* gsrc; int ldg, mi, ploff, row0;
            if (q < instA)               { gsrc = Ah; ldg = lda; mi = q;                 ploff = OFF_AH; row0 = m0; }
            else if (q < 2*instA)        { gsrc = Al; ldg = lda; mi = q - instA;         ploff = OFF_AL; row0 = m0; }
            else if (q < 2*instA+instB)  { gsrc = Bh; ldg = ldb; mi = q - 2*instA;       ploff = OFF_BH; row0 = n0; }
            else                         { gsrc = Bl; ldg = ldb; mi = q - 2*instA-instB; ploff = OFF_BL; row0 = n0; }
            const short* g = gsrc + (long)(row0 + mi * 16 + lr) * ldg + (k0 + lg * 8);
            GLDS16(g,      smem + ploff + mi * 512);
            GLDS16(g + 32, smem + CHUNK + ploff + mi * 512);
        }
        __syncthreads();
        #pragma unroll
        for (int kc2 = 0; kc2 < 2; ++kc2) {
            const short* sm2 = smem + kc2 * CHUNK;
            bf16x8 ah[MI], al[MI];
            #pragma unroll
            for (int mi = 0; mi < MI; ++mi) {
                ah[mi] = *(const bf16x8*)(sm2 + OFF_AH + ((wr * MI + mi) * 64 + lane) * 8);
                al[mi] = *(const bf16x8*)(sm2 + OFF_AL + ((wr * MI + mi) * 64 + lane) * 8);
            }
            #pragma unroll
            for (int ni = 0; ni < NI; ++ni) {
                bf16x8 bh = *(const bf16x8*)(sm2 + OFF_BH + ((wc * NI + ni) * 64 + lane) * 8);
                #pragma unroll
                for (int mi = 0; mi < MI; ++mi) {
                    acc[mi][ni] = __builtin_amdgcn_mfma_f32_16x16x32_bf16(ah[mi], bh, acc[mi][ni], 0, 0, 0);
                    acc[mi][ni] = __builtin_amdgcn_mfma_f32_16x16x32_bf16(al[mi], bh, acc[mi][ni], 0, 0, 0);
                }
                if (BLO) {
                    bf16x8 bl = *(const bf16x8*)(sm2 + OFF_BL + ((wc * NI + ni) * 64 + lane) * 8);
                    #pragma unroll
                    for (int mi = 0; mi < MI; ++mi)
                        acc[mi][ni] = __builtin_amdgcn_mfma_f32_16x16x32_bf16(ah[mi], bl, acc[mi][ni], 0, 0, 0);
                }
            }
        }
        __syncthreads();
    }

    for (int mi = 0; mi < MI; ++mi) {
        for (int i = 0; i < 4; ++i) {
            int row = m0 + wr * (BM / 2) + mi * 16 + lg * 4 + i;
            for (int ni = 0; ni < NI; ++ni) {
                int col = n0 + wc * (BN / 2) + ni * 16 + lr;
                float v = acc[mi][ni][i] * scale;
                if (bias) v += bias[col];
                if (EPI == 0) {
                    outF[(long)row * ldo + col + oOff] = v;
                } else if (EPI == 1) {
                    __hip_bfloat16 h, l;
                    split2(v, h, l);
                    outHi[(long)row * ldo + col + oOff] = h;
                    outLo[(long)row * ldo + col + oOff] = l;
                } else if (EPI == 2) {
                    // Q -> hi/lo frag order; K,V -> hi-only frag order
                    int dirb = row >> 10, rloc = row & 1023;
                    int tq = col >> 8, within = col & 255;
                    int h4 = within >> 6, hd = within & 63;
                    __hip_bfloat16 hh, ll;
                    split2(v, hh, ll);
                    if (tq == 2) {
                        int w2 = rloc >> 8, mloc = rloc & 255;
                        int lane2 = ((mloc & 31) >> 3) * 16 + (hd & 15);
                        long idx = ((((long)(dirb*4+h4)*4 + w2)*8 + (mloc>>5))*4 + (hd>>4))*512 + lane2*8 + (mloc&7);
                        outHi2[idx] = hh;
                    } else {
                        int lane2 = ((hd & 31) >> 3) * 16 + (rloc & 15);
                        long idx = (((long)(dirb*4+h4)*64 + (rloc>>4))*2 + (hd>>5))*512 + lane2*8 + (hd&7);
                        if (tq == 0) { outHi[idx] = hh; outLo[idx] = ll; }
                        else         { outHi3[idx] = hh; }
                    }
                } else { // EPI==3: fused residual (descF) + cat planes cols 0..255
                    long i256 = (long)row * 256 + col;
                    v += outF[i256];
                    outF[i256] = v;
                    __hip_bfloat16 h, l;
                    split2(v, h, l);
                    outHi[(long)row * 512 + col] = h;
                    outLo[(long)row * 512 + col] = l;
                }
            }
        }
    }
}

// =======================================================================
// Fully fused attention. Q hi/lo; K,V hi-only. Fragment-order coalesced loads.
// =======================================================================
__global__ __launch_bounds__(256) void attn_fused(
    const __hip_bfloat16* __restrict__ qFh, const __hip_bfloat16* __restrict__ qFl,
    const __hip_bfloat16* __restrict__ kFh, const __hip_bfloat16* __restrict__ vFh,
    __hip_bfloat16* __restrict__ catHi, __hip_bfloat16* __restrict__ catLo)
{
    __shared__ short pLds[4 * 16 * 256];   // 32KB; reused as f32 partials
    __shared__ float redm[4][16], reds[4][16];
    const int y = blockIdx.y;
    const int dir = y >> 3, b = (y >> 2) & 1, h = y & 3;
    const int q0 = blockIdx.x * 16;
    const int t = threadIdx.x, lane = t & 63, w = t >> 6;
    const int lr = lane & 15, lg = lane >> 4;
    const int dbQ = dir * 2 + b;
    const int srcdb = (1 - dir) * 2 + b;
    const short* qh = (const short*)qFh; const short* ql = (const short*)qFl;
    const short* kh = (const short*)kFh;
    const short* vh = (const short*)vFh;

    const long qbase = (((long)(dbQ * 4 + h)) * 64 + (q0 >> 4)) * 2;
    bf16x8 ah[2], al[2];
    #pragma unroll
    for (int kc = 0; kc < 2; ++kc) {
        ah[kc] = *(const bf16x8*)(qh + (qbase + kc) * 512 + lane * 8);
        al[kc] = *(const bf16x8*)(ql + (qbase + kc) * 512 + lane * 8);
    }

    f32x4 acc[16];
    #pragma unroll
    for (int ni = 0; ni < 16; ++ni) acc[ni] = f32x4{0.f, 0.f, 0.f, 0.f};

    const long kbase0 = (((long)(srcdb * 4 + h)) * 64 + w * 16) * 2;
    #pragma unroll
    for (int ni = 0; ni < 16; ++ni) {
        long kb = (kbase0 + ni * 2) * 512 + lane * 8;
        bf16x8 bh0 = *(const bf16x8*)(kh + kb);
        bf16x8 bh1 = *(const bf16x8*)(kh + kb + 512);
        acc[ni] = __builtin_amdgcn_mfma_f32_16x16x32_bf16(ah[0], bh0, acc[ni], 0, 0, 0);
        acc[ni] = __builtin_amdgcn_mfma_f32_16x16x32_bf16(al[0], bh0, acc[ni], 0, 0, 0);
        acc[ni] = __builtin_amdgcn_mfma_f32_16x16x32_bf16(ah[1], bh1, acc[ni], 0, 0, 0);
        acc[ni] = __builtin_amdgcn_mfma_f32_16x16x32_bf16(al[1], bh1, acc[ni], 0, 0, 0);
    }

    float mx[4] = {-1e30f, -1e30f, -1e30f, -1e30f};
    #pragma unroll
    for (int ni = 0; ni < 16; ++ni)
        #pragma unroll
        for (int i = 0; i < 4; ++i) {
            float v = acc[ni][i] * 0.125f;
            acc[ni][i] = v;
            mx[i] = fmaxf(mx[i], v);
        }
    #pragma unroll
    for (int off = 1; off < 16; off <<= 1)
        #pragma unroll
        for (int i = 0; i < 4; ++i) mx[i] = fmaxf(mx[i], __shfl_xor(mx[i], off));
    if (lr == 0)
        #pragma unroll
        for (int i = 0; i < 4; ++i) redm[w][lg * 4 + i] = mx[i];
    __syncthreads();
    float Mv[4];
    #pragma unroll
    for (int i = 0; i < 4; ++i)
        Mv[i] = fmaxf(fmaxf(redm[0][lg*4+i], redm[1][lg*4+i]),
                      fmaxf(redm[2][lg*4+i], redm[3][lg*4+i]));
    float sm[4] = {0.f, 0.f, 0.f, 0.f};
    #pragma unroll
    for (int ni = 0; ni < 16; ++ni)
        #pragma unroll
        for (int i = 0; i < 4; ++i) {
            float e = __expf(acc[ni][i] - Mv[i]);
            acc[ni][i] = e;
            sm[i] += e;
        }
    #pragma unroll
    for (int off = 1; off < 16; off <<= 1)
        #pragma unroll
        for (int i = 0; i < 4; ++i) sm[i] += __shfl_xor(sm[i], off);
    if (lr == 0)
        #pragma unroll
        for (int i = 0; i < 4; ++i) reds[w][lg * 4 + i] = sm[i];
    __syncthreads();
    float inv[4];
    #pragma unroll
    for (int i = 0; i < 4; ++i)
        inv[i] = 1.f / (reds[0][lg*4+i] + reds[1][lg*4+i] + reds[2][lg*4+i] + reds[3][lg*4+i]);

    char* pB = (char*)pLds + w * 8192;
    #pragma unroll
    for (int ni = 0; ni < 16; ++ni)
        #pragma unroll
        for (int i = 0; i < 4; ++i) {
            int q = lg * 4 + i, m = ni * 16 + lr;
            int byte = (q * 512 + m * 2) ^ ((q & 7) << 4);
            *(short*)(pB + byte) = (short)__bfloat16_as_ushort(__float2bfloat16(acc[ni][i] * inv[i]));
        }
    __syncthreads();

    f32x4 acc2[4];
    #pragma unroll
    for (int bi = 0; bi < 4; ++bi) acc2[bi] = f32x4{0.f, 0.f, 0.f, 0.f};
    const long vbase0 = (((long)(srcdb * 4 + h)) * 4 + w) * 8;
    #pragma unroll
    for (int km = 0; km < 8; ++km) {
        int rb = (lr * 512 + km * 64 + lg * 16) ^ ((lr & 7) << 4);
        bf16x8 pa = *(const bf16x8*)(pB + rb);
        #pragma unroll
        for (int bi = 0; bi < 4; ++bi) {
            long vr = ((vbase0 + km) * 4 + bi) * 512 + lane * 8;
            bf16x8 vhf = *(const bf16x8*)(vh + vr);
            acc2[bi] = __builtin_amdgcn_mfma_f32_16x16x32_bf16(pa, vhf, acc2[bi], 0, 0, 0);
        }
    }
    __syncthreads();
    float* pr = (float*)pLds;
    #pragma unroll
    for (int bi = 0; bi < 4; ++bi)
        #pragma unroll
        for (int i = 0; i < 4; ++i)
            pr[w * 1024 + (lg * 4 + i) * 64 + bi * 16 + lr] = acc2[bi][i];
    __syncthreads();
    #pragma unroll
    for (int k = 0; k < 4; ++k) {
        int e = t + k * 256;
        float v = pr[e] + pr[1024 + e] + pr[2048 + e] + pr[3072 + e];
        int q = e >> 6, d = e & 63;
        long a = ((long)dbQ * 1024 + q0 + q) * 512 + 256 + h * 64 + d;
        __hip_bfloat16 hh, ll; split2(v, hh, ll);
        catHi[a] = hh; catLo[a] = ll;
    }
}

// ---------------- LN(channel,ddof=1,eps-on-std)+ReLU; write planes ----------------
__global__ __launch_bounds__(256) void ln_relu_planes(
    const float* __restrict__ y, const float* __restrict__ g, const float* __restrict__ be,
    __hip_bfloat16* __restrict__ hi, __hip_bfloat16* __restrict__ lo)
{
    __shared__ float s1[256], s2[256];
    const long row = blockIdx.x;
    const int t = threadIdx.x;
    const float* src = y + row * 512;
    float a = src[t], b = src[t + 256];
    s1[t] = a + b; s2[t] = a * a + b * b;
    __syncthreads();
    for (int s = 128; s > 0; s >>= 1) {
        if (t < s) { s1[t] += s1[t + s]; s2[t] += s2[t + s]; }
        __syncthreads();
    }
    float mean = s1[0] / 512.f;
    float var = fmaxf((s2[0] - 512.f * mean * mean) / 511.f, 0.f);
    float rstd = 1.f / (sqrtf(var) + LN_EPS);
    float v1 = fmaxf(g[t] * (a - mean) * rstd + be[t], 0.f);
    float v2 = fmaxf(g[t + 256] * (b - mean) * rstd + be[t + 256], 0.f);
    __hip_bfloat16 h, l;
    split2(v1, h, l); hi[row * 512 + t] = h;       lo[row * 512 + t] = l;
    split2(v2, h, l); hi[row * 512 + t + 256] = h; lo[row * 512 + t + 256] = l;
}

// ---------------- weight converts ----------------
__global__ __launch_bounds__(256) void wconv_plain(
    const float* __restrict__ w, __hip_bfloat16* __restrict__ hi, __hip_bfloat16* __restrict__ lo, long total)
{
    long i = (long)blockIdx.x * 256 + threadIdx.x;
    if (i >= total) return;
    __hip_bfloat16 h, l; split2(w[i], h, l);
    hi[i] = h; lo[i] = l;
}

__global__ __launch_bounds__(256) void wconv_proj(
    const float* __restrict__ w, __hip_bfloat16* __restrict__ hi, __hip_bfloat16* __restrict__ lo)
{
    long i = (long)blockIdx.x * 256 + threadIdx.x;
    if (i >= 9L * 768 * 256) return;
    long l9 = i / (768 * 256);
    int rem = (int)(i % (768 * 256));
    int op = rem / 256, c = rem % 256;
    int tq = op / 256, within = op % 256;
    int h = within / 64, hd = within % 64;
    int o = tq * 256 + hd * 4 + h;
    float v = w[(l9 * 768 + o) * 256 + c];
    __hip_bfloat16 hh, ll; split2(v, hh, ll);
    hi[i] = hh; lo[i] = ll;
}

__global__ void wconv_proj_bias(const float* __restrict__ b, float* __restrict__ bp)
{
    int i = blockIdx.x * 256 + threadIdx.x;
    if (i >= 9 * 768) return;
    int l9 = i / 768, op = i % 768;
    int tq = op / 256, within = op % 256;
    int h = within / 64, hd = within % 64;
    bp[i] = b[(l9 * 3 + tq) * 256 + hd * 4 + h];
}

// WmT planes: [l][c=h*64+hd][j] = Wm[l][j][hd*4+h]
__global__ __launch_bounds__(256) void wconv_mergeT(
    const float* __restrict__ w, __hip_bfloat16* __restrict__ hi, __hip_bfloat16* __restrict__ lo)
{
    long i = (long)blockIdx.x * 256 + threadIdx.x;
    if (i >= 9L * 256 * 256) return;
    long l9 = i / (256 * 256);
    int rem = (int)(i % (256 * 256));
    int c = rem / 256, j = rem % 256;
    int h = c / 64, hd = c % 64;
    float v = w[(l9 * 256 + j) * 256 + (hd * 4 + h)];
    __hip_bfloat16 hh, ll; split2(v, hh, ll);
    hi[i] = hh; lo[i] = ll;
}

// mlp1 W split: cols 0..255 -> m1c[..512-wide cols 0..255]; cols 256..511 -> m1b[..256-wide]
__global__ __launch_bounds__(256) void wconv_m1(
    const float* __restrict__ w,
    __hip_bfloat16* __restrict__ m1cHi, __hip_bfloat16* __restrict__ m1cLo,
    __hip_bfloat16* __restrict__ m1bHi, __hip_bfloat16* __restrict__ m1bLo)
{
    long i = (long)blockIdx.x * 256 + threadIdx.x;
    if (i >= 9L * 512 * 512) return;
    long lo9 = i / 512;
    int c = (int)(i % 512);
    __hip_bfloat16 hh, ll; split2(w[i], hh, ll);
    if (c < 256) { m1cHi[lo9 * 512 + c] = hh; m1cLo[lo9 * 512 + c] = ll; }
    else         { m1bHi[lo9 * 256 + c - 256] = hh; m1bLo[lo9 * 256 + c - 256] = ll; }
}

// b1c[l*512+o] = b1[l][o] + sum_j W1[l][o][256+j]*bm[l][j]
__global__ __launch_bounds__(64) void bias_fold(
    const float* __restrict__ w1, const float* __restrict__ b1,
    const float* __restrict__ bm, float* __restrict__ out)
{
    int og = blockIdx.x;
    int l = og >> 9, o = og & 511;
    int t = threadIdx.x;
    float s = 0.f;
    for (int j = t; j < 256; j += 64)
        s += w1[((long)l * 512 + o) * 512 + 256 + j] * bm[l * 256 + j];
    for (int off = 32; off > 0; off >>= 1) s += __shfl_down(s, off);
    if (t == 0) out[og] = b1[(long)l * 512 + o] + s;
}

// ---------------- Sinkhorn pieces ----------------
__global__ void bins_fill(float* __restrict__ Z, const float* __restrict__ alpha_p)
{
    float alpha = alpha_p[0];
    int idx = blockIdx.x * 256 + threadIdx.x;
    int b = blockIdx.y;
    float* Zb = Z + (long)b * NP1c * NP1c;
    if (idx < NP1c) Zb[(long)1024 * NP1c + idx] = alpha;
    else { int i = idx - NP1c; if (i < 1024) Zb[(long)i * NP1c + 1024] = alpha; }
}

__global__ void transpose_np1(const float* __restrict__ Z, float* __restrict__ ZT)
{
    __shared__ float tile[32][33];
    int b = blockIdx.z;
    int i0 = blockIdx.y * 32, j0 = blockIdx.x * 32;
    int tx = threadIdx.x, ty = threadIdx.y;
    const float* Zb = Z + (long)b * NP1c * NP1c;
    float* Tb = ZT + (long)b * NP1c * NP1c;
    for (int ii = ty; ii < 32; ii += 8) {
        int i = i0 + ii, j = j0 + tx;
        if (i < NP1c && j < NP1c) tile[ii][tx] = Zb[(long)i * NP1c + j];
    }
    __syncthreads();
    for (int jj = ty; jj < 32; jj += 8) {
        int j = j0 + jj, i = i0 + tx;
        if (j < NP1c && i < NP1c) Tb[(long)j * NP1c + i] = tile[tx][jj];
    }
}

__global__ void zero_vec(float* __restrict__ v, int n)
{
    int i = blockIdx.x * 256 + threadIdx.x;
    if (i < n) v[i] = 0.f;
}

__global__ __launch_bounds__(256) void sinkhorn_lse(
    const float* __restrict__ M, const float* __restrict__ addv, float* __restrict__ outv)
{
    __shared__ float sm[256], ss[256];
    const int i = blockIdx.x, b = blockIdx.y, t = threadIdx.x;
    const float* row = M + ((long)b * NP1c + i) * NP1c;
    const float* av = addv + b * NP1c;
    float m = -1e30f, s = 0.f;
    for (int j = t; j < NP1c; j += 256) {
        float xv = row[j] + av[j];
        if (xv > m) { s = s * __expf(m - xv) + 1.f; m = xv; }
        else s += __expf(xv - m);
    }
    sm[t] = m; ss[t] = s;
    __syncthreads();
    for (int st = 128; st > 0; st >>= 1) {
        if (t < st) {
            float m1 = sm[t], s1 = ss[t], m2 = sm[t + st], s2 = ss[t + st];
            float mm = fmaxf(m1, m2);
            sm[t] = mm;
            ss[t] = s1 * __expf(m1 - mm) + s2 * __expf(m2 - mm);
        }
        __syncthreads();
    }
    if (t == 0) {
        float lse = sm[0] + __logf(ss[0]);
        float lmu = (i < 1024) ? NORMV : (LOGNV + NORMV);
        outv[b * NP1c + i] = lmu - lse;
    }
}

__global__ __launch_bounds__(256) void final_out_k(
    const float* __restrict__ Z, const float* __restrict__ u,
    const float* __restrict__ v, float* __restrict__ outp)
{
    const int i = blockIdx.x, b = blockIdx.y, t = threadIdx.x;
    const float* row = Z + ((long)b * NP1c + i) * NP1c;
    float* orow = outp + ((long)b * NP1c + i) * NP1c;
    float ui = u[b * NP1c + i];
    for (int j = t; j < NP1c; j += 256)
        orow[j] = row[j] + ui + v[b * NP1c + j] - NORMV;
}

// =======================================================================
extern "C" void kernel_launch(void* const* d_in, const int* in_sizes, int n_in,
                              void* d_out, int out_size, void* d_ws, size_t ws_size,
                              hipStream_t stream)
{
    (void)in_sizes; (void)n_in; (void)out_size; (void)ws_size;
    const float* kpts0   = (const float*)d_in[0];
    const float* kpts1   = (const float*)d_in[1];
    const float* scores0 = (const float*)d_in[2];
    const float* scores1 = (const float*)d_in[3];
    const float* desc0   = (const float*)d_in[4];
    const float* desc1   = (const float*)d_in[5];
    const float* kw0 = (const float*)d_in[6];  const float* kb0 = (const float*)d_in[7];
    const float* kg0 = (const float*)d_in[8];  const float* ke0 = (const float*)d_in[9];
    const float* kw1 = (const float*)d_in[10]; const float* kb1 = (const float*)d_in[11];
    const float* kg1 = (const float*)d_in[12]; const float* ke1 = (const float*)d_in[13];
    const float* kw2 = (const float*)d_in[14]; const float* kb2 = (const float*)d_in[15];
    const float* kg2 = (const float*)d_in[16]; const float* ke2 = (const float*)d_in[17];
    const float* kw3 = (const float*)d_in[18]; const float* kb3 = (const float*)d_in[19];
    const float* gnn_proj_w  = (const float*)d_in[20];
    const float* gnn_proj_b  = (const float*)d_in[21];
    const float* gnn_merge_w = (const float*)d_in[22];
    const float* gnn_merge_b = (const float*)d_in[23];
    const float* gnn_mlp1_w  = (const float*)d_in[24];
    const float* gnn_mlp1_b  = (const float*)d_in[25];
    const float* gnn_ln_g    = (const float*)d_in[26];
    const float* gnn_ln_b    = (const float*)d_in[27];
    const float* gnn_mlp2_w  = (const float*)d_in[28];
    const float* gnn_mlp2_b  = (const float*)d_in[29];
    const float* final_w     = (const float*)d_in[30];
    const float* final_b     = (const float*)d_in[31];
    const float* bin_score   = (const float*)d_in[32];

    char* wsb = (char*)d_ws;
    size_t off = 0;
    auto alloc = [&](size_t bytes) -> void* {
        void* p = wsb + off;
        off = (off + bytes + 255) & ~(size_t)255;
        return p;
    };
    typedef __hip_bfloat16 bf;
    const long ROWS = 4L * Nc;
    // fp32
    float* descF  = (float*)alloc(ROWS * 256 * 4);
    float* ybufF  = (float*)alloc(ROWS * 512 * 4);
    float* Zm     = (float*)alloc((long)Bc * NP1c * NP1c * 4);
    float* ZT     = (float*)alloc((long)Bc * NP1c * NP1c * 4);
    float* uvec   = (float*)alloc(Bc * NP1c * 4);
    float* vvec   = (float*)alloc(Bc * NP1c * 4);
    float* projBp = (float*)alloc(9L * 768 * 4);
    float* b1c    = (float*)alloc(9L * 512 * 4);
    float* kw1T   = (float*)alloc(32L * 64 * 4);
    float* kw2T   = (float*)alloc(64L * 128 * 4);
    float* kw3T   = (float*)alloc(128L * 256 * 4);
    // activation planes
    bf* catHi = (bf*)alloc(ROWS * 512 * 2);  bf* catLo = (bf*)alloc(ROWS * 512 * 2);
    bf* qFh = (bf*)alloc(1048576 * 2); bf* qFl = (bf*)alloc(1048576 * 2);
    bf* kFh = (bf*)alloc(1048576 * 2);
    bf* vFh = (bf*)alloc(1048576 * 2);
    bf* ybHi  = (bf*)alloc(ROWS * 512 * 2);  bf* ybLo  = (bf*)alloc(ROWS * 512 * 2);
    bf* mdHi  = (bf*)alloc(ROWS * 256 * 2);  bf* mdLo  = (bf*)alloc(ROWS * 256 * 2);
    // weight planes
    bf* projHi = (bf*)alloc(9L*768*256*2);   bf* projLo = (bf*)alloc(9L*768*256*2);
    bf* mrgTHi = (bf*)alloc(9L*256*256*2);   bf* mrgTLo = (bf*)alloc(9L*256*256*2);
    bf* m1bHi  = (bf*)alloc(9L*512*256*2);   bf* m1bLo  = (bf*)alloc(9L*512*256*2);
    bf* m1cHi  = (bf*)alloc(9L*512*512*2);   bf* m1cLo  = (bf*)alloc(9L*512*512*2);
    bf* m2Hi   = (bf*)alloc(9L*256*512*2);   bf* m2Lo   = (bf*)alloc(9L*256*512*2);
    bf* finHi  = (bf*)alloc(256L*256*2);     bf* finLo  = (bf*)alloc(256L*256*2);

    // ---- weight prep ----
    wconv_proj<<<dim3((9*768*256+255)/256), 256, 0, stream>>>(gnn_proj_w, projHi, projLo);
    wconv_proj_bias<<<dim3(27), 256, 0, stream>>>(gnn_proj_b, projBp);
    wconv_mergeT<<<dim3((9*256*256+255)/256), 256, 0, stream>>>(gnn_merge_w, mrgTHi, mrgTLo);
    wconv_m1<<<dim3((int)((9L*512*512+255)/256)), 256, 0, stream>>>(gnn_mlp1_w, m1cHi, m1cLo, m1bHi, m1bLo);
    wconv_plain<<<dim3((9*256*512+255)/256), 256, 0, stream>>>(gnn_mlp2_w, m2Hi, m2Lo, 9L*256*512);
    wconv_plain<<<dim3((256*256+255)/256), 256, 0, stream>>>(final_w, finHi, finLo, 256L*256);
    bias_fold<<<dim3(9*512), 64, 0, stream>>>(gnn_mlp1_w, gnn_mlp1_b, gnn_merge_b, b1c);
    transposeW<<<dim3((64*32+255)/256), 256, 0, stream>>>(kw1, kw1T, 64, 32);
    transposeW<<<dim3((128*64+255)/256), 256, 0, stream>>>(kw2, kw2T, 128, 64);
    transposeW<<<dim3((256*128+255)/256), 256, 0, stream>>>(kw3, kw3T, 256, 128);
    // combined mlp1 cols 256..511 = W1b x WmT^T per layer (full hi/lo accuracy)
    mfma_nt<128,128,1,1><<<dim3(2,4,9), 256, 0, stream>>>(
        (const short*)m1bHi, (const short*)m1bLo, 256,
        (const short*)mrgTHi, (const short*)mrgTLo, 256,
        256, 1.f, nullptr,
        nullptr, m1cHi + 256, m1cLo + 256, nullptr, nullptr, 512,
        512L*256, 256L*256, 512L*512);

    // ---- keypoint encoder -> descF + cat planes cols 0..255 ----
    kenc_kernel<<<dim3(Nc, Bc), 256, 0, stream>>>(kpts0, scores0, desc0, descF,
        catHi, catLo,
        kw0, kb0, kg0, ke0, kw1T, kb1, kg1, ke1, kw2T, kb2, kg2, ke2, kw3T, kb3);
    kenc_kernel<<<dim3(Nc, Bc), 256, 0, stream>>>(kpts1, scores1, desc1, descF + 2L*Nc*256,
        catHi + 2L*Nc*512, catLo + 2L*Nc*512,
        kw0, kb0, kg0, ke0, kw1T, kb1, kg1, ke1, kw2T, kb2, kg2, ke2, kw3T, kb3);

    // ---- GNN layers ----
    for (int l = 0; l < 9; ++l) {
        // 1) qkv GEMM (W hi-only) -> Q hi/lo + K hi + V hi fragment-order
        mfma_nt<64,128,2,0><<<dim3(6,64,1), 256, 0, stream>>>(
            (const short*)catHi, (const short*)catLo, 512,
            (const short*)(projHi + (long)l*768*256), nullptr, 256,
            256, 1.f, projBp + (long)l*768,
            nullptr, qFh, qFl, vFh, kFh, 0,
            0, 0, 0);
        // 2) fused attention -> catbuf cols 256..511
        attn_fused<<<dim3(64, 16), 256, 0, stream>>>(qFh, qFl, kFh, vFh, catHi, catLo);
        // 3) mlp1 (W hi-only, combined weights) -> ybufF
        mfma_nt<64,128,0,0><<<dim3(4,64,1), 256, 0, stream>>>(
            (const short*)catHi, (const short*)catLo, 512,
            (const short*)(m1cHi + (long)l*512*512), nullptr, 512,
            512, 1.f, b1c + (long)l*512,
            ybufF, nullptr, nullptr, nullptr, nullptr, 512,
            0, 0, 0);
        // 4) LN+ReLU -> yb planes
        ln_relu_planes<<<dim3((unsigned)ROWS), 256, 0, stream>>>(
            ybufF, gnn_ln_g + (long)l*512, gnn_ln_b + (long)l*512, ybHi, ybLo);
        // 5) mlp2 (W hi-only) fused residual -> descF + cat cols 0..255
        mfma_nt<64,64,3,0><<<dim3(4,64,1), 256, 0, stream>>>(
            (const short*)ybHi, (const short*)ybLo, 512,
            (const short*)(m2Hi + (long)l*256*512), nullptr, 512,
            512, 1.f, gnn_mlp2_b + (long)l*256,
            descF, catHi, catLo, nullptr, nullptr, 0,
            0, 0, 0);
    }

    // ---- final projection (W hi-only) -> mdesc planes ----
    mfma_nt<64,64,1,0><<<dim3(4,64,1), 256, 0, stream>>>(
        (const short*)catHi, (const short*)catLo, 512,
        (const short*)finHi, nullptr, 256,
        256, 1.f, final_b,
        nullptr, mdHi, mdLo, nullptr, nullptr, 256,
        0, 0, 0);
    // ---- score matrix into Z (activation x activation: full hi/lo) ----
    mfma_nt<128,128,0,1><<<dim3(8,8,2), 256, 0, stream>>>(
        (const short*)mdHi, (const short*)mdLo, 256,
        (const short*)mdHi + 2048L*256, (const short*)mdLo + 2048L*256, 256,
        256, 1.f/16.f, nullptr,
        Zm, nullptr, nullptr, nullptr, nullptr, NP1c,
        1024L*256, 1024L*256, (long)NP1c*NP1c);
    bins_fill<<<dim3(9,2), 256, 0, stream>>>(Zm, bin_score);

    // ---- Sinkhorn (log-space), 20 iterations ----
    transpose_np1<<<dim3(33,33,2), dim3(32,8), 0, stream>>>(Zm, ZT);
    zero_vec<<<dim3(9), 256, 0, stream>>>(vvec, Bc * NP1c);
    for (int it = 0; it < 20; ++it) {
        sinkhorn_lse<<<dim3(NP1c, Bc), 256, 0, stream>>>(Zm, vvec, uvec);
        sinkhorn_lse<<<dim3(NP1c, Bc), 256, 0, stream>>>(ZT, uvec, vvec);
    }
    final_out_k<<<dim3(NP1c, Bc), 256, 0, stream>>>(Zm, uvec, vvec, (float*)d_out);
}

// Round 9
// 1001.742 us; speedup vs baseline: 5.8493x; 1.1048x over previous
//
#include <hip/hip_runtime.h>
#include <hip/hip_bf16.h>
#include <math.h>

#define DEVI static __device__ __forceinline__

namespace {
constexpr int Bc   = 2;
constexpr int Nc   = 1024;
constexpr int Dc   = 256;
constexpr int NP1c = 1025;
constexpr int LDZ  = 1028;              // padded Z row stride (16B-aligned)
constexpr int LDV  = 1028;              // padded u/v stride
constexpr float LN_EPS = 1e-6f;
constexpr float NORMV  = -7.6246189861593985f; // -log(2048)
constexpr float LOGNV  =  6.9314718055994531f; // log(1024)
}

typedef __attribute__((ext_vector_type(8))) short bf16x8;
typedef __attribute__((ext_vector_type(4))) float f32x4;

DEVI void split2(float v, __hip_bfloat16& h, __hip_bfloat16& l) {
    h = __float2bfloat16(v);
    l = __float2bfloat16(v - __bfloat162float(h));
}

// async global->LDS, 16B per lane
#define GLDS16(gp, lp) __builtin_amdgcn_global_load_lds( \
    (const __attribute__((address_space(1))) void*)(gp), \
    (__attribute__((address_space(3))) void*)(lp), 16, 0, 0)

// ---------------- helpers ----------------
DEVI float block_sum_256(float v, float* scratch) {
    int t = threadIdx.x;
    scratch[t] = v;
    __syncthreads();
    for (int s = 128; s > 0; s >>= 1) {
        if (t < s) scratch[t] += scratch[t + s];
        __syncthreads();
    }
    float r = scratch[0];
    __syncthreads();
    return r;
}

DEVI void ln_relu_inplace(float* x, const float* g, const float* be, int C, float* scratch) {
    int t = threadIdx.x;
    float v = (t < C) ? x[t] : 0.f;
    float mean = block_sum_256(v, scratch) / (float)C;
    float dv = (t < C) ? (x[t] - mean) : 0.f;
    float var = block_sum_256(dv * dv, scratch) / (float)(C - 1);
    float rstd = 1.f / (sqrtf(var) + LN_EPS);
    if (t < C) x[t] = fmaxf(g[t] * dv * rstd + be[t], 0.f);
    __syncthreads();
}

// ---------------- keypoint encoder (coalesced weights; writes cat planes) ----------------
__global__ __launch_bounds__(256) void kenc_kernel(
    const float* __restrict__ kpts, const float* __restrict__ scr,
    const float* __restrict__ desc_in, float* __restrict__ desc_out,
    __hip_bfloat16* __restrict__ catHi, __hip_bfloat16* __restrict__ catLo,
    const float* __restrict__ w0, const float* __restrict__ b0,
    const float* __restrict__ g0, const float* __restrict__ be0,
    const float* __restrict__ w1T, const float* __restrict__ b1,
    const float* __restrict__ g1, const float* __restrict__ be1,
    const float* __restrict__ w2T, const float* __restrict__ b2,
    const float* __restrict__ g2, const float* __restrict__ be2,
    const float* __restrict__ w3T, const float* __restrict__ b3)
{
    __shared__ float xa[256], xb[256], scratch[256];
    const int n = blockIdx.x, b = blockIdx.y, t = threadIdx.x;
    if (t == 0) {
        float kx = kpts[((long)b * Nc + n) * 2 + 0];
        float ky = kpts[((long)b * Nc + n) * 2 + 1];
        xa[0] = (kx - 320.f) * (1.f / 448.f);
        xa[1] = (ky - 240.f) * (1.f / 448.f);
        xa[2] = scr[b * Nc + n];
    }
    __syncthreads();
    if (t < 32) { float a = b0[t]; for (int c = 0; c < 3;  ++c) a += w0[t*3 + c] * xa[c]; xb[t] = a; }
    __syncthreads();
    ln_relu_inplace(xb, g0, be0, 32, scratch);
    if (t < 64) {
        float a = b1[t];
        #pragma unroll 8
        for (int c = 0; c < 32;  ++c) a += w1T[c*64 + t] * xb[c];
        xa[t] = a;
    }
    __syncthreads();
    ln_relu_inplace(xa, g1, be1, 64, scratch);
    if (t < 128) {
        float a = b2[t];
        #pragma unroll 8
        for (int c = 0; c < 64;  ++c) a += w2T[c*128 + t] * xa[c];
        xb[t] = a;
    }
    __syncthreads();
    ln_relu_inplace(xb, g2, be2, 128, scratch);
    {   float a = b3[t];
        #pragma unroll 8
        for (int c = 0; c < 128; ++c) a += w3T[c*256 + t] * xb[c];
        float v = desc_in[((long)b * Dc + t) * Nc + n] + a;
        desc_out[((long)b * Nc + n) * Dc + t] = v;
        __hip_bfloat16 h, l; split2(v, h, l);
        long cr = ((long)b * Nc + n) * 512 + t;
        catHi[cr] = h; catLo[cr] = l;
    }
}

__global__ __launch_bounds__(256) void transposeW(
    const float* __restrict__ src, float* __restrict__ dst, int O, int C)
{
    long i = (long)blockIdx.x * 256 + threadIdx.x;
    if (i >= (long)O * C) return;
    int o = (int)(i / C), c = (int)(i % C);
    dst[(long)c * O + o] = src[i];
}

// =======================================================================
// MFMA NT GEMM, BK=64 double-chunk K-loop. A hi/lo; B hi/lo (BLO=1) or hi (BLO=0).
// EPI: 0 fp32 out; 1 bf16 planes; 2 qkv -> Q(hi/lo)/K(hi)/V(hi) fragment-order;
//      3 mlp2 fused resid. K must be a multiple of 64.
// =======================================================================
template<int BM, int BN, int EPI, int BLO>
__global__ __launch_bounds__(256) void mfma_nt(
    const short* __restrict__ Ahi0, const short* __restrict__ Alo0, int lda,
    const short* __restrict__ Bhi0, const short* __restrict__ Blo0, int ldb,
    int K, float scale, const float* __restrict__ bias,
    float* __restrict__ outF, __hip_bfloat16* __restrict__ outHi,
    __hip_bfloat16* __restrict__ outLo,
    __hip_bfloat16* __restrict__ outHi2, __hip_bfloat16* __restrict__ outHi3,
    int ldo,
    long aS1, long bS1, long oS1)
{
    constexpr int MI = BM / 32;
    constexpr int NI = BN / 32;
    constexpr int instA = BM / 16, instB = BN / 16;
    constexpr int OFF_AH = 0;
    constexpr int OFF_AL = BM * 32;
    constexpr int OFF_BH = 2 * BM * 32;
    constexpr int OFF_BL = 2 * BM * 32 + BN * 32;  // used only when BLO
    constexpr int CHUNK = (2 * BM + (BLO ? 2 : 1) * BN) * 32;
    __shared__ short smem[2 * CHUNK];

    const int z = blockIdx.z;
    const long aOff = z * aS1, bOff = z * bS1, oOff = z * oS1;
    const short* Ah = Ahi0 + aOff; const short* Al = Alo0 + aOff;
    const short* Bh = Bhi0 + bOff; const short* Bl = BLO ? (Blo0 + bOff) : nullptr;

    const int m0 = blockIdx.y * BM, n0 = blockIdx.x * BN;
    const int t = threadIdx.x, lane = t & 63, wid = t >> 6;
    const int lr = lane & 15, lg = lane >> 4;
    const int wr = wid >> 1, wc = wid & 1;

    f32x4 acc[MI][NI];
    for (int mi = 0; mi < MI; ++mi)
        for (int ni = 0; ni < NI; ++ni)
            acc[mi][ni] = f32x4{0.f, 0.f, 0.f, 0.f};

    for (int k0 = 0; k0 < K; k0 += 64) {
        constexpr int total = 2 * instA + (BLO ? 2 : 1) * instB;
        for (int q = wid; q < total; q += 4) {
            const short* gsrc; int ldg, mi, ploff, row0;
            if (q < instA)               { gsrc = Ah; ldg = lda; mi = q;                 ploff = OFF_AH; row0 = m0; }
            else if (q < 2*instA)        { gsrc = Al; ldg = lda; mi = q - instA;         ploff = OFF_AL; row0 = m0; }
            else if (q < 2*instA+instB)  { gsrc = Bh; ldg = ldb; mi = q - 2*instA;       ploff = OFF_BH; row0 = n0; }
            else                         { gsrc = Bl; ldg = ldb; mi = q - 2*instA-instB; ploff = OFF_BL; row0 = n0; }
            const short* g = gsrc + (long)(row0 + mi * 16 + lr) * ldg + (k0 + lg * 8);
            GLDS16(g,      smem + ploff + mi * 512);
            GLDS16(g + 32, smem + CHUNK + ploff + mi * 512);
        }
        __syncthreads();
        #pragma unroll
        for (int kc2 = 0; kc2 < 2; ++kc2) {
            const short* sm2 = smem + kc2 * CHUNK;
            bf16x8 ah[MI], al[MI];
            #pragma unroll
            for (int mi = 0; mi < MI; ++mi) {
                ah[mi] = *(const bf16x8*)(sm2 + OFF_AH + ((wr * MI + mi) * 64 + lane) * 8);
                al[mi] = *(const bf16x8*)(sm2 + OFF_AL + ((wr * MI + mi) * 64 + lane) * 8);
            }
            #pragma unroll
            for (int ni = 0; ni < NI; ++ni) {
                bf16x8 bh = *(const bf16x8*)(sm2 + OFF_BH + ((wc * NI + ni) * 64 + lane) * 8);
                #pragma unroll
                for (int mi = 0; mi < MI; ++mi) {
                    acc[mi][ni] = __builtin_amdgcn_mfma_f32_16x16x32_bf16(ah[mi], bh, acc[mi][ni], 0, 0, 0);
                    acc[mi][ni] = __builtin_amdgcn_mfma_f32_16x16x32_bf16(al[mi], bh, acc[mi][ni], 0, 0, 0);
                }
                if (BLO) {
                    bf16x8 bl = *(const bf16x8*)(sm2 + OFF_BL + ((wc * NI + ni) * 64 + lane) * 8);
                    #pragma unroll
                    for (int mi = 0; mi < MI; ++mi)
                        acc[mi][ni] = __builtin_amdgcn_mfma_f32_16x16x32_bf16(ah[mi], bl, acc[mi][ni], 0, 0, 0);
                }
            }
        }
        __syncthreads();
    }

    for (int mi = 0; mi < MI; ++mi) {
        for (int i = 0; i < 4; ++i) {
            int row = m0 + wr * (BM / 2) + mi * 16 + lg * 4 + i;
            for (int ni = 0; ni < NI; ++ni) {
                int col = n0 + wc * (BN / 2) + ni * 16 + lr;
                float v = acc[mi][ni][i] * scale;
                if (bias) v += bias[col];
                if (EPI == 0) {
                    outF[(long)row * ldo + col + oOff] = v;
                } else if (EPI == 1) {
                    __hip_bfloat16 h, l;
                    split2(v, h, l);
                    outHi[(long)row * ldo + col + oOff] = h;
                    outLo[(long)row * ldo + col + oOff] = l;
                } else if (EPI == 2) {
                    // Q -> hi/lo frag order; K,V -> hi-only frag order
                    int dirb = row >> 10, rloc = row & 1023;
                    int tq = col >> 8, within = col & 255;
                    int h4 = within >> 6, hd = within & 63;
                    __hip_bfloat16 hh, ll;
                    split2(v, hh, ll);
                    if (tq == 2) {
                        int w2 = rloc >> 8, mloc = rloc & 255;
                        int lane2 = ((mloc & 31) >> 3) * 16 + (hd & 15);
                        long idx = ((((long)(dirb*4+h4)*4 + w2)*8 + (mloc>>5))*4 + (hd>>4))*512 + lane2*8 + (mloc&7);
                        outHi2[idx] = hh;
                    } else {
                        int lane2 = ((hd & 31) >> 3) * 16 + (rloc & 15);
                        long idx = (((long)(dirb*4+h4)*64 + (rloc>>4))*2 + (hd>>5))*512 + lane2*8 + (hd&7);
                        if (tq == 0) { outHi[idx] = hh; outLo[idx] = ll; }
                        else         { outHi3[idx] = hh; }
                    }
                } else { // EPI==3: fused residual (descF) + cat planes cols 0..255
                    long i256 = (long)row * 256 + col;
                    v += outF[i256];
                    outF[i256] = v;
                    __hip_bfloat16 h, l;
                    split2(v, h, l);
                    outHi[(long)row * 512 + col] = h;
                    outLo[(long)row * 512 + col] = l;
                }
            }
        }
    }
}

// =======================================================================
// Fully fused attention. Q hi/lo; K,V hi-only. Fragment-order coalesced loads.
// =======================================================================
__global__ __launch_bounds__(256) void attn_fused(
    const __hip_bfloat16* __restrict__ qFh, const __hip_bfloat16* __restrict__ qFl,
    const __hip_bfloat16* __restrict__ kFh, const __hip_bfloat16* __restrict__ vFh,
    __hip_bfloat16* __restrict__ catHi, __hip_bfloat16* __restrict__ catLo)
{
    __shared__ short pLds[4 * 16 * 256];   // 32KB; reused as f32 partials
    __shared__ float redm[4][16], reds[4][16];
    const int y = blockIdx.y;
    const int dir = y >> 3, b = (y >> 2) & 1, h = y & 3;
    const int q0 = blockIdx.x * 16;
    const int t = threadIdx.x, lane = t & 63, w = t >> 6;
    const int lr = lane & 15, lg = lane >> 4;
    const int dbQ = dir * 2 + b;
    const int srcdb = (1 - dir) * 2 + b;
    const short* qh = (const short*)qFh; const short* ql = (const short*)qFl;
    const short* kh = (const short*)kFh;
    const short* vh = (const short*)vFh;

    const long qbase = (((long)(dbQ * 4 + h)) * 64 + (q0 >> 4)) * 2;
    bf16x8 ah[2], al[2];
    #pragma unroll
    for (int kc = 0; kc < 2; ++kc) {
        ah[kc] = *(const bf16x8*)(qh + (qbase + kc) * 512 + lane * 8);
        al[kc] = *(const bf16x8*)(ql + (qbase + kc) * 512 + lane * 8);
    }

    f32x4 acc[16];
    #pragma unroll
    for (int ni = 0; ni < 16; ++ni) acc[ni] = f32x4{0.f, 0.f, 0.f, 0.f};

    const long kbase0 = (((long)(srcdb * 4 + h)) * 64 + w * 16) * 2;
    #pragma unroll
    for (int ni = 0; ni < 16; ++ni) {
        long kb = (kbase0 + ni * 2) * 512 + lane * 8;
        bf16x8 bh0 = *(const bf16x8*)(kh + kb);
        bf16x8 bh1 = *(const bf16x8*)(kh + kb + 512);
        acc[ni] = __builtin_amdgcn_mfma_f32_16x16x32_bf16(ah[0], bh0, acc[ni], 0, 0, 0);
        acc[ni] = __builtin_amdgcn_mfma_f32_16x16x32_bf16(al[0], bh0, acc[ni], 0, 0, 0);
        acc[ni] = __builtin_amdgcn_mfma_f32_16x16x32_bf16(ah[1], bh1, acc[ni], 0, 0, 0);
        acc[ni] = __builtin_amdgcn_mfma_f32_16x16x32_bf16(al[1], bh1, acc[ni], 0, 0, 0);
    }

    float mx[4] = {-1e30f, -1e30f, -1e30f, -1e30f};
    #pragma unroll
    for (int ni = 0; ni < 16; ++ni)
        #pragma unroll
        for (int i = 0; i < 4; ++i) {
            float v = acc[ni][i] * 0.125f;
            acc[ni][i] = v;
            mx[i] = fmaxf(mx[i], v);
        }
    #pragma unroll
    for (int off = 1; off < 16; off <<= 1)
        #pragma unroll
        for (int i = 0; i < 4; ++i) mx[i] = fmaxf(mx[i], __shfl_xor(mx[i], off));
    if (lr == 0)
        #pragma unroll
        for (int i = 0; i < 4; ++i) redm[w][lg * 4 + i] = mx[i];
    __syncthreads();
    float Mv[4];
    #pragma unroll
    for (int i = 0; i < 4; ++i)
        Mv[i] = fmaxf(fmaxf(redm[0][lg*4+i], redm[1][lg*4+i]),
                      fmaxf(redm[2][lg*4+i], redm[3][lg*4+i]));
    float sm[4] = {0.f, 0.f, 0.f, 0.f};
    #pragma unroll
    for (int ni = 0; ni < 16; ++ni)
        #pragma unroll
        for (int i = 0; i < 4; ++i) {
            float e = __expf(acc[ni][i] - Mv[i]);
            acc[ni][i] = e;
            sm[i] += e;
        }
    #pragma unroll
    for (int off = 1; off < 16; off <<= 1)
        #pragma unroll
        for (int i = 0; i < 4; ++i) sm[i] += __shfl_xor(sm[i], off);
    if (lr == 0)
        #pragma unroll
        for (int i = 0; i < 4; ++i) reds[w][lg * 4 + i] = sm[i];
    __syncthreads();
    float inv[4];
    #pragma unroll
    for (int i = 0; i < 4; ++i)
        inv[i] = 1.f / (reds[0][lg*4+i] + reds[1][lg*4+i] + reds[2][lg*4+i] + reds[3][lg*4+i]);

    char* pB = (char*)pLds + w * 8192;
    #pragma unroll
    for (int ni = 0; ni < 16; ++ni)
        #pragma unroll
        for (int i = 0; i < 4; ++i) {
            int q = lg * 4 + i, m = ni * 16 + lr;
            int byte = (q * 512 + m * 2) ^ ((q & 7) << 4);
            *(short*)(pB + byte) = (short)__bfloat16_as_ushort(__float2bfloat16(acc[ni][i] * inv[i]));
        }
    __syncthreads();

    f32x4 acc2[4];
    #pragma unroll
    for (int bi = 0; bi < 4; ++bi) acc2[bi] = f32x4{0.f, 0.f, 0.f, 0.f};
    const long vbase0 = (((long)(srcdb * 4 + h)) * 4 + w) * 8;
    #pragma unroll
    for (int km = 0; km < 8; ++km) {
        int rb = (lr * 512 + km * 64 + lg * 16) ^ ((lr & 7) << 4);
        bf16x8 pa = *(const bf16x8*)(pB + rb);
        #pragma unroll
        for (int bi = 0; bi < 4; ++bi) {
            long vr = ((vbase0 + km) * 4 + bi) * 512 + lane * 8;
            bf16x8 vhf = *(const bf16x8*)(vh + vr);
            acc2[bi] = __builtin_amdgcn_mfma_f32_16x16x32_bf16(pa, vhf, acc2[bi], 0, 0, 0);
        }
    }
    __syncthreads();
    float* pr = (float*)pLds;
    #pragma unroll
    for (int bi = 0; bi < 4; ++bi)
        #pragma unroll
        for (int i = 0; i < 4; ++i)
            pr[w * 1024 + (lg * 4 + i) * 64 + bi * 16 + lr] = acc2[bi][i];
    __syncthreads();
    #pragma unroll
    for (int k = 0; k < 4; ++k) {
        int e = t + k * 256;
        float v = pr[e] + pr[1024 + e] + pr[2048 + e] + pr[3072 + e];
        int q = e >> 6, d = e & 63;
        long a = ((long)dbQ * 1024 + q0 + q) * 512 + 256 + h * 64 + d;
        __hip_bfloat16 hh, ll; split2(v, hh, ll);
        catHi[a] = hh; catLo[a] = ll;
    }
}

// ---------------- LN(channel,ddof=1,eps-on-std)+ReLU; write planes ----------------
__global__ __launch_bounds__(256) void ln_relu_planes(
    const float* __restrict__ y, const float* __restrict__ g, const float* __restrict__ be,
    __hip_bfloat16* __restrict__ hi, __hip_bfloat16* __restrict__ lo)
{
    __shared__ float s1[256], s2[256];
    const long row = blockIdx.x;
    const int t = threadIdx.x;
    const float* src = y + row * 512;
    float a = src[t], b = src[t + 256];
    s1[t] = a + b; s2[t] = a * a + b * b;
    __syncthreads();
    for (int s = 128; s > 0; s >>= 1) {
        if (t < s) { s1[t] += s1[t + s]; s2[t] += s2[t + s]; }
        __syncthreads();
    }
    float mean = s1[0] / 512.f;
    float var = fmaxf((s2[0] - 512.f * mean * mean) / 511.f, 0.f);
    float rstd = 1.f / (sqrtf(var) + LN_EPS);
    float v1 = fmaxf(g[t] * (a - mean) * rstd + be[t], 0.f);
    float v2 = fmaxf(g[t + 256] * (b - mean) * rstd + be[t + 256], 0.f);
    __hip_bfloat16 h, l;
    split2(v1, h, l); hi[row * 512 + t] = h;       lo[row * 512 + t] = l;
    split2(v2, h, l); hi[row * 512 + t + 256] = h; lo[row * 512 + t + 256] = l;
}

// ---------------- weight converts ----------------
__global__ __launch_bounds__(256) void wconv_plain(
    const float* __restrict__ w, __hip_bfloat16* __restrict__ hi, __hip_bfloat16* __restrict__ lo, long total)
{
    long i = (long)blockIdx.x * 256 + threadIdx.x;
    if (i >= total) return;
    __hip_bfloat16 h, l; split2(w[i], h, l);
    hi[i] = h; lo[i] = l;
}

__global__ __launch_bounds__(256) void wconv_proj(
    const float* __restrict__ w, __hip_bfloat16* __restrict__ hi, __hip_bfloat16* __restrict__ lo)
{
    long i = (long)blockIdx.x * 256 + threadIdx.x;
    if (i >= 9L * 768 * 256) return;
    long l9 = i / (768 * 256);
    int rem = (int)(i % (768 * 256));
    int op = rem / 256, c = rem % 256;
    int tq = op / 256, within = op % 256;
    int h = within / 64, hd = within % 64;
    int o = tq * 256 + hd * 4 + h;
    float v = w[(l9 * 768 + o) * 256 + c];
    __hip_bfloat16 hh, ll; split2(v, hh, ll);
    hi[i] = hh; lo[i] = ll;
}

__global__ void wconv_proj_bias(const float* __restrict__ b, float* __restrict__ bp)
{
    int i = blockIdx.x * 256 + threadIdx.x;
    if (i >= 9 * 768) return;
    int l9 = i / 768, op = i % 768;
    int tq = op / 256, within = op % 256;
    int h = within / 64, hd = within % 64;
    bp[i] = b[(l9 * 3 + tq) * 256 + hd * 4 + h];
}

// WmT planes: [l][c=h*64+hd][j] = Wm[l][j][hd*4+h]
__global__ __launch_bounds__(256) void wconv_mergeT(
    const float* __restrict__ w, __hip_bfloat16* __restrict__ hi, __hip_bfloat16* __restrict__ lo)
{
    long i = (long)blockIdx.x * 256 + threadIdx.x;
    if (i >= 9L * 256 * 256) return;
    long l9 = i / (256 * 256);
    int rem = (int)(i % (256 * 256));
    int c = rem / 256, j = rem % 256;
    int h = c / 64, hd = c % 64;
    float v = w[(l9 * 256 + j) * 256 + (hd * 4 + h)];
    __hip_bfloat16 hh, ll; split2(v, hh, ll);
    hi[i] = hh; lo[i] = ll;
}

// mlp1 W split: cols 0..255 -> m1c[..512-wide cols 0..255]; cols 256..511 -> m1b[..256-wide]
__global__ __launch_bounds__(256) void wconv_m1(
    const float* __restrict__ w,
    __hip_bfloat16* __restrict__ m1cHi, __hip_bfloat16* __restrict__ m1cLo,
    __hip_bfloat16* __restrict__ m1bHi, __hip_bfloat16* __restrict__ m1bLo)
{
    long i = (long)blockIdx.x * 256 + threadIdx.x;
    if (i >= 9L * 512 * 512) return;
    long lo9 = i / 512;
    int c = (int)(i % 512);
    __hip_bfloat16 hh, ll; split2(w[i], hh, ll);
    if (c < 256) { m1cHi[lo9 * 512 + c] = hh; m1cLo[lo9 * 512 + c] = ll; }
    else         { m1bHi[lo9 * 256 + c - 256] = hh; m1bLo[lo9 * 256 + c - 256] = ll; }
}

// b1c[l*512+o] = b1[l][o] + sum_j W1[l][o][256+j]*bm[l][j]
__global__ __launch_bounds__(64) void bias_fold(
    const float* __restrict__ w1, const float* __restrict__ b1,
    const float* __restrict__ bm, float* __restrict__ out)
{
    int og = blockIdx.x;
    int l = og >> 9, o = og & 511;
    int t = threadIdx.x;
    float s = 0.f;
    for (int j = t; j < 256; j += 64)
        s += w1[((long)l * 512 + o) * 512 + 256 + j] * bm[l * 256 + j];
    for (int off = 32; off > 0; off >>= 1) s += __shfl_down(s, off);
    if (t == 0) out[og] = b1[(long)l * 512 + o] + s;
}

// ---------------- Sinkhorn pieces (padded LDZ=1028 layout) ----------------
__global__ void bins_fill(float* __restrict__ Z, const float* __restrict__ alpha_p)
{
    float alpha = alpha_p[0];
    int idx = blockIdx.x * 256 + threadIdx.x;
    int b = blockIdx.y;
    float* Zb = Z + (long)b * NP1c * LDZ;
    if (idx < NP1c) Zb[(long)1024 * LDZ + idx] = alpha;
    else { int i = idx - NP1c; if (i < 1024) Zb[(long)i * LDZ + 1024] = alpha; }
}

// set pad cols 1025..1027 of both Zm and ZT to -1e30
__global__ void pad_fill(float* __restrict__ Zm, float* __restrict__ ZT)
{
    int i = blockIdx.x * 256 + threadIdx.x;   // 2*1025*3 = 6150 entries per buffer
    if (i >= 2 * NP1c * 3) return;
    int b = i / (NP1c * 3);
    int rem = i % (NP1c * 3);
    int row = rem / 3, c = 1025 + rem % 3;
    long a = (long)b * NP1c * LDZ + (long)row * LDZ + c;
    Zm[a] = -1e30f;
    ZT[a] = -1e30f;
}

__global__ void transpose_np1(const float* __restrict__ Z, float* __restrict__ ZT)
{
    __shared__ float tile[32][33];
    int b = blockIdx.z;
    int i0 = blockIdx.y * 32, j0 = blockIdx.x * 32;
    int tx = threadIdx.x, ty = threadIdx.y;
    const float* Zb = Z + (long)b * NP1c * LDZ;
    float* Tb = ZT + (long)b * NP1c * LDZ;
    for (int ii = ty; ii < 32; ii += 8) {
        int i = i0 + ii, j = j0 + tx;
        if (i < NP1c && j < NP1c) tile[ii][tx] = Zb[(long)i * LDZ + j];
    }
    __syncthreads();
    for (int jj = ty; jj < 32; jj += 8) {
        int j = j0 + jj, i = i0 + tx;
        if (j < NP1c && i < NP1c) Tb[(long)j * LDZ + i] = tile[tx][jj];
    }
}

__global__ void zero_vec(float* __restrict__ v, int n)
{
    int i = blockIdx.x * 256 + threadIdx.x;
    if (i < n) v[i] = 0.f;
}

// out[b][i] = lmu(i) - LSE_j( M[b][i][j] + addv[b][j] ), vectorized float4 (LDZ rows)
__global__ __launch_bounds__(256) void sinkhorn_lse(
    const float* __restrict__ M, const float* __restrict__ addv, float* __restrict__ outv)
{
    __shared__ float sm[256], ss[256];
    const int i = blockIdx.x, b = blockIdx.y, t = threadIdx.x;
    const float* row = M + ((long)b * NP1c + i) * LDZ;
    const float* av = addv + (long)b * LDV;
    float4 x = ((const float4*)row)[t];
    float4 a = ((const float4*)av)[t];
    float v0 = x.x + a.x, v1 = x.y + a.y, v2 = x.z + a.z, v3 = x.w + a.w;
    float m = fmaxf(fmaxf(v0, v1), fmaxf(v2, v3));
    float s = __expf(v0 - m) + __expf(v1 - m) + __expf(v2 - m) + __expf(v3 - m);
    if (t == 0) {
        // elements 1024..1027 (1025..1027 are -1e30 pads)
        float4 x2 = ((const float4*)row)[256];
        float4 a2 = ((const float4*)av)[256];
        float v4 = x2.x + a2.x;
        if (v4 > m) { s = s * __expf(m - v4) + 1.f; m = v4; }
        else s += __expf(v4 - m);
    }
    sm[t] = m; ss[t] = s;
    __syncthreads();
    for (int st = 128; st > 0; st >>= 1) {
        if (t < st) {
            float m1 = sm[t], s1 = ss[t], m2 = sm[t + st], s2 = ss[t + st];
            float mm = fmaxf(m1, m2);
            sm[t] = mm;
            ss[t] = s1 * __expf(m1 - mm) + s2 * __expf(m2 - mm);
        }
        __syncthreads();
    }
    if (t == 0) {
        float lse = sm[0] + __logf(ss[0]);
        float lmu = (i < 1024) ? NORMV : (LOGNV + NORMV);
        outv[(long)b * LDV + i] = lmu - lse;
    }
}

__global__ __launch_bounds__(256) void final_out_k(
    const float* __restrict__ Z, const float* __restrict__ u,
    const float* __restrict__ v, float* __restrict__ outp)
{
    const int i = blockIdx.x, b = blockIdx.y, t = threadIdx.x;
    const float* row = Z + ((long)b * NP1c + i) * LDZ;
    float* orow = outp + ((long)b * NP1c + i) * NP1c;
    float ui = u[(long)b * LDV + i];
    for (int j = t; j < NP1c; j += 256)
        orow[j] = row[j] + ui + v[(long)b * LDV + j] - NORMV;
}

// =======================================================================
extern "C" void kernel_launch(void* const* d_in, const int* in_sizes, int n_in,
                              void* d_out, int out_size, void* d_ws, size_t ws_size,
                              hipStream_t stream)
{
    (void)in_sizes; (void)n_in; (void)out_size; (void)ws_size;
    const float* kpts0   = (const float*)d_in[0];
    const float* kpts1   = (const float*)d_in[1];
    const float* scores0 = (const float*)d_in[2];
    const float* scores1 = (const float*)d_in[3];
    const float* desc0   = (const float*)d_in[4];
    const float* desc1   = (const float*)d_in[5];
    const float* kw0 = (const float*)d_in[6];  const float* kb0 = (const float*)d_in[7];
    const float* kg0 = (const float*)d_in[8];  const float* ke0 = (const float*)d_in[9];
    const float* kw1 = (const float*)d_in[10]; const float* kb1 = (const float*)d_in[11];
    const float* kg1 = (const float*)d_in[12]; const float* ke1 = (const float*)d_in[13];
    const float* kw2 = (const float*)d_in[14]; const float* kb2 = (const float*)d_in[15];
    const float* kg2 = (const float*)d_in[16]; const float* ke2 = (const float*)d_in[17];
    const float* kw3 = (const float*)d_in[18]; const float* kb3 = (const float*)d_in[19];
    const float* gnn_proj_w  = (const float*)d_in[20];
    const float* gnn_proj_b  = (const float*)d_in[21];
    const float* gnn_merge_w = (const float*)d_in[22];
    const float* gnn_merge_b = (const float*)d_in[23];
    const float* gnn_mlp1_w  = (const float*)d_in[24];
    const float* gnn_mlp1_b  = (const float*)d_in[25];
    const float* gnn_ln_g    = (const float*)d_in[26];
    const float* gnn_ln_b    = (const float*)d_in[27];
    const float* gnn_mlp2_w  = (const float*)d_in[28];
    const float* gnn_mlp2_b  = (const float*)d_in[29];
    const float* final_w     = (const float*)d_in[30];
    const float* final_b     = (const float*)d_in[31];
    const float* bin_score   = (const float*)d_in[32];

    char* wsb = (char*)d_ws;
    size_t off = 0;
    auto alloc = [&](size_t bytes) -> void* {
        void* p = wsb + off;
        off = (off + bytes + 255) & ~(size_t)255;
        return p;
    };
    typedef __hip_bfloat16 bf;
    const long ROWS = 4L * Nc;
    // fp32
    float* descF  = (float*)alloc(ROWS * 256 * 4);
    float* ybufF  = (float*)alloc(ROWS * 512 * 4);
    float* Zm     = (float*)alloc((long)Bc * NP1c * LDZ * 4);
    float* ZT     = (float*)alloc((long)Bc * NP1c * LDZ * 4);
    float* uvec   = (float*)alloc(Bc * LDV * 4);
    float* vvec   = (float*)alloc(Bc * LDV * 4);
    float* projBp = (float*)alloc(9L * 768 * 4);
    float* b1c    = (float*)alloc(9L * 512 * 4);
    float* kw1T   = (float*)alloc(32L * 64 * 4);
    float* kw2T   = (float*)alloc(64L * 128 * 4);
    float* kw3T   = (float*)alloc(128L * 256 * 4);
    // activation planes
    bf* catHi = (bf*)alloc(ROWS * 512 * 2);  bf* catLo = (bf*)alloc(ROWS * 512 * 2);
    bf* qFh = (bf*)alloc(1048576 * 2); bf* qFl = (bf*)alloc(1048576 * 2);
    bf* kFh = (bf*)alloc(1048576 * 2);
    bf* vFh = (bf*)alloc(1048576 * 2);
    bf* ybHi  = (bf*)alloc(ROWS * 512 * 2);  bf* ybLo  = (bf*)alloc(ROWS * 512 * 2);
    bf* mdHi  = (bf*)alloc(ROWS * 256 * 2);  bf* mdLo  = (bf*)alloc(ROWS * 256 * 2);
    // weight planes
    bf* projHi = (bf*)alloc(9L*768*256*2);   bf* projLo = (bf*)alloc(9L*768*256*2);
    bf* mrgTHi = (bf*)alloc(9L*256*256*2);   bf* mrgTLo = (bf*)alloc(9L*256*256*2);
    bf* m1bHi  = (bf*)alloc(9L*512*256*2);   bf* m1bLo  = (bf*)alloc(9L*512*256*2);
    bf* m1cHi  = (bf*)alloc(9L*512*512*2);   bf* m1cLo  = (bf*)alloc(9L*512*512*2);
    bf* m2Hi   = (bf*)alloc(9L*256*512*2);   bf* m2Lo   = (bf*)alloc(9L*256*512*2);
    bf* finHi  = (bf*)alloc(256L*256*2);     bf* finLo  = (bf*)alloc(256L*256*2);

    // ---- weight prep ----
    wconv_proj<<<dim3((9*768*256+255)/256), 256, 0, stream>>>(gnn_proj_w, projHi, projLo);
    wconv_proj_bias<<<dim3(27), 256, 0, stream>>>(gnn_proj_b, projBp);
    wconv_mergeT<<<dim3((9*256*256+255)/256), 256, 0, stream>>>(gnn_merge_w, mrgTHi, mrgTLo);
    wconv_m1<<<dim3((int)((9L*512*512+255)/256)), 256, 0, stream>>>(gnn_mlp1_w, m1cHi, m1cLo, m1bHi, m1bLo);
    wconv_plain<<<dim3((9*256*512+255)/256), 256, 0, stream>>>(gnn_mlp2_w, m2Hi, m2Lo, 9L*256*512);
    wconv_plain<<<dim3((256*256+255)/256), 256, 0, stream>>>(final_w, finHi, finLo, 256L*256);
    bias_fold<<<dim3(9*512), 64, 0, stream>>>(gnn_mlp1_w, gnn_mlp1_b, gnn_merge_b, b1c);
    transposeW<<<dim3((64*32+255)/256), 256, 0, stream>>>(kw1, kw1T, 64, 32);
    transposeW<<<dim3((128*64+255)/256), 256, 0, stream>>>(kw2, kw2T, 128, 64);
    transposeW<<<dim3((256*128+255)/256), 256, 0, stream>>>(kw3, kw3T, 256, 128);
    // combined mlp1 cols 256..511 = W1b x WmT^T per layer (full hi/lo accuracy)
    mfma_nt<128,128,1,1><<<dim3(2,4,9), 256, 0, stream>>>(
        (const short*)m1bHi, (const short*)m1bLo, 256,
        (const short*)mrgTHi, (const short*)mrgTLo, 256,
        256, 1.f, nullptr,
        nullptr, m1cHi + 256, m1cLo + 256, nullptr, nullptr, 512,
        512L*256, 256L*256, 512L*512);

    // ---- keypoint encoder -> descF + cat planes cols 0..255 ----
    kenc_kernel<<<dim3(Nc, Bc), 256, 0, stream>>>(kpts0, scores0, desc0, descF,
        catHi, catLo,
        kw0, kb0, kg0, ke0, kw1T, kb1, kg1, ke1, kw2T, kb2, kg2, ke2, kw3T, kb3);
    kenc_kernel<<<dim3(Nc, Bc), 256, 0, stream>>>(kpts1, scores1, desc1, descF + 2L*Nc*256,
        catHi + 2L*Nc*512, catLo + 2L*Nc*512,
        kw0, kb0, kg0, ke0, kw1T, kb1, kg1, ke1, kw2T, kb2, kg2, ke2, kw3T, kb3);

    // ---- GNN layers ----
    for (int l = 0; l < 9; ++l) {
        // 1) qkv GEMM (W hi-only, 64x64 tiles for occupancy) -> Q hi/lo + K hi + V hi
        mfma_nt<64,64,2,0><<<dim3(12,64,1), 256, 0, stream>>>(
            (const short*)catHi, (const short*)catLo, 512,
            (const short*)(projHi + (long)l*768*256), nullptr, 256,
            256, 1.f, projBp + (long)l*768,
            nullptr, qFh, qFl, vFh, kFh, 0,
            0, 0, 0);
        // 2) fused attention -> catbuf cols 256..511
        attn_fused<<<dim3(64, 16), 256, 0, stream>>>(qFh, qFl, kFh, vFh, catHi, catLo);
        // 3) mlp1 (W hi-only, combined weights, 64x64) -> ybufF
        mfma_nt<64,64,0,0><<<dim3(8,64,1), 256, 0, stream>>>(
            (const short*)catHi, (const short*)catLo, 512,
            (const short*)(m1cHi + (long)l*512*512), nullptr, 512,
            512, 1.f, b1c + (long)l*512,
            ybufF, nullptr, nullptr, nullptr, nullptr, 512,
            0, 0, 0);
        // 4) LN+ReLU -> yb planes
        ln_relu_planes<<<dim3((unsigned)ROWS), 256, 0, stream>>>(
            ybufF, gnn_ln_g + (long)l*512, gnn_ln_b + (long)l*512, ybHi, ybLo);
        // 5) mlp2 (W hi-only) fused residual -> descF + cat cols 0..255
        mfma_nt<64,64,3,0><<<dim3(4,64,1), 256, 0, stream>>>(
            (const short*)ybHi, (const short*)ybLo, 512,
            (const short*)(m2Hi + (long)l*256*512), nullptr, 512,
            512, 1.f, gnn_mlp2_b + (long)l*256,
            descF, catHi, catLo, nullptr, nullptr, 0,
            0, 0, 0);
    }

    // ---- final projection (W hi-only) -> mdesc planes ----
    mfma_nt<64,64,1,0><<<dim3(4,64,1), 256, 0, stream>>>(
        (const short*)catHi, (const short*)catLo, 512,
        (const short*)finHi, nullptr, 256,
        256, 1.f, final_b,
        nullptr, mdHi, mdLo, nullptr, nullptr, 256,
        0, 0, 0);
    // ---- score matrix into Z (activation x activation: full hi/lo; 64x64 tiles) ----
    mfma_nt<64,64,0,1><<<dim3(16,16,2), 256, 0, stream>>>(
        (const short*)mdHi, (const short*)mdLo, 256,
        (const short*)mdHi + 2048L*256, (const short*)mdLo + 2048L*256, 256,
        256, 1.f/16.f, nullptr,
        Zm, nullptr, nullptr, nullptr, nullptr, LDZ,
        1024L*256, 1024L*256, (long)NP1c*LDZ);
    bins_fill<<<dim3(9,2), 256, 0, stream>>>(Zm, bin_score);

    // ---- Sinkhorn (log-space), 20 iterations ----
    transpose_np1<<<dim3(33,33,2), dim3(32,8), 0, stream>>>(Zm, ZT);
    pad_fill<<<dim3((2*NP1c*3+255)/256), 256, 0, stream>>>(Zm, ZT);
    zero_vec<<<dim3((2*LDV+255)/256), 256, 0, stream>>>(vvec, Bc * LDV);
    zero_vec<<<dim3((2*LDV+255)/256), 256, 0, stream>>>(uvec, Bc * LDV);
    for (int it = 0; it < 20; ++it) {
        sinkhorn_lse<<<dim3(NP1c, Bc), 256, 0, stream>>>(Zm, vvec, uvec);
        sinkhorn_lse<<<dim3(NP1c, Bc), 256, 0, stream>>>(ZT, uvec, vvec);
    }
    final_out_k<<<dim3(NP1c, Bc), 256, 0, stream>>>(Zm, uvec, vvec, (float*)d_out);
}

// Round 10
// 907.426 us; speedup vs baseline: 6.4572x; 1.1039x over previous
//
#include <hip/hip_runtime.h>
#include <hip/hip_bf16.h>
#include <math.h>

#define DEVI static __device__ __forceinline__

namespace {
constexpr int Bc   = 2;
constexpr int Nc   = 1024;
constexpr int Dc   = 256;
constexpr int NP1c = 1025;
constexpr int LDZ  = 1028;              // padded Z row stride (16B-aligned)
constexpr int LDV  = 1028;              // padded u/v stride
constexpr float LN_EPS = 1e-6f;
constexpr float NORMV  = -7.6246189861593985f; // -log(2048)
constexpr float LOGNV  =  6.9314718055994531f; // log(1024)
}

typedef __attribute__((ext_vector_type(8))) short bf16x8;
typedef __attribute__((ext_vector_type(4))) float f32x4;

DEVI void split2(float v, __hip_bfloat16& h, __hip_bfloat16& l) {
    h = __float2bfloat16(v);
    l = __float2bfloat16(v - __bfloat162float(h));
}

// async global->LDS, 16B per lane
#define GLDS16(gp, lp) __builtin_amdgcn_global_load_lds( \
    (const __attribute__((address_space(1))) void*)(gp), \
    (__attribute__((address_space(3))) void*)(lp), 16, 0, 0)

// ---------------- helpers ----------------
DEVI float block_sum_256(float v, float* scratch) {
    int t = threadIdx.x;
    scratch[t] = v;
    __syncthreads();
    for (int s = 128; s > 0; s >>= 1) {
        if (t < s) scratch[t] += scratch[t + s];
        __syncthreads();
    }
    float r = scratch[0];
    __syncthreads();
    return r;
}

DEVI void ln_relu_inplace(float* x, const float* g, const float* be, int C, float* scratch) {
    int t = threadIdx.x;
    float v = (t < C) ? x[t] : 0.f;
    float mean = block_sum_256(v, scratch) / (float)C;
    float dv = (t < C) ? (x[t] - mean) : 0.f;
    float var = block_sum_256(dv * dv, scratch) / (float)(C - 1);
    float rstd = 1.f / (sqrtf(var) + LN_EPS);
    if (t < C) x[t] = fmaxf(g[t] * dv * rstd + be[t], 0.f);
    __syncthreads();
}

// ---------------- keypoint encoder (coalesced weights; writes cat planes) ----------------
__global__ __launch_bounds__(256) void kenc_kernel(
    const float* __restrict__ kpts, const float* __restrict__ scr,
    const float* __restrict__ desc_in, float* __restrict__ desc_out,
    __hip_bfloat16* __restrict__ catHi, __hip_bfloat16* __restrict__ catLo,
    const float* __restrict__ w0, const float* __restrict__ b0,
    const float* __restrict__ g0, const float* __restrict__ be0,
    const float* __restrict__ w1T, const float* __restrict__ b1,
    const float* __restrict__ g1, const float* __restrict__ be1,
    const float* __restrict__ w2T, const float* __restrict__ b2,
    const float* __restrict__ g2, const float* __restrict__ be2,
    const float* __restrict__ w3T, const float* __restrict__ b3)
{
    __shared__ float xa[256], xb[256], scratch[256];
    const int n = blockIdx.x, b = blockIdx.y, t = threadIdx.x;
    if (t == 0) {
        float kx = kpts[((long)b * Nc + n) * 2 + 0];
        float ky = kpts[((long)b * Nc + n) * 2 + 1];
        xa[0] = (kx - 320.f) * (1.f / 448.f);
        xa[1] = (ky - 240.f) * (1.f / 448.f);
        xa[2] = scr[b * Nc + n];
    }
    __syncthreads();
    if (t < 32) { float a = b0[t]; for (int c = 0; c < 3;  ++c) a += w0[t*3 + c] * xa[c]; xb[t] = a; }
    __syncthreads();
    ln_relu_inplace(xb, g0, be0, 32, scratch);
    if (t < 64) {
        float a = b1[t];
        #pragma unroll 8
        for (int c = 0; c < 32;  ++c) a += w1T[c*64 + t] * xb[c];
        xa[t] = a;
    }
    __syncthreads();
    ln_relu_inplace(xa, g1, be1, 64, scratch);
    if (t < 128) {
        float a = b2[t];
        #pragma unroll 8
        for (int c = 0; c < 64;  ++c) a += w2T[c*128 + t] * xa[c];
        xb[t] = a;
    }
    __syncthreads();
    ln_relu_inplace(xb, g2, be2, 128, scratch);
    {   float a = b3[t];
        #pragma unroll 8
        for (int c = 0; c < 128; ++c) a += w3T[c*256 + t] * xb[c];
        float v = desc_in[((long)b * Dc + t) * Nc + n] + a;
        desc_out[((long)b * Nc + n) * Dc + t] = v;
        __hip_bfloat16 h, l; split2(v, h, l);
        long cr = ((long)b * Nc + n) * 512 + t;
        catHi[cr] = h; catLo[cr] = l;
    }
}

__global__ __launch_bounds__(256) void transposeW(
    const float* __restrict__ src, float* __restrict__ dst, int O, int C)
{
    long i = (long)blockIdx.x * 256 + threadIdx.x;
    if (i >= (long)O * C) return;
    int o = (int)(i / C), c = (int)(i % C);
    dst[(long)c * O + o] = src[i];
}

// =======================================================================
// MFMA NT GEMM, BK=64. A hi(+lo if ALO); B hi(+lo if BLO).
// EPI: 0 fp32 out; 1 bf16 hi/lo planes; 2 qkv -> Q/K/V hi frag-order;
//      3 mlp2 fused resid (descF + cat hi/lo cols 0..255). K % 64 == 0.
// =======================================================================
template<int BM, int BN, int EPI, int BLO, int ALO>
__global__ __launch_bounds__(256) void mfma_nt(
    const short* __restrict__ Ahi0, const short* __restrict__ Alo0, int lda,
    const short* __restrict__ Bhi0, const short* __restrict__ Blo0, int ldb,
    int K, float scale, const float* __restrict__ bias,
    float* __restrict__ outF, __hip_bfloat16* __restrict__ outHi,
    __hip_bfloat16* __restrict__ outLo,
    __hip_bfloat16* __restrict__ outHi2, __hip_bfloat16* __restrict__ outHi3,
    int ldo,
    long aS1, long bS1, long oS1)
{
    constexpr int MI = BM / 32;
    constexpr int NI = BN / 32;
    constexpr int instA = BM / 16, instB = BN / 16;
    constexpr int OFF_AH = 0;
    constexpr int OFF_AL = BM * 32;                       // valid when ALO
    constexpr int OFF_BH = (1 + ALO) * BM * 32;
    constexpr int OFF_BL = OFF_BH + BN * 32;              // valid when BLO
    constexpr int CHUNK = ((1 + ALO) * BM + (1 + BLO) * BN) * 32;
    __shared__ short smem[2 * CHUNK];

    const int z = blockIdx.z;
    const long aOff = z * aS1, bOff = z * bS1, oOff = z * oS1;
    const short* Ah = Ahi0 + aOff;
    const short* Al = ALO ? (Alo0 + aOff) : nullptr;
    const short* Bh = Bhi0 + bOff;
    const short* Bl = BLO ? (Blo0 + bOff) : nullptr;

    const int m0 = blockIdx.y * BM, n0 = blockIdx.x * BN;
    const int t = threadIdx.x, lane = t & 63, wid = t >> 6;
    const int lr = lane & 15, lg = lane >> 4;
    const int wr = wid >> 1, wc = wid & 1;

    f32x4 acc[MI][NI];
    for (int mi = 0; mi < MI; ++mi)
        for (int ni = 0; ni < NI; ++ni)
            acc[mi][ni] = f32x4{0.f, 0.f, 0.f, 0.f};

    for (int k0 = 0; k0 < K; k0 += 64) {
        constexpr int total = (1 + ALO) * instA + (1 + BLO) * instB;
        for (int q = wid; q < total; q += 4) {
            const short* gsrc; int ldg, mi, ploff, row0;
            if (q < instA)                      { gsrc = Ah; ldg = lda; mi = q;          ploff = OFF_AH; row0 = m0; }
            else if (ALO && q < 2 * instA)      { gsrc = Al; ldg = lda; mi = q - instA;  ploff = OFF_AL; row0 = m0; }
            else {
                int rb = q - (1 + ALO) * instA;
                if (rb < instB) { gsrc = Bh; mi = rb;         ploff = OFF_BH; }
                else            { gsrc = Bl; mi = rb - instB; ploff = OFF_BL; }
                ldg = ldb; row0 = n0;
            }
            const short* g = gsrc + (long)(row0 + mi * 16 + lr) * ldg + (k0 + lg * 8);
            GLDS16(g,      smem + ploff + mi * 512);
            GLDS16(g + 32, smem + CHUNK + ploff + mi * 512);
        }
        __syncthreads();
        #pragma unroll
        for (int kc2 = 0; kc2 < 2; ++kc2) {
            const short* sm2 = smem + kc2 * CHUNK;
            bf16x8 ah[MI], al[MI];
            #pragma unroll
            for (int mi = 0; mi < MI; ++mi) {
                ah[mi] = *(const bf16x8*)(sm2 + OFF_AH + ((wr * MI + mi) * 64 + lane) * 8);
                if (ALO) al[mi] = *(const bf16x8*)(sm2 + OFF_AL + ((wr * MI + mi) * 64 + lane) * 8);
            }
            #pragma unroll
            for (int ni = 0; ni < NI; ++ni) {
                bf16x8 bh = *(const bf16x8*)(sm2 + OFF_BH + ((wc * NI + ni) * 64 + lane) * 8);
                #pragma unroll
                for (int mi = 0; mi < MI; ++mi) {
                    acc[mi][ni] = __builtin_amdgcn_mfma_f32_16x16x32_bf16(ah[mi], bh, acc[mi][ni], 0, 0, 0);
                    if (ALO) acc[mi][ni] = __builtin_amdgcn_mfma_f32_16x16x32_bf16(al[mi], bh, acc[mi][ni], 0, 0, 0);
                }
                if (BLO) {
                    bf16x8 bl = *(const bf16x8*)(sm2 + OFF_BL + ((wc * NI + ni) * 64 + lane) * 8);
                    #pragma unroll
                    for (int mi = 0; mi < MI; ++mi)
                        acc[mi][ni] = __builtin_amdgcn_mfma_f32_16x16x32_bf16(ah[mi], bl, acc[mi][ni], 0, 0, 0);
                }
            }
        }
        __syncthreads();
    }

    for (int mi = 0; mi < MI; ++mi) {
        for (int i = 0; i < 4; ++i) {
            int row = m0 + wr * (BM / 2) + mi * 16 + lg * 4 + i;
            for (int ni = 0; ni < NI; ++ni) {
                int col = n0 + wc * (BN / 2) + ni * 16 + lr;
                float v = acc[mi][ni][i] * scale;
                if (bias) v += bias[col];
                if (EPI == 0) {
                    outF[(long)row * ldo + col + oOff] = v;
                } else if (EPI == 1) {
                    __hip_bfloat16 h, l;
                    split2(v, h, l);
                    outHi[(long)row * ldo + col + oOff] = h;
                    outLo[(long)row * ldo + col + oOff] = l;
                } else if (EPI == 2) {
                    // Q/K/V hi-only fragment-order scatter
                    int dirb = row >> 10, rloc = row & 1023;
                    int tq = col >> 8, within = col & 255;
                    int h4 = within >> 6, hd = within & 63;
                    __hip_bfloat16 hh = __float2bfloat16(v);
                    if (tq == 2) {
                        int w2 = rloc >> 8, mloc = rloc & 255;
                        int lane2 = ((mloc & 31) >> 3) * 16 + (hd & 15);
                        long idx = ((((long)(dirb*4+h4)*4 + w2)*8 + (mloc>>5))*4 + (hd>>4))*512 + lane2*8 + (mloc&7);
                        outHi2[idx] = hh;
                    } else {
                        int lane2 = ((hd & 31) >> 3) * 16 + (rloc & 15);
                        long idx = (((long)(dirb*4+h4)*64 + (rloc>>4))*2 + (hd>>5))*512 + lane2*8 + (hd&7);
                        if (tq == 0) outHi[idx] = hh;
                        else         outHi3[idx] = hh;
                    }
                } else { // EPI==3: fused residual (descF) + cat planes cols 0..255
                    long i256 = (long)row * 256 + col;
                    v += outF[i256];
                    outF[i256] = v;
                    __hip_bfloat16 h, l;
                    split2(v, h, l);
                    outHi[(long)row * 512 + col] = h;
                    outLo[(long)row * 512 + col] = l;
                }
            }
        }
    }
}

// =======================================================================
// Fully fused attention. Q,K,V hi-only. Fragment-order coalesced loads.
// =======================================================================
__global__ __launch_bounds__(256) void attn_fused(
    const __hip_bfloat16* __restrict__ qFh,
    const __hip_bfloat16* __restrict__ kFh, const __hip_bfloat16* __restrict__ vFh,
    __hip_bfloat16* __restrict__ catHi)
{
    __shared__ short pLds[4 * 16 * 256];   // 32KB; reused as f32 partials
    __shared__ float redm[4][16], reds[4][16];
    const int y = blockIdx.y;
    const int dir = y >> 3, b = (y >> 2) & 1, h = y & 3;
    const int q0 = blockIdx.x * 16;
    const int t = threadIdx.x, lane = t & 63, w = t >> 6;
    const int lr = lane & 15, lg = lane >> 4;
    const int dbQ = dir * 2 + b;
    const int srcdb = (1 - dir) * 2 + b;
    const short* qh = (const short*)qFh;
    const short* kh = (const short*)kFh;
    const short* vh = (const short*)vFh;

    const long qbase = (((long)(dbQ * 4 + h)) * 64 + (q0 >> 4)) * 2;
    bf16x8 ah[2];
    #pragma unroll
    for (int kc = 0; kc < 2; ++kc)
        ah[kc] = *(const bf16x8*)(qh + (qbase + kc) * 512 + lane * 8);

    f32x4 acc[16];
    #pragma unroll
    for (int ni = 0; ni < 16; ++ni) acc[ni] = f32x4{0.f, 0.f, 0.f, 0.f};

    const long kbase0 = (((long)(srcdb * 4 + h)) * 64 + w * 16) * 2;
    #pragma unroll
    for (int ni = 0; ni < 16; ++ni) {
        long kb = (kbase0 + ni * 2) * 512 + lane * 8;
        bf16x8 bh0 = *(const bf16x8*)(kh + kb);
        bf16x8 bh1 = *(const bf16x8*)(kh + kb + 512);
        acc[ni] = __builtin_amdgcn_mfma_f32_16x16x32_bf16(ah[0], bh0, acc[ni], 0, 0, 0);
        acc[ni] = __builtin_amdgcn_mfma_f32_16x16x32_bf16(ah[1], bh1, acc[ni], 0, 0, 0);
    }

    float mx[4] = {-1e30f, -1e30f, -1e30f, -1e30f};
    #pragma unroll
    for (int ni = 0; ni < 16; ++ni)
        #pragma unroll
        for (int i = 0; i < 4; ++i) {
            float v = acc[ni][i] * 0.125f;
            acc[ni][i] = v;
            mx[i] = fmaxf(mx[i], v);
        }
    #pragma unroll
    for (int off = 1; off < 16; off <<= 1)
        #pragma unroll
        for (int i = 0; i < 4; ++i) mx[i] = fmaxf(mx[i], __shfl_xor(mx[i], off));
    if (lr == 0)
        #pragma unroll
        for (int i = 0; i < 4; ++i) redm[w][lg * 4 + i] = mx[i];
    __syncthreads();
    float Mv[4];
    #pragma unroll
    for (int i = 0; i < 4; ++i)
        Mv[i] = fmaxf(fmaxf(redm[0][lg*4+i], redm[1][lg*4+i]),
                      fmaxf(redm[2][lg*4+i], redm[3][lg*4+i]));
    float sm[4] = {0.f, 0.f, 0.f, 0.f};
    #pragma unroll
    for (int ni = 0; ni < 16; ++ni)
        #pragma unroll
        for (int i = 0; i < 4; ++i) {
            float e = __expf(acc[ni][i] - Mv[i]);
            acc[ni][i] = e;
            sm[i] += e;
        }
    #pragma unroll
    for (int off = 1; off < 16; off <<= 1)
        #pragma unroll
        for (int i = 0; i < 4; ++i) sm[i] += __shfl_xor(sm[i], off);
    if (lr == 0)
        #pragma unroll
        for (int i = 0; i < 4; ++i) reds[w][lg * 4 + i] = sm[i];
    __syncthreads();
    float inv[4];
    #pragma unroll
    for (int i = 0; i < 4; ++i)
        inv[i] = 1.f / (reds[0][lg*4+i] + reds[1][lg*4+i] + reds[2][lg*4+i] + reds[3][lg*4+i]);

    char* pB = (char*)pLds + w * 8192;
    #pragma unroll
    for (int ni = 0; ni < 16; ++ni)
        #pragma unroll
        for (int i = 0; i < 4; ++i) {
            int q = lg * 4 + i, m = ni * 16 + lr;
            int byte = (q * 512 + m * 2) ^ ((q & 7) << 4);
            *(short*)(pB + byte) = (short)__bfloat16_as_ushort(__float2bfloat16(acc[ni][i] * inv[i]));
        }
    __syncthreads();

    f32x4 acc2[4];
    #pragma unroll
    for (int bi = 0; bi < 4; ++bi) acc2[bi] = f32x4{0.f, 0.f, 0.f, 0.f};
    const long vbase0 = (((long)(srcdb * 4 + h)) * 4 + w) * 8;
    #pragma unroll
    for (int km = 0; km < 8; ++km) {
        int rb = (lr * 512 + km * 64 + lg * 16) ^ ((lr & 7) << 4);
        bf16x8 pa = *(const bf16x8*)(pB + rb);
        #pragma unroll
        for (int bi = 0; bi < 4; ++bi) {
            long vr = ((vbase0 + km) * 4 + bi) * 512 + lane * 8;
            bf16x8 vhf = *(const bf16x8*)(vh + vr);
            acc2[bi] = __builtin_amdgcn_mfma_f32_16x16x32_bf16(pa, vhf, acc2[bi], 0, 0, 0);
        }
    }
    __syncthreads();
    float* pr = (float*)pLds;
    #pragma unroll
    for (int bi = 0; bi < 4; ++bi)
        #pragma unroll
        for (int i = 0; i < 4; ++i)
            pr[w * 1024 + (lg * 4 + i) * 64 + bi * 16 + lr] = acc2[bi][i];
    __syncthreads();
    #pragma unroll
    for (int k = 0; k < 4; ++k) {
        int e = t + k * 256;
        float v = pr[e] + pr[1024 + e] + pr[2048 + e] + pr[3072 + e];
        int q = e >> 6, d = e & 63;
        long a = ((long)dbQ * 1024 + q0 + q) * 512 + 256 + h * 64 + d;
        catHi[a] = __float2bfloat16(v);
    }
}

// ---------------- LN(channel,ddof=1,eps-on-std)+ReLU; wave-per-row; write hi ----------------
__global__ __launch_bounds__(256) void ln_relu_w(
    const float* __restrict__ y, const float* __restrict__ g, const float* __restrict__ be,
    __hip_bfloat16* __restrict__ hi)
{
    const int t = threadIdx.x, lane = t & 63, w = t >> 6;
    const long row = (long)blockIdx.x * 4 + w;
    const float* src = y + row * 512;
    float4 v0 = ((const float4*)src)[lane * 2];
    float4 v1 = ((const float4*)src)[lane * 2 + 1];
    float s = v0.x + v0.y + v0.z + v0.w + v1.x + v1.y + v1.z + v1.w;
    float q = v0.x*v0.x + v0.y*v0.y + v0.z*v0.z + v0.w*v0.w
            + v1.x*v1.x + v1.y*v1.y + v1.z*v1.z + v1.w*v1.w;
    #pragma unroll
    for (int off = 1; off < 64; off <<= 1) {
        s += __shfl_xor(s, off);
        q += __shfl_xor(q, off);
    }
    float mean = s / 512.f;
    float var = fmaxf((q - 512.f * mean * mean) / 511.f, 0.f);
    float rstd = 1.f / (sqrtf(var) + LN_EPS);
    float4 g0 = ((const float4*)g)[lane * 2], g1 = ((const float4*)g)[lane * 2 + 1];
    float4 b0 = ((const float4*)be)[lane * 2], b1 = ((const float4*)be)[lane * 2 + 1];
    float xv[8] = {v0.x, v0.y, v0.z, v0.w, v1.x, v1.y, v1.z, v1.w};
    float gv[8] = {g0.x, g0.y, g0.z, g0.w, g1.x, g1.y, g1.z, g1.w};
    float bv[8] = {b0.x, b0.y, b0.z, b0.w, b1.x, b1.y, b1.z, b1.w};
    bf16x8 outv;
    #pragma unroll
    for (int k = 0; k < 8; ++k) {
        float o = fmaxf(gv[k] * (xv[k] - mean) * rstd + bv[k], 0.f);
        outv[k] = (short)__bfloat16_as_ushort(__float2bfloat16(o));
    }
    *(bf16x8*)((short*)hi + row * 512 + lane * 8) = outv;
}

// ---------------- weight converts ----------------
__global__ __launch_bounds__(256) void wconv_plain(
    const float* __restrict__ w, __hip_bfloat16* __restrict__ hi, __hip_bfloat16* __restrict__ lo, long total)
{
    long i = (long)blockIdx.x * 256 + threadIdx.x;
    if (i >= total) return;
    __hip_bfloat16 h, l; split2(w[i], h, l);
    hi[i] = h; lo[i] = l;
}

__global__ __launch_bounds__(256) void wconv_proj(
    const float* __restrict__ w, __hip_bfloat16* __restrict__ hi, __hip_bfloat16* __restrict__ lo)
{
    long i = (long)blockIdx.x * 256 + threadIdx.x;
    if (i >= 9L * 768 * 256) return;
    long l9 = i / (768 * 256);
    int rem = (int)(i % (768 * 256));
    int op = rem / 256, c = rem % 256;
    int tq = op / 256, within = op % 256;
    int h = within / 64, hd = within % 64;
    int o = tq * 256 + hd * 4 + h;
    float v = w[(l9 * 768 + o) * 256 + c];
    __hip_bfloat16 hh, ll; split2(v, hh, ll);
    hi[i] = hh; lo[i] = ll;
}

__global__ void wconv_proj_bias(const float* __restrict__ b, float* __restrict__ bp)
{
    int i = blockIdx.x * 256 + threadIdx.x;
    if (i >= 9 * 768) return;
    int l9 = i / 768, op = i % 768;
    int tq = op / 256, within = op % 256;
    int h = within / 64, hd = within % 64;
    bp[i] = b[(l9 * 3 + tq) * 256 + hd * 4 + h];
}

// WmT planes: [l][c=h*64+hd][j] = Wm[l][j][hd*4+h]
__global__ __launch_bounds__(256) void wconv_mergeT(
    const float* __restrict__ w, __hip_bfloat16* __restrict__ hi, __hip_bfloat16* __restrict__ lo)
{
    long i = (long)blockIdx.x * 256 + threadIdx.x;
    if (i >= 9L * 256 * 256) return;
    long l9 = i / (256 * 256);
    int rem = (int)(i % (256 * 256));
    int c = rem / 256, j = rem % 256;
    int h = c / 64, hd = c % 64;
    float v = w[(l9 * 256 + j) * 256 + (hd * 4 + h)];
    __hip_bfloat16 hh, ll; split2(v, hh, ll);
    hi[i] = hh; lo[i] = ll;
}

// mlp1 W split: cols 0..255 -> m1c[..512-wide cols 0..255]; cols 256..511 -> m1b[..256-wide]
__global__ __launch_bounds__(256) void wconv_m1(
    const float* __restrict__ w,
    __hip_bfloat16* __restrict__ m1cHi, __hip_bfloat16* __restrict__ m1cLo,
    __hip_bfloat16* __restrict__ m1bHi, __hip_bfloat16* __restrict__ m1bLo)
{
    long i = (long)blockIdx.x * 256 + threadIdx.x;
    if (i >= 9L * 512 * 512) return;
    long lo9 = i / 512;
    int c = (int)(i % 512);
    __hip_bfloat16 hh, ll; split2(w[i], hh, ll);
    if (c < 256) { m1cHi[lo9 * 512 + c] = hh; m1cLo[lo9 * 512 + c] = ll; }
    else         { m1bHi[lo9 * 256 + c - 256] = hh; m1bLo[lo9 * 256 + c - 256] = ll; }
}

// b1c[l*512+o] = b1[l][o] + sum_j W1[l][o][256+j]*bm[l][j]
__global__ __launch_bounds__(64) void bias_fold(
    const float* __restrict__ w1, const float* __restrict__ b1,
    const float* __restrict__ bm, float* __restrict__ out)
{
    int og = blockIdx.x;
    int l = og >> 9, o = og & 511;
    int t = threadIdx.x;
    float s = 0.f;
    for (int j = t; j < 256; j += 64)
        s += w1[((long)l * 512 + o) * 512 + 256 + j] * bm[l * 256 + j];
    for (int off = 32; off > 0; off >>= 1) s += __shfl_down(s, off);
    if (t == 0) out[og] = b1[(long)l * 512 + o] + s;
}

// ---------------- Sinkhorn pieces (padded LDZ=1028 layout) ----------------
__global__ void bins_fill(float* __restrict__ Z, const float* __restrict__ alpha_p)
{
    float alpha = alpha_p[0];
    int idx = blockIdx.x * 256 + threadIdx.x;
    int b = blockIdx.y;
    float* Zb = Z + (long)b * NP1c * LDZ;
    if (idx < NP1c) Zb[(long)1024 * LDZ + idx] = alpha;
    else { int i = idx - NP1c; if (i < 1024) Zb[(long)i * LDZ + 1024] = alpha; }
}

__global__ void transpose_np1(const float* __restrict__ Z, float* __restrict__ ZT)
{
    __shared__ float tile[32][33];
    int b = blockIdx.z;
    int i0 = blockIdx.y * 32, j0 = blockIdx.x * 32;
    int tx = threadIdx.x, ty = threadIdx.y;
    const float* Zb = Z + (long)b * NP1c * LDZ;
    float* Tb = ZT + (long)b * NP1c * LDZ;
    for (int ii = ty; ii < 32; ii += 8) {
        int i = i0 + ii, j = j0 + tx;
        if (i < NP1c && j < NP1c) tile[ii][tx] = Zb[(long)i * LDZ + j];
    }
    __syncthreads();
    for (int jj = ty; jj < 32; jj += 8) {
        int j = j0 + jj, i = i0 + tx;
        if (j < NP1c && i < NP1c) Tb[(long)j * LDZ + i] = tile[tx][jj];
    }
}

__global__ void zero_vec(float* __restrict__ v, int n)
{
    int i = blockIdx.x * 256 + threadIdx.x;
    if (i < n) v[i] = 0.f;
}

// wave-per-row LSE: out[b][i] = lmu(i) - LSE_j( M[b][i][j] + addv[b][j] )
__global__ __launch_bounds__(256) void sinkhorn_lse(
    const float* __restrict__ M, const float* __restrict__ addv, float* __restrict__ outv)
{
    const int t = threadIdx.x, lane = t & 63, w = t >> 6;
    long rowid = (long)blockIdx.x * 4 + w;
    if (rowid >= 2 * NP1c) return;        // wave-uniform exit
    int b = rowid >= NP1c ? 1 : 0;
    int i = (int)(rowid - (long)b * NP1c);
    const float* row = M + ((long)b * NP1c + i) * LDZ;
    const float* av = addv + (long)b * LDV;
    float m = -1e30f, s = 0.f;
    #pragma unroll
    for (int k = 0; k < 4; ++k) {
        float4 x = ((const float4*)row)[lane * 4 + k];
        float4 a = ((const float4*)av)[lane * 4 + k];
        float u0 = x.x + a.x, u1 = x.y + a.y, u2 = x.z + a.z, u3 = x.w + a.w;
        float mk = fmaxf(fmaxf(u0, u1), fmaxf(u2, u3));
        float sk = __expf(u0 - mk) + __expf(u1 - mk) + __expf(u2 - mk) + __expf(u3 - mk);
        if (mk > m) { s = s * __expf(m - mk) + sk; m = mk; }
        else        { s += sk * __expf(mk - m); }
    }
    if (lane == 0) {
        float v4 = row[1024] + av[1024];
        if (v4 > m) { s = s * __expf(m - v4) + 1.f; m = v4; }
        else        { s += __expf(v4 - m); }
    }
    #pragma unroll
    for (int off = 1; off < 64; off <<= 1) {
        float m2 = __shfl_xor(m, off);
        float s2 = __shfl_xor(s, off);
        float mm = fmaxf(m, m2);
        s = s * __expf(m - mm) + s2 * __expf(m2 - mm);
        m = mm;
    }
    if (lane == 0) {
        float lse = m + __logf(s);
        float lmu = (i < 1024) ? NORMV : (LOGNV + NORMV);
        outv[(long)b * LDV + i] = lmu - lse;
    }
}

__global__ __launch_bounds__(256) void final_out_k(
    const float* __restrict__ Z, const float* __restrict__ u,
    const float* __restrict__ v, float* __restrict__ outp)
{
    const int i = blockIdx.x, b = blockIdx.y, t = threadIdx.x;
    const float* row = Z + ((long)b * NP1c + i) * LDZ;
    float* orow = outp + ((long)b * NP1c + i) * NP1c;
    float ui = u[(long)b * LDV + i];
    for (int j = t; j < NP1c; j += 256)
        orow[j] = row[j] + ui + v[(long)b * LDV + j] - NORMV;
}

// =======================================================================
extern "C" void kernel_launch(void* const* d_in, const int* in_sizes, int n_in,
                              void* d_out, int out_size, void* d_ws, size_t ws_size,
                              hipStream_t stream)
{
    (void)in_sizes; (void)n_in; (void)out_size; (void)ws_size;
    const float* kpts0   = (const float*)d_in[0];
    const float* kpts1   = (const float*)d_in[1];
    const float* scores0 = (const float*)d_in[2];
    const float* scores1 = (const float*)d_in[3];
    const float* desc0   = (const float*)d_in[4];
    const float* desc1   = (const float*)d_in[5];
    const float* kw0 = (const float*)d_in[6];  const float* kb0 = (const float*)d_in[7];
    const float* kg0 = (const float*)d_in[8];  const float* ke0 = (const float*)d_in[9];
    const float* kw1 = (const float*)d_in[10]; const float* kb1 = (const float*)d_in[11];
    const float* kg1 = (const float*)d_in[12]; const float* ke1 = (const float*)d_in[13];
    const float* kw2 = (const float*)d_in[14]; const float* kb2 = (const float*)d_in[15];
    const float* kg2 = (const float*)d_in[16]; const float* ke2 = (const float*)d_in[17];
    const float* kw3 = (const float*)d_in[18]; const float* kb3 = (const float*)d_in[19];
    const float* gnn_proj_w  = (const float*)d_in[20];
    const float* gnn_proj_b  = (const float*)d_in[21];
    const float* gnn_merge_w = (const float*)d_in[22];
    const float* gnn_merge_b = (const float*)d_in[23];
    const float* gnn_mlp1_w  = (const float*)d_in[24];
    const float* gnn_mlp1_b  = (const float*)d_in[25];
    const float* gnn_ln_g    = (const float*)d_in[26];
    const float* gnn_ln_b    = (const float*)d_in[27];
    const float* gnn_mlp2_w  = (const float*)d_in[28];
    const float* gnn_mlp2_b  = (const float*)d_in[29];
    const float* final_w     = (const float*)d_in[30];
    const float* final_b     = (const float*)d_in[31];
    const float* bin_score   = (const float*)d_in[32];

    char* wsb = (char*)d_ws;
    size_t off = 0;
    auto alloc = [&](size_t bytes) -> void* {
        void* p = wsb + off;
        off = (off + bytes + 255) & ~(size_t)255;
        return p;
    };
    typedef __hip_bfloat16 bf;
    const long ROWS = 4L * Nc;
    // fp32
    float* descF  = (float*)alloc(ROWS * 256 * 4);
    float* ybufF  = (float*)alloc(ROWS * 512 * 4);
    float* Zm     = (float*)alloc((long)Bc * NP1c * LDZ * 4);
    float* ZT     = (float*)alloc((long)Bc * NP1c * LDZ * 4);
    float* uvec   = (float*)alloc(Bc * LDV * 4);
    float* vvec   = (float*)alloc(Bc * LDV * 4);
    float* projBp = (float*)alloc(9L * 768 * 4);
    float* b1c    = (float*)alloc(9L * 512 * 4);
    float* kw1T   = (float*)alloc(32L * 64 * 4);
    float* kw2T   = (float*)alloc(64L * 128 * 4);
    float* kw3T   = (float*)alloc(128L * 256 * 4);
    // activation planes
    bf* catHi = (bf*)alloc(ROWS * 512 * 2);  bf* catLo = (bf*)alloc(ROWS * 512 * 2);
    bf* qFh = (bf*)alloc(1048576 * 2);
    bf* kFh = (bf*)alloc(1048576 * 2);
    bf* vFh = (bf*)alloc(1048576 * 2);
    bf* ybHi  = (bf*)alloc(ROWS * 512 * 2);
    bf* mdHi  = (bf*)alloc(ROWS * 256 * 2);  bf* mdLo  = (bf*)alloc(ROWS * 256 * 2);
    // weight planes
    bf* projHi = (bf*)alloc(9L*768*256*2);   bf* projLo = (bf*)alloc(9L*768*256*2);
    bf* mrgTHi = (bf*)alloc(9L*256*256*2);   bf* mrgTLo = (bf*)alloc(9L*256*256*2);
    bf* m1bHi  = (bf*)alloc(9L*512*256*2);   bf* m1bLo  = (bf*)alloc(9L*512*256*2);
    bf* m1cHi  = (bf*)alloc(9L*512*512*2);   bf* m1cLo  = (bf*)alloc(9L*512*512*2);
    bf* m2Hi   = (bf*)alloc(9L*256*512*2);   bf* m2Lo   = (bf*)alloc(9L*256*512*2);
    bf* finHi  = (bf*)alloc(256L*256*2);     bf* finLo  = (bf*)alloc(256L*256*2);

    // ---- weight prep ----
    wconv_proj<<<dim3((9*768*256+255)/256), 256, 0, stream>>>(gnn_proj_w, projHi, projLo);
    wconv_proj_bias<<<dim3(27), 256, 0, stream>>>(gnn_proj_b, projBp);
    wconv_mergeT<<<dim3((9*256*256+255)/256), 256, 0, stream>>>(gnn_merge_w, mrgTHi, mrgTLo);
    wconv_m1<<<dim3((int)((9L*512*512+255)/256)), 256, 0, stream>>>(gnn_mlp1_w, m1cHi, m1cLo, m1bHi, m1bLo);
    wconv_plain<<<dim3((9*256*512+255)/256), 256, 0, stream>>>(gnn_mlp2_w, m2Hi, m2Lo, 9L*256*512);
    wconv_plain<<<dim3((256*256+255)/256), 256, 0, stream>>>(final_w, finHi, finLo, 256L*256);
    bias_fold<<<dim3(9*512), 64, 0, stream>>>(gnn_mlp1_w, gnn_mlp1_b, gnn_merge_b, b1c);
    transposeW<<<dim3((64*32+255)/256), 256, 0, stream>>>(kw1, kw1T, 64, 32);
    transposeW<<<dim3((128*64+255)/256), 256, 0, stream>>>(kw2, kw2T, 128, 64);
    transposeW<<<dim3((256*128+255)/256), 256, 0, stream>>>(kw3, kw3T, 256, 128);
    // combined mlp1 cols 256..511 = W1b x WmT^T per layer (full hi/lo accuracy)
    mfma_nt<128,128,1,1,1><<<dim3(2,4,9), 256, 0, stream>>>(
        (const short*)m1bHi, (const short*)m1bLo, 256,
        (const short*)mrgTHi, (const short*)mrgTLo, 256,
        256, 1.f, nullptr,
        nullptr, m1cHi + 256, m1cLo + 256, nullptr, nullptr, 512,
        512L*256, 256L*256, 512L*512);

    // ---- keypoint encoder -> descF + cat planes cols 0..255 ----
    kenc_kernel<<<dim3(Nc, Bc), 256, 0, stream>>>(kpts0, scores0, desc0, descF,
        catHi, catLo,
        kw0, kb0, kg0, ke0, kw1T, kb1, kg1, ke1, kw2T, kb2, kg2, ke2, kw3T, kb3);
    kenc_kernel<<<dim3(Nc, Bc), 256, 0, stream>>>(kpts1, scores1, desc1, descF + 2L*Nc*256,
        catHi + 2L*Nc*512, catLo + 2L*Nc*512,
        kw0, kb0, kg0, ke0, kw1T, kb1, kg1, ke1, kw2T, kb2, kg2, ke2, kw3T, kb3);

    // ---- GNN layers ----
    for (int l = 0; l < 9; ++l) {
        // 1) qkv GEMM (A hi, W hi) -> Q/K/V hi fragment-order
        mfma_nt<64,64,2,0,0><<<dim3(12,64,1), 256, 0, stream>>>(
            (const short*)catHi, nullptr, 512,
            (const short*)(projHi + (long)l*768*256), nullptr, 256,
            256, 1.f, projBp + (long)l*768,
            nullptr, qFh, nullptr, vFh, kFh, 0,
            0, 0, 0);
        // 2) fused attention -> catbuf hi cols 256..511
        attn_fused<<<dim3(64, 16), 256, 0, stream>>>(qFh, kFh, vFh, catHi);
        // 3) mlp1 (A hi, W hi, combined weights) -> ybufF
        mfma_nt<64,64,0,0,0><<<dim3(8,64,1), 256, 0, stream>>>(
            (const short*)catHi, nullptr, 512,
            (const short*)(m1cHi + (long)l*512*512), nullptr, 512,
            512, 1.f, b1c + (long)l*512,
            ybufF, nullptr, nullptr, nullptr, nullptr, 512,
            0, 0, 0);
        // 4) LN+ReLU (wave-per-row) -> yb hi
        ln_relu_w<<<dim3(1024), 256, 0, stream>>>(
            ybufF, gnn_ln_g + (long)l*512, gnn_ln_b + (long)l*512, ybHi);
        // 5) mlp2 (A hi, W hi) fused residual -> descF + cat hi/lo cols 0..255
        mfma_nt<64,64,3,0,0><<<dim3(4,64,1), 256, 0, stream>>>(
            (const short*)ybHi, nullptr, 512,
            (const short*)(m2Hi + (long)l*256*512), nullptr, 512,
            512, 1.f, gnn_mlp2_b + (long)l*256,
            descF, catHi, catLo, nullptr, nullptr, 0,
            0, 0, 0);
    }

    // ---- final projection (A hi/lo, W hi) -> mdesc planes ----
    mfma_nt<64,64,1,0,1><<<dim3(4,64,1), 256, 0, stream>>>(
        (const short*)catHi, (const short*)catLo, 512,
        (const short*)finHi, nullptr, 256,
        256, 1.f, final_b,
        nullptr, mdHi, mdLo, nullptr, nullptr, 256,
        0, 0, 0);
    // ---- score matrix into Z (activation x activation: full hi/lo) ----
    mfma_nt<64,64,0,1,1><<<dim3(16,16,2), 256, 0, stream>>>(
        (const short*)mdHi, (const short*)mdLo, 256,
        (const short*)mdHi + 2048L*256, (const short*)mdLo + 2048L*256, 256,
        256, 1.f/16.f, nullptr,
        Zm, nullptr, nullptr, nullptr, nullptr, LDZ,
        1024L*256, 1024L*256, (long)NP1c*LDZ);
    bins_fill<<<dim3(9,2), 256, 0, stream>>>(Zm, bin_score);

    // ---- Sinkhorn (log-space), 20 iterations (wave-per-row LSE) ----
    transpose_np1<<<dim3(33,33,2), dim3(32,8), 0, stream>>>(Zm, ZT);
    zero_vec<<<dim3((2*LDV+255)/256), 256, 0, stream>>>(vvec, Bc * LDV);
    zero_vec<<<dim3((2*LDV+255)/256), 256, 0, stream>>>(uvec, Bc * LDV);
    for (int it = 0; it < 20; ++it) {
        sinkhorn_lse<<<dim3(513), 256, 0, stream>>>(Zm, vvec, uvec);
        sinkhorn_lse<<<dim3(513), 256, 0, stream>>>(ZT, uvec, vvec);
    }
    final_out_k<<<dim3(NP1c, Bc), 256, 0, stream>>>(Zm, uvec, vvec, (float*)d_out);
}

// Round 11
// 879.399 us; speedup vs baseline: 6.6630x; 1.0319x over previous
//
#include <hip/hip_runtime.h>
#include <hip/hip_bf16.h>
#include <math.h>

#define DEVI static __device__ __forceinline__

namespace {
constexpr int Bc   = 2;
constexpr int Nc   = 1024;
constexpr int Dc   = 256;
constexpr int NP1c = 1025;
constexpr int LDZ  = 1028;              // padded Z row stride (16B-aligned)
constexpr int LDV  = 1028;              // padded u/v stride
constexpr float LN_EPS = 1e-6f;
constexpr float NORMV  = -7.6246189861593985f; // -log(2048)
constexpr float LOGNV  =  6.9314718055994531f; // log(1024)
}

typedef __attribute__((ext_vector_type(8))) short bf16x8;
typedef __attribute__((ext_vector_type(4))) float f32x4;

DEVI void split2(float v, __hip_bfloat16& h, __hip_bfloat16& l) {
    h = __float2bfloat16(v);
    l = __float2bfloat16(v - __bfloat162float(h));
}

DEVI float bf2f(short u) { return __uint_as_float(((unsigned)(unsigned short)u) << 16); }

// async global->LDS, 16B per lane
#define GLDS16(gp, lp) __builtin_amdgcn_global_load_lds( \
    (const __attribute__((address_space(1))) void*)(gp), \
    (__attribute__((address_space(3))) void*)(lp), 16, 0, 0)

// ---------------- helpers ----------------
DEVI float block_sum_256(float v, float* scratch) {
    int t = threadIdx.x;
    scratch[t] = v;
    __syncthreads();
    for (int s = 128; s > 0; s >>= 1) {
        if (t < s) scratch[t] += scratch[t + s];
        __syncthreads();
    }
    float r = scratch[0];
    __syncthreads();
    return r;
}

DEVI void ln_relu_inplace(float* x, const float* g, const float* be, int C, float* scratch) {
    int t = threadIdx.x;
    float v = (t < C) ? x[t] : 0.f;
    float mean = block_sum_256(v, scratch) / (float)C;
    float dv = (t < C) ? (x[t] - mean) : 0.f;
    float var = block_sum_256(dv * dv, scratch) / (float)(C - 1);
    float rstd = 1.f / (sqrtf(var) + LN_EPS);
    if (t < C) x[t] = fmaxf(g[t] * dv * rstd + be[t], 0.f);
    __syncthreads();
}

// ---------------- keypoint encoder (both dirs in one launch) ----------------
__global__ __launch_bounds__(256) void kenc_kernel(
    const float* __restrict__ kpts0, const float* __restrict__ kpts1,
    const float* __restrict__ scr0, const float* __restrict__ scr1,
    const float* __restrict__ desc0, const float* __restrict__ desc1,
    float* __restrict__ descF,
    __hip_bfloat16* __restrict__ catHi, __hip_bfloat16* __restrict__ catLo,
    const float* __restrict__ w0, const float* __restrict__ b0,
    const float* __restrict__ g0, const float* __restrict__ be0,
    const float* __restrict__ w1T, const float* __restrict__ b1,
    const float* __restrict__ g1, const float* __restrict__ be1,
    const float* __restrict__ w2T, const float* __restrict__ b2,
    const float* __restrict__ g2, const float* __restrict__ be2,
    const float* __restrict__ w3T, const float* __restrict__ b3)
{
    __shared__ float xa[256], xb[256], scratch[256];
    const int n = blockIdx.x, db = blockIdx.y, t = threadIdx.x;
    const int dir = db >> 1, b = db & 1;
    const float* kpts = dir ? kpts1 : kpts0;
    const float* scr  = dir ? scr1  : scr0;
    const float* dsc  = dir ? desc1 : desc0;
    if (t == 0) {
        float kx = kpts[((long)b * Nc + n) * 2 + 0];
        float ky = kpts[((long)b * Nc + n) * 2 + 1];
        xa[0] = (kx - 320.f) * (1.f / 448.f);
        xa[1] = (ky - 240.f) * (1.f / 448.f);
        xa[2] = scr[b * Nc + n];
    }
    __syncthreads();
    if (t < 32) { float a = b0[t]; for (int c = 0; c < 3;  ++c) a += w0[t*3 + c] * xa[c]; xb[t] = a; }
    __syncthreads();
    ln_relu_inplace(xb, g0, be0, 32, scratch);
    if (t < 64) {
        float a = b1[t];
        #pragma unroll 8
        for (int c = 0; c < 32;  ++c) a += w1T[c*64 + t] * xb[c];
        xa[t] = a;
    }
    __syncthreads();
    ln_relu_inplace(xa, g1, be1, 64, scratch);
    if (t < 128) {
        float a = b2[t];
        #pragma unroll 8
        for (int c = 0; c < 64;  ++c) a += w2T[c*128 + t] * xa[c];
        xb[t] = a;
    }
    __syncthreads();
    ln_relu_inplace(xb, g2, be2, 128, scratch);
    {   float a = b3[t];
        #pragma unroll 8
        for (int c = 0; c < 128; ++c) a += w3T[c*256 + t] * xb[c];
        float v = dsc[((long)b * Dc + t) * Nc + n] + a;
        descF[((long)db * Nc + n) * Dc + t] = v;
        __hip_bfloat16 h, l; split2(v, h, l);
        long cr = ((long)db * Nc + n) * 512 + t;
        catHi[cr] = h; catLo[cr] = l;
    }
}

__global__ __launch_bounds__(256) void transposeW(
    const float* __restrict__ src, float* __restrict__ dst, int O, int C)
{
    long i = (long)blockIdx.x * 256 + threadIdx.x;
    if (i >= (long)O * C) return;
    int o = (int)(i / C), c = (int)(i % C);
    dst[(long)c * O + o] = src[i];
}

// =======================================================================
// MFMA NT GEMM, BK=32*BKC staged per barrier. A hi(+lo if ALO); B hi(+lo if BLO).
// EPI: 0 fp32 out; 1 bf16 hi/lo planes; 2 qkv -> Q/K/V hi frag-order;
//      3 mlp2 fused resid; 4 bf16 hi only. K % (32*BKC) == 0.
// =======================================================================
template<int BM, int BN, int EPI, int BLO, int ALO, int BKC>
__global__ __launch_bounds__(256) void mfma_nt(
    const short* __restrict__ Ahi0, const short* __restrict__ Alo0, int lda,
    const short* __restrict__ Bhi0, const short* __restrict__ Blo0, int ldb,
    int K, float scale, const float* __restrict__ bias,
    float* __restrict__ outF, __hip_bfloat16* __restrict__ outHi,
    __hip_bfloat16* __restrict__ outLo,
    __hip_bfloat16* __restrict__ outHi2, __hip_bfloat16* __restrict__ outHi3,
    int ldo,
    long aS1, long bS1, long oS1)
{
    constexpr int MI = BM / 32;
    constexpr int NI = BN / 32;
    constexpr int instA = BM / 16, instB = BN / 16;
    constexpr int OFF_AH = 0;
    constexpr int OFF_AL = BM * 32;                       // valid when ALO
    constexpr int OFF_BH = (1 + ALO) * BM * 32;
    constexpr int OFF_BL = OFF_BH + BN * 32;              // valid when BLO
    constexpr int CHUNK = ((1 + ALO) * BM + (1 + BLO) * BN) * 32;
    __shared__ short smem[BKC * CHUNK];

    const int z = blockIdx.z;
    const long aOff = z * aS1, bOff = z * bS1, oOff = z * oS1;
    const short* Ah = Ahi0 + aOff;
    const short* Al = ALO ? (Alo0 + aOff) : nullptr;
    const short* Bh = Bhi0 + bOff;
    const short* Bl = BLO ? (Blo0 + bOff) : nullptr;

    const int m0 = blockIdx.y * BM, n0 = blockIdx.x * BN;
    const int t = threadIdx.x, lane = t & 63, wid = t >> 6;
    const int lr = lane & 15, lg = lane >> 4;
    const int wr = wid >> 1, wc = wid & 1;

    f32x4 acc[MI][NI];
    for (int mi = 0; mi < MI; ++mi)
        for (int ni = 0; ni < NI; ++ni)
            acc[mi][ni] = f32x4{0.f, 0.f, 0.f, 0.f};

    for (int k0 = 0; k0 < K; k0 += 32 * BKC) {
        constexpr int total = (1 + ALO) * instA + (1 + BLO) * instB;
        for (int q = wid; q < total; q += 4) {
            const short* gsrc; int ldg, mi, ploff, row0;
            if (q < instA)                      { gsrc = Ah; ldg = lda; mi = q;          ploff = OFF_AH; row0 = m0; }
            else if (ALO && q < 2 * instA)      { gsrc = Al; ldg = lda; mi = q - instA;  ploff = OFF_AL; row0 = m0; }
            else {
                int rb = q - (1 + ALO) * instA;
                if (rb < instB) { gsrc = Bh; mi = rb;         ploff = OFF_BH; }
                else            { gsrc = Bl; mi = rb - instB; ploff = OFF_BL; }
                ldg = ldb; row0 = n0;
            }
            const short* g = gsrc + (long)(row0 + mi * 16 + lr) * ldg + (k0 + lg * 8);
            #pragma unroll
            for (int c = 0; c < BKC; ++c)
                GLDS16(g + 32 * c, smem + c * CHUNK + ploff + mi * 512);
        }
        __syncthreads();
        #pragma unroll
        for (int kc2 = 0; kc2 < BKC; ++kc2) {
            const short* sm2 = smem + kc2 * CHUNK;
            bf16x8 ah[MI], al[MI];
            #pragma unroll
            for (int mi = 0; mi < MI; ++mi) {
                ah[mi] = *(const bf16x8*)(sm2 + OFF_AH + ((wr * MI + mi) * 64 + lane) * 8);
                if (ALO) al[mi] = *(const bf16x8*)(sm2 + OFF_AL + ((wr * MI + mi) * 64 + lane) * 8);
            }
            #pragma unroll
            for (int ni = 0; ni < NI; ++ni) {
                bf16x8 bh = *(const bf16x8*)(sm2 + OFF_BH + ((wc * NI + ni) * 64 + lane) * 8);
                #pragma unroll
                for (int mi = 0; mi < MI; ++mi) {
                    acc[mi][ni] = __builtin_amdgcn_mfma_f32_16x16x32_bf16(ah[mi], bh, acc[mi][ni], 0, 0, 0);
                    if (ALO) acc[mi][ni] = __builtin_amdgcn_mfma_f32_16x16x32_bf16(al[mi], bh, acc[mi][ni], 0, 0, 0);
                }
                if (BLO) {
                    bf16x8 bl = *(const bf16x8*)(sm2 + OFF_BL + ((wc * NI + ni) * 64 + lane) * 8);
                    #pragma unroll
                    for (int mi = 0; mi < MI; ++mi)
                        acc[mi][ni] = __builtin_amdgcn_mfma_f32_16x16x32_bf16(ah[mi], bl, acc[mi][ni], 0, 0, 0);
                }
            }
        }
        __syncthreads();
    }

    for (int mi = 0; mi < MI; ++mi) {
        for (int i = 0; i < 4; ++i) {
            int row = m0 + wr * (BM / 2) + mi * 16 + lg * 4 + i;
            for (int ni = 0; ni < NI; ++ni) {
                int col = n0 + wc * (BN / 2) + ni * 16 + lr;
                float v = acc[mi][ni][i] * scale;
                if (bias) v += bias[col];
                if (EPI == 0) {
                    outF[(long)row * ldo + col + oOff] = v;
                } else if (EPI == 1) {
                    __hip_bfloat16 h, l;
                    split2(v, h, l);
                    outHi[(long)row * ldo + col + oOff] = h;
                    outLo[(long)row * ldo + col + oOff] = l;
                } else if (EPI == 2) {
                    // Q/K/V hi-only fragment-order scatter
                    int dirb = row >> 10, rloc = row & 1023;
                    int tq = col >> 8, within = col & 255;
                    int h4 = within >> 6, hd = within & 63;
                    __hip_bfloat16 hh = __float2bfloat16(v);
                    if (tq == 2) {
                        int w2 = rloc >> 8, mloc = rloc & 255;
                        int lane2 = ((mloc & 31) >> 3) * 16 + (hd & 15);
                        long idx = ((((long)(dirb*4+h4)*4 + w2)*8 + (mloc>>5))*4 + (hd>>4))*512 + lane2*8 + (mloc&7);
                        outHi2[idx] = hh;
                    } else {
                        int lane2 = ((hd & 31) >> 3) * 16 + (rloc & 15);
                        long idx = (((long)(dirb*4+h4)*64 + (rloc>>4))*2 + (hd>>5))*512 + lane2*8 + (hd&7);
                        if (tq == 0) outHi[idx] = hh;
                        else         outHi3[idx] = hh;
                    }
                } else if (EPI == 3) { // fused residual (descF) + cat planes cols 0..255
                    long i256 = (long)row * 256 + col;
                    v += outF[i256];
                    outF[i256] = v;
                    __hip_bfloat16 h, l;
                    split2(v, h, l);
                    outHi[(long)row * 512 + col] = h;
                    outLo[(long)row * 512 + col] = l;
                } else { // EPI==4: bf16 hi only
                    outHi[(long)row * ldo + col + oOff] = __float2bfloat16(v);
                }
            }
        }
    }
}

// =======================================================================
// Fully fused attention. Q,K,V hi-only. Fragment-order coalesced loads.
// =======================================================================
__global__ __launch_bounds__(256) void attn_fused(
    const __hip_bfloat16* __restrict__ qFh,
    const __hip_bfloat16* __restrict__ kFh, const __hip_bfloat16* __restrict__ vFh,
    __hip_bfloat16* __restrict__ catHi)
{
    __shared__ short pLds[4 * 16 * 256];   // 32KB; reused as f32 partials
    __shared__ float redm[4][16], reds[4][16];
    const int y = blockIdx.y;
    const int dir = y >> 3, b = (y >> 2) & 1, h = y & 3;
    const int q0 = blockIdx.x * 16;
    const int t = threadIdx.x, lane = t & 63, w = t >> 6;
    const int lr = lane & 15, lg = lane >> 4;
    const int dbQ = dir * 2 + b;
    const int srcdb = (1 - dir) * 2 + b;
    const short* qh = (const short*)qFh;
    const short* kh = (const short*)kFh;
    const short* vh = (const short*)vFh;

    const long qbase = (((long)(dbQ * 4 + h)) * 64 + (q0 >> 4)) * 2;
    bf16x8 ah[2];
    #pragma unroll
    for (int kc = 0; kc < 2; ++kc)
        ah[kc] = *(const bf16x8*)(qh + (qbase + kc) * 512 + lane * 8);

    f32x4 acc[16];
    #pragma unroll
    for (int ni = 0; ni < 16; ++ni) acc[ni] = f32x4{0.f, 0.f, 0.f, 0.f};

    const long kbase0 = (((long)(srcdb * 4 + h)) * 64 + w * 16) * 2;
    #pragma unroll
    for (int ni = 0; ni < 16; ++ni) {
        long kb = (kbase0 + ni * 2) * 512 + lane * 8;
        bf16x8 bh0 = *(const bf16x8*)(kh + kb);
        bf16x8 bh1 = *(const bf16x8*)(kh + kb + 512);
        acc[ni] = __builtin_amdgcn_mfma_f32_16x16x32_bf16(ah[0], bh0, acc[ni], 0, 0, 0);
        acc[ni] = __builtin_amdgcn_mfma_f32_16x16x32_bf16(ah[1], bh1, acc[ni], 0, 0, 0);
    }

    float mx[4] = {-1e30f, -1e30f, -1e30f, -1e30f};
    #pragma unroll
    for (int ni = 0; ni < 16; ++ni)
        #pragma unroll
        for (int i = 0; i < 4; ++i) {
            float v = acc[ni][i] * 0.125f;
            acc[ni][i] = v;
            mx[i] = fmaxf(mx[i], v);
        }
    #pragma unroll
    for (int off = 1; off < 16; off <<= 1)
        #pragma unroll
        for (int i = 0; i < 4; ++i) mx[i] = fmaxf(mx[i], __shfl_xor(mx[i], off));
    if (lr == 0)
        #pragma unroll
        for (int i = 0; i < 4; ++i) redm[w][lg * 4 + i] = mx[i];
    __syncthreads();
    float Mv[4];
    #pragma unroll
    for (int i = 0; i < 4; ++i)
        Mv[i] = fmaxf(fmaxf(redm[0][lg*4+i], redm[1][lg*4+i]),
                      fmaxf(redm[2][lg*4+i], redm[3][lg*4+i]));
    float sm[4] = {0.f, 0.f, 0.f, 0.f};
    #pragma unroll
    for (int ni = 0; ni < 16; ++ni)
        #pragma unroll
        for (int i = 0; i < 4; ++i) {
            float e = __expf(acc[ni][i] - Mv[i]);
            acc[ni][i] = e;
            sm[i] += e;
        }
    #pragma unroll
    for (int off = 1; off < 16; off <<= 1)
        #pragma unroll
        for (int i = 0; i < 4; ++i) sm[i] += __shfl_xor(sm[i], off);
    if (lr == 0)
        #pragma unroll
        for (int i = 0; i < 4; ++i) reds[w][lg * 4 + i] = sm[i];
    __syncthreads();
    float inv[4];
    #pragma unroll
    for (int i = 0; i < 4; ++i)
        inv[i] = 1.f / (reds[0][lg*4+i] + reds[1][lg*4+i] + reds[2][lg*4+i] + reds[3][lg*4+i]);

    char* pB = (char*)pLds + w * 8192;
    #pragma unroll
    for (int ni = 0; ni < 16; ++ni)
        #pragma unroll
        for (int i = 0; i < 4; ++i) {
            int q = lg * 4 + i, m = ni * 16 + lr;
            int byte = (q * 512 + m * 2) ^ ((q & 7) << 4);
            *(short*)(pB + byte) = (short)__bfloat16_as_ushort(__float2bfloat16(acc[ni][i] * inv[i]));
        }
    __syncthreads();

    f32x4 acc2[4];
    #pragma unroll
    for (int bi = 0; bi < 4; ++bi) acc2[bi] = f32x4{0.f, 0.f, 0.f, 0.f};
    const long vbase0 = (((long)(srcdb * 4 + h)) * 4 + w) * 8;
    #pragma unroll
    for (int km = 0; km < 8; ++km) {
        int rb = (lr * 512 + km * 64 + lg * 16) ^ ((lr & 7) << 4);
        bf16x8 pa = *(const bf16x8*)(pB + rb);
        #pragma unroll
        for (int bi = 0; bi < 4; ++bi) {
            long vr = ((vbase0 + km) * 4 + bi) * 512 + lane * 8;
            bf16x8 vhf = *(const bf16x8*)(vh + vr);
            acc2[bi] = __builtin_amdgcn_mfma_f32_16x16x32_bf16(pa, vhf, acc2[bi], 0, 0, 0);
        }
    }
    __syncthreads();
    float* pr = (float*)pLds;
    #pragma unroll
    for (int bi = 0; bi < 4; ++bi)
        #pragma unroll
        for (int i = 0; i < 4; ++i)
            pr[w * 1024 + (lg * 4 + i) * 64 + bi * 16 + lr] = acc2[bi][i];
    __syncthreads();
    #pragma unroll
    for (int k = 0; k < 4; ++k) {
        int e = t + k * 256;
        float v = pr[e] + pr[1024 + e] + pr[2048 + e] + pr[3072 + e];
        int q = e >> 6, d = e & 63;
        long a = ((long)dbQ * 1024 + q0 + q) * 512 + 256 + h * 64 + d;
        catHi[a] = __float2bfloat16(v);
    }
}

// ---------------- LN(channel,ddof=1,eps-on-std)+ReLU; wave-per-row; bf16 in-place ----------------
__global__ __launch_bounds__(256) void ln_relu_w(
    __hip_bfloat16* __restrict__ y, const float* __restrict__ g, const float* __restrict__ be)
{
    const int t = threadIdx.x, lane = t & 63, w = t >> 6;
    const long row = (long)blockIdx.x * 4 + w;
    short* src = (short*)y + row * 512;
    bf16x8 r = *(const bf16x8*)(src + lane * 8);
    float xv[8];
    #pragma unroll
    for (int k = 0; k < 8; ++k) xv[k] = bf2f(r[k]);
    float s = 0.f, q = 0.f;
    #pragma unroll
    for (int k = 0; k < 8; ++k) { s += xv[k]; q += xv[k] * xv[k]; }
    #pragma unroll
    for (int off = 1; off < 64; off <<= 1) {
        s += __shfl_xor(s, off);
        q += __shfl_xor(q, off);
    }
    float mean = s / 512.f;
    float var = fmaxf((q - 512.f * mean * mean) / 511.f, 0.f);
    float rstd = 1.f / (sqrtf(var) + LN_EPS);
    float4 g0 = ((const float4*)g)[lane * 2], g1 = ((const float4*)g)[lane * 2 + 1];
    float4 b0 = ((const float4*)be)[lane * 2], b1 = ((const float4*)be)[lane * 2 + 1];
    float gv[8] = {g0.x, g0.y, g0.z, g0.w, g1.x, g1.y, g1.z, g1.w};
    float bv[8] = {b0.x, b0.y, b0.z, b0.w, b1.x, b1.y, b1.z, b1.w};
    bf16x8 outv;
    #pragma unroll
    for (int k = 0; k < 8; ++k) {
        float o = fmaxf(gv[k] * (xv[k] - mean) * rstd + bv[k], 0.f);
        outv[k] = (short)__bfloat16_as_ushort(__float2bfloat16(o));
    }
    *(bf16x8*)(src + lane * 8) = outv;
}

// ---------------- weight converts ----------------
__global__ __launch_bounds__(256) void wconv_plain(
    const float* __restrict__ w, __hip_bfloat16* __restrict__ hi, __hip_bfloat16* __restrict__ lo, long total)
{
    long i = (long)blockIdx.x * 256 + threadIdx.x;
    if (i >= total) return;
    __hip_bfloat16 h, l; split2(w[i], h, l);
    hi[i] = h; lo[i] = l;
}

__global__ __launch_bounds__(256) void wconv_proj(
    const float* __restrict__ w, __hip_bfloat16* __restrict__ hi, __hip_bfloat16* __restrict__ lo)
{
    long i = (long)blockIdx.x * 256 + threadIdx.x;
    if (i >= 9L * 768 * 256) return;
    long l9 = i / (768 * 256);
    int rem = (int)(i % (768 * 256));
    int op = rem / 256, c = rem % 256;
    int tq = op / 256, within = op % 256;
    int h = within / 64, hd = within % 64;
    int o = tq * 256 + hd * 4 + h;
    float v = w[(l9 * 768 + o) * 256 + c];
    __hip_bfloat16 hh, ll; split2(v, hh, ll);
    hi[i] = hh; lo[i] = ll;
}

__global__ void wconv_proj_bias(const float* __restrict__ b, float* __restrict__ bp)
{
    int i = blockIdx.x * 256 + threadIdx.x;
    if (i >= 9 * 768) return;
    int l9 = i / 768, op = i % 768;
    int tq = op / 256, within = op % 256;
    int h = within / 64, hd = within % 64;
    bp[i] = b[(l9 * 3 + tq) * 256 + hd * 4 + h];
}

// WmT planes: [l][c=h*64+hd][j] = Wm[l][j][hd*4+h]
__global__ __launch_bounds__(256) void wconv_mergeT(
    const float* __restrict__ w, __hip_bfloat16* __restrict__ hi, __hip_bfloat16* __restrict__ lo)
{
    long i = (long)blockIdx.x * 256 + threadIdx.x;
    if (i >= 9L * 256 * 256) return;
    long l9 = i / (256 * 256);
    int rem = (int)(i % (256 * 256));
    int c = rem / 256, j = rem % 256;
    int h = c / 64, hd = c % 64;
    float v = w[(l9 * 256 + j) * 256 + (hd * 4 + h)];
    __hip_bfloat16 hh, ll; split2(v, hh, ll);
    hi[i] = hh; lo[i] = ll;
}

// mlp1 W split: cols 0..255 -> m1c[..512-wide cols 0..255]; cols 256..511 -> m1b[..256-wide]
__global__ __launch_bounds__(256) void wconv_m1(
    const float* __restrict__ w,
    __hip_bfloat16* __restrict__ m1cHi, __hip_bfloat16* __restrict__ m1cLo,
    __hip_bfloat16* __restrict__ m1bHi, __hip_bfloat16* __restrict__ m1bLo)
{
    long i = (long)blockIdx.x * 256 + threadIdx.x;
    if (i >= 9L * 512 * 512) return;
    long lo9 = i / 512;
    int c = (int)(i % 512);
    __hip_bfloat16 hh, ll; split2(w[i], hh, ll);
    if (c < 256) { m1cHi[lo9 * 512 + c] = hh; m1cLo[lo9 * 512 + c] = ll; }
    else         { m1bHi[lo9 * 256 + c - 256] = hh; m1bLo[lo9 * 256 + c - 256] = ll; }
}

// b1c[l*512+o] = b1[l][o] + sum_j W1[l][o][256+j]*bm[l][j]
__global__ __launch_bounds__(64) void bias_fold(
    const float* __restrict__ w1, const float* __restrict__ b1,
    const float* __restrict__ bm, float* __restrict__ out)
{
    int og = blockIdx.x;
    int l = og >> 9, o = og & 511;
    int t = threadIdx.x;
    float s = 0.f;
    for (int j = t; j < 256; j += 64)
        s += w1[((long)l * 512 + o) * 512 + 256 + j] * bm[l * 256 + j];
    for (int off = 32; off > 0; off >>= 1) s += __shfl_down(s, off);
    if (t == 0) out[og] = b1[(long)l * 512 + o] + s;
}

// ---------------- Sinkhorn pieces (padded LDZ=1028 layout) ----------------
__global__ void bins_fill(float* __restrict__ Z, const float* __restrict__ alpha_p)
{
    float alpha = alpha_p[0];
    int idx = blockIdx.x * 256 + threadIdx.x;
    int b = blockIdx.y;
    float* Zb = Z + (long)b * NP1c * LDZ;
    if (idx < NP1c) Zb[(long)1024 * LDZ + idx] = alpha;
    else { int i = idx - NP1c; if (i < 1024) Zb[(long)i * LDZ + 1024] = alpha; }
}

__global__ void transpose_np1(const float* __restrict__ Z, float* __restrict__ ZT)
{
    __shared__ float tile[32][33];
    int b = blockIdx.z;
    int i0 = blockIdx.y * 32, j0 = blockIdx.x * 32;
    int tx = threadIdx.x, ty = threadIdx.y;
    const float* Zb = Z + (long)b * NP1c * LDZ;
    float* Tb = ZT + (long)b * NP1c * LDZ;
    for (int ii = ty; ii < 32; ii += 8) {
        int i = i0 + ii, j = j0 + tx;
        if (i < NP1c && j < NP1c) tile[ii][tx] = Zb[(long)i * LDZ + j];
    }
    __syncthreads();
    for (int jj = ty; jj < 32; jj += 8) {
        int j = j0 + jj, i = i0 + tx;
        if (j < NP1c && i < NP1c) Tb[(long)j * LDZ + i] = tile[tx][jj];
    }
}

__global__ void zero_vec2(float* __restrict__ a, float* __restrict__ b, int n)
{
    int i = blockIdx.x * 256 + threadIdx.x;
    if (i < n) { a[i] = 0.f; b[i] = 0.f; }
}

// wave-per-row LSE: out[b][i] = lmu(i) - LSE_j( M[b][i][j] + addv[b][j] )
__global__ __launch_bounds__(256) void sinkhorn_lse(
    const float* __restrict__ M, const float* __restrict__ addv, float* __restrict__ outv)
{
    const int t = threadIdx.x, lane = t & 63, w = t >> 6;
    long rowid = (long)blockIdx.x * 4 + w;
    if (rowid >= 2 * NP1c) return;        // wave-uniform exit
    int b = rowid >= NP1c ? 1 : 0;
    int i = (int)(rowid - (long)b * NP1c);
    const float* row = M + ((long)b * NP1c + i) * LDZ;
    const float* av = addv + (long)b * LDV;
    float m = -1e30f, s = 0.f;
    #pragma unroll
    for (int k = 0; k < 4; ++k) {
        float4 x = ((const float4*)row)[lane * 4 + k];
        float4 a = ((const float4*)av)[lane * 4 + k];
        float u0 = x.x + a.x, u1 = x.y + a.y, u2 = x.z + a.z, u3 = x.w + a.w;
        float mk = fmaxf(fmaxf(u0, u1), fmaxf(u2, u3));
        float sk = __expf(u0 - mk) + __expf(u1 - mk) + __expf(u2 - mk) + __expf(u3 - mk);
        if (mk > m) { s = s * __expf(m - mk) + sk; m = mk; }
        else        { s += sk * __expf(mk - m); }
    }
    if (lane == 0) {
        float v4 = row[1024] + av[1024];
        if (v4 > m) { s = s * __expf(m - v4) + 1.f; m = v4; }
        else        { s += __expf(v4 - m); }
    }
    #pragma unroll
    for (int off = 1; off < 64; off <<= 1) {
        float m2 = __shfl_xor(m, off);
        float s2 = __shfl_xor(s, off);
        float mm = fmaxf(m, m2);
        s = s * __expf(m - mm) + s2 * __expf(m2 - mm);
        m = mm;
    }
    if (lane == 0) {
        float lse = m + __logf(s);
        float lmu = (i < 1024) ? NORMV : (LOGNV + NORMV);
        outv[(long)b * LDV + i] = lmu - lse;
    }
}

__global__ __launch_bounds__(256) void final_out_k(
    const float* __restrict__ Z, const float* __restrict__ u,
    const float* __restrict__ v, float* __restrict__ outp)
{
    const int i = blockIdx.x, b = blockIdx.y, t = threadIdx.x;
    const float* row = Z + ((long)b * NP1c + i) * LDZ;
    float* orow = outp + ((long)b * NP1c + i) * NP1c;
    float ui = u[(long)b * LDV + i];
    for (int j = t; j < NP1c; j += 256)
        orow[j] = row[j] + ui + v[(long)b * LDV + j] - NORMV;
}

// =======================================================================
extern "C" void kernel_launch(void* const* d_in, const int* in_sizes, int n_in,
                              void* d_out, int out_size, void* d_ws, size_t ws_size,
                              hipStream_t stream)
{
    (void)in_sizes; (void)n_in; (void)out_size; (void)ws_size;
    const float* kpts0   = (const float*)d_in[0];
    const float* kpts1   = (const float*)d_in[1];
    const float* scores0 = (const float*)d_in[2];
    const float* scores1 = (const float*)d_in[3];
    const float* desc0   = (const float*)d_in[4];
    const float* desc1   = (const float*)d_in[5];
    const float* kw0 = (const float*)d_in[6];  const float* kb0 = (const float*)d_in[7];
    const float* kg0 = (const float*)d_in[8];  const float* ke0 = (const float*)d_in[9];
    const float* kw1 = (const float*)d_in[10]; const float* kb1 = (const float*)d_in[11];
    const float* kg1 = (const float*)d_in[12]; const float* ke1 = (const float*)d_in[13];
    const float* kw2 = (const float*)d_in[14]; const float* kb2 = (const float*)d_in[15];
    const float* kg2 = (const float*)d_in[16]; const float* ke2 = (const float*)d_in[17];
    const float* kw3 = (const float*)d_in[18]; const float* kb3 = (const float*)d_in[19];
    const float* gnn_proj_w  = (const float*)d_in[20];
    const float* gnn_proj_b  = (const float*)d_in[21];
    const float* gnn_merge_w = (const float*)d_in[22];
    const float* gnn_merge_b = (const float*)d_in[23];
    const float* gnn_mlp1_w  = (const float*)d_in[24];
    const float* gnn_mlp1_b  = (const float*)d_in[25];
    const float* gnn_ln_g    = (const float*)d_in[26];
    const float* gnn_ln_b    = (const float*)d_in[27];
    const float* gnn_mlp2_w  = (const float*)d_in[28];
    const float* gnn_mlp2_b  = (const float*)d_in[29];
    const float* final_w     = (const float*)d_in[30];
    const float* final_b     = (const float*)d_in[31];
    const float* bin_score   = (const float*)d_in[32];

    char* wsb = (char*)d_ws;
    size_t off = 0;
    auto alloc = [&](size_t bytes) -> void* {
        void* p = wsb + off;
        off = (off + bytes + 255) & ~(size_t)255;
        return p;
    };
    typedef __hip_bfloat16 bf;
    const long ROWS = 4L * Nc;
    // fp32
    float* descF  = (float*)alloc(ROWS * 256 * 4);
    float* Zm     = (float*)alloc((long)Bc * NP1c * LDZ * 4);
    float* ZT     = (float*)alloc((long)Bc * NP1c * LDZ * 4);
    float* uvec   = (float*)alloc(Bc * LDV * 4);
    float* vvec   = (float*)alloc(Bc * LDV * 4);
    float* projBp = (float*)alloc(9L * 768 * 4);
    float* b1c    = (float*)alloc(9L * 512 * 4);
    float* kw1T   = (float*)alloc(32L * 64 * 4);
    float* kw2T   = (float*)alloc(64L * 128 * 4);
    float* kw3T   = (float*)alloc(128L * 256 * 4);
    // activation planes
    bf* catHi = (bf*)alloc(ROWS * 512 * 2);  bf* catLo = (bf*)alloc(ROWS * 512 * 2);
    bf* qFh = (bf*)alloc(1048576 * 2);
    bf* kFh = (bf*)alloc(1048576 * 2);
    bf* vFh = (bf*)alloc(1048576 * 2);
    bf* ybHi  = (bf*)alloc(ROWS * 512 * 2);
    bf* mdHi  = (bf*)alloc(ROWS * 256 * 2);  bf* mdLo  = (bf*)alloc(ROWS * 256 * 2);
    // weight planes
    bf* projHi = (bf*)alloc(9L*768*256*2);   bf* projLo = (bf*)alloc(9L*768*256*2);
    bf* mrgTHi = (bf*)alloc(9L*256*256*2);   bf* mrgTLo = (bf*)alloc(9L*256*256*2);
    bf* m1bHi  = (bf*)alloc(9L*512*256*2);   bf* m1bLo  = (bf*)alloc(9L*512*256*2);
    bf* m1cHi  = (bf*)alloc(9L*512*512*2);   bf* m1cLo  = (bf*)alloc(9L*512*512*2);
    bf* m2Hi   = (bf*)alloc(9L*256*512*2);   bf* m2Lo   = (bf*)alloc(9L*256*512*2);
    bf* finHi  = (bf*)alloc(256L*256*2);     bf* finLo  = (bf*)alloc(256L*256*2);

    // ---- weight prep ----
    wconv_proj<<<dim3((9*768*256+255)/256), 256, 0, stream>>>(gnn_proj_w, projHi, projLo);
    wconv_proj_bias<<<dim3(27), 256, 0, stream>>>(gnn_proj_b, projBp);
    wconv_mergeT<<<dim3((9*256*256+255)/256), 256, 0, stream>>>(gnn_merge_w, mrgTHi, mrgTLo);
    wconv_m1<<<dim3((int)((9L*512*512+255)/256)), 256, 0, stream>>>(gnn_mlp1_w, m1cHi, m1cLo, m1bHi, m1bLo);
    wconv_plain<<<dim3((9*256*512+255)/256), 256, 0, stream>>>(gnn_mlp2_w, m2Hi, m2Lo, 9L*256*512);
    wconv_plain<<<dim3((256*256+255)/256), 256, 0, stream>>>(final_w, finHi, finLo, 256L*256);
    bias_fold<<<dim3(9*512), 64, 0, stream>>>(gnn_mlp1_w, gnn_mlp1_b, gnn_merge_b, b1c);
    transposeW<<<dim3((64*32+255)/256), 256, 0, stream>>>(kw1, kw1T, 64, 32);
    transposeW<<<dim3((128*64+255)/256), 256, 0, stream>>>(kw2, kw2T, 128, 64);
    transposeW<<<dim3((256*128+255)/256), 256, 0, stream>>>(kw3, kw3T, 256, 128);
    // combined mlp1 cols 256..511 = W1b x WmT^T per layer (full hi/lo accuracy)
    mfma_nt<128,128,1,1,1,2><<<dim3(2,4,9), 256, 0, stream>>>(
        (const short*)m1bHi, (const short*)m1bLo, 256,
        (const short*)mrgTHi, (const short*)mrgTLo, 256,
        256, 1.f, nullptr,
        nullptr, m1cHi + 256, m1cLo + 256, nullptr, nullptr, 512,
        512L*256, 256L*256, 512L*512);

    // ---- keypoint encoder (both dirs) -> descF + cat planes cols 0..255 ----
    kenc_kernel<<<dim3(Nc, 4), 256, 0, stream>>>(
        kpts0, kpts1, scores0, scores1, desc0, desc1, descF, catHi, catLo,
        kw0, kb0, kg0, ke0, kw1T, kb1, kg1, ke1, kw2T, kb2, kg2, ke2, kw3T, kb3);

    // ---- GNN layers ----
    for (int l = 0; l < 9; ++l) {
        // 1) qkv GEMM (A hi, W hi, BKC=4) -> Q/K/V hi fragment-order
        mfma_nt<64,64,2,0,0,4><<<dim3(12,64,1), 256, 0, stream>>>(
            (const short*)catHi, nullptr, 512,
            (const short*)(projHi + (long)l*768*256), nullptr, 256,
            256, 1.f, projBp + (long)l*768,
            nullptr, qFh, nullptr, vFh, kFh, 0,
            0, 0, 0);
        // 2) fused attention -> catbuf hi cols 256..511
        attn_fused<<<dim3(64, 16), 256, 0, stream>>>(qFh, kFh, vFh, catHi);
        // 3) mlp1 (A hi, W hi, BKC=4) -> ybHi bf16 directly
        mfma_nt<64,64,4,0,0,4><<<dim3(8,64,1), 256, 0, stream>>>(
            (const short*)catHi, nullptr, 512,
            (const short*)(m1cHi + (long)l*512*512), nullptr, 512,
            512, 1.f, b1c + (long)l*512,
            nullptr, ybHi, nullptr, nullptr, nullptr, 512,
            0, 0, 0);
        // 4) LN+ReLU (wave-per-row, bf16 in-place)
        ln_relu_w<<<dim3(1024), 256, 0, stream>>>(
            ybHi, gnn_ln_g + (long)l*512, gnn_ln_b + (long)l*512);
        // 5) mlp2 (A hi, W hi, BKC=4) fused residual -> descF + cat hi/lo cols 0..255
        mfma_nt<64,64,3,0,0,4><<<dim3(4,64,1), 256, 0, stream>>>(
            (const short*)ybHi, nullptr, 512,
            (const short*)(m2Hi + (long)l*256*512), nullptr, 512,
            512, 1.f, gnn_mlp2_b + (long)l*256,
            descF, catHi, catLo, nullptr, nullptr, 0,
            0, 0, 0);
    }

    // ---- final projection (A hi/lo, W hi, BKC=4) -> mdesc planes ----
    mfma_nt<64,64,1,0,1,4><<<dim3(4,64,1), 256, 0, stream>>>(
        (const short*)catHi, (const short*)catLo, 512,
        (const short*)finHi, nullptr, 256,
        256, 1.f, final_b,
        nullptr, mdHi, mdLo, nullptr, nullptr, 256,
        0, 0, 0);
    // ---- score matrix into Z (activation x activation: full hi/lo) ----
    mfma_nt<64,64,0,1,1,2><<<dim3(16,16,2), 256, 0, stream>>>(
        (const short*)mdHi, (const short*)mdLo, 256,
        (const short*)mdHi + 2048L*256, (const short*)mdLo + 2048L*256, 256,
        256, 1.f/16.f, nullptr,
        Zm, nullptr, nullptr, nullptr, nullptr, LDZ,
        1024L*256, 1024L*256, (long)NP1c*LDZ);
    bins_fill<<<dim3(9,2), 256, 0, stream>>>(Zm, bin_score);

    // ---- Sinkhorn (log-space), 20 iterations (wave-per-row LSE) ----
    transpose_np1<<<dim3(33,33,2), dim3(32,8), 0, stream>>>(Zm, ZT);
    zero_vec2<<<dim3((2*LDV+255)/256), 256, 0, stream>>>(uvec, vvec, Bc * LDV);
    for (int it = 0; it < 20; ++it) {
        sinkhorn_lse<<<dim3(513), 256, 0, stream>>>(Zm, vvec, uvec);
        sinkhorn_lse<<<dim3(513), 256, 0, stream>>>(ZT, uvec, vvec);
    }
    final_out_k<<<dim3(NP1c, Bc), 256, 0, stream>>>(Zm, uvec, vvec, (float*)d_out);
}